// Round 11
// baseline (1359.021 us; speedup 1.0000x reference)
//
#include <hip/hip_runtime.h>
#include <hip/hip_bf16.h>
#include <math.h>

#define NN 100000      // nodes
#define NE 1600000     // edges
#define NG 64          // graphs
#define F_IN 5
#define F1 128         // H*HID
#define F2 64          // HID
#define NCLS 4
#define NB_SCAN ((NN + 255) / 256)   // 391 blocks in node scan level 1
#define GROWS 32                     // rows per block in register-blocked GEMMs
#define NCHUNK 250                   // edge chunks (250 * 6400 = NE)
#define CH_E 6400                    // edges per chunk (6400 = 256*25)
#define NBUCK ((NN + 255) / 256)     // 391 dst buckets of 256 nodes
#define CAPB 6144                    // bucket capacity in LDS sort (avg 4096, 32 sigma margin)

typedef unsigned short ushort;

// ---------- bf16 helpers (round-to-nearest-even pack) ----------
__device__ __forceinline__ ushort f2bf(float f) {
    unsigned u = __float_as_uint(f);
    u = (u + 0x7fffu + ((u >> 16) & 1u)) >> 16;
    return (ushort)u;
}
__device__ __forceinline__ float bf2f(ushort h) {
    return __uint_as_float(((unsigned)h) << 16);
}
__device__ __forceinline__ unsigned pack2bf(float a, float b) {
    return (unsigned)f2bf(a) | ((unsigned)f2bf(b) << 16);
}
__device__ __forceinline__ float lo_bf(unsigned p) { return __uint_as_float(p << 16); }
__device__ __forceinline__ float hi_bf(unsigned p) { return __uint_as_float(p & 0xffff0000u); }

// ---------- order-preserving float<->uint encoding for atomicMax ----------
__device__ __forceinline__ unsigned enc_f(float f) {
    unsigned b = __float_as_uint(f);
    return (b & 0x80000000u) ? ~b : (b | 0x80000000u);
}
__device__ __forceinline__ float dec_f(unsigned k) {
    unsigned b = (k & 0x80000000u) ? (k ^ 0x80000000u) : ~k;
    return __uint_as_float(b);
}
#define ENC_NEG_INF 0x007FFFFFu   // enc_f(-inf)

__global__ void k_fill_u32(unsigned* p, unsigned v, int n) {
    int i = blockIdx.x * blockDim.x + threadIdx.x;
    if (i < n) p[i] = v;
}

// =================== CSR build ===================
__global__ void k_count(const int* __restrict__ ei, int* __restrict__ degi) {
    int e = blockIdx.x * blockDim.x + threadIdx.x;
    if (e < NE) atomicAdd(&degi[ei[NE + e]], 1);
}

__global__ void k_scan1(const int* __restrict__ degi, int* __restrict__ rowptr,
                        int* __restrict__ bsum) {
    __shared__ int sh[256];
    int i = blockIdx.x * 256 + threadIdx.x;
    int v = (i < NN) ? degi[i] : 0;
    sh[threadIdx.x] = v;
    __syncthreads();
    for (int off = 1; off < 256; off <<= 1) {
        int t = (threadIdx.x >= off) ? sh[threadIdx.x - off] : 0;
        __syncthreads();
        sh[threadIdx.x] += t;
        __syncthreads();
    }
    if (i < NN) rowptr[i] = sh[threadIdx.x] - v;   // exclusive, block-local
    if (threadIdx.x == 255) bsum[blockIdx.x] = sh[255];
}

__global__ void k_scan2(int* __restrict__ bsum, int nb) {
    __shared__ int sh[512];
    int v = (threadIdx.x < nb) ? bsum[threadIdx.x] : 0;
    sh[threadIdx.x] = v;
    __syncthreads();
    for (int off = 1; off < 512; off <<= 1) {
        int t = (threadIdx.x >= off) ? sh[threadIdx.x - off] : 0;
        __syncthreads();
        sh[threadIdx.x] += t;
        __syncthreads();
    }
    if (threadIdx.x < nb) bsum[threadIdx.x] = sh[threadIdx.x] - v;   // exclusive
}

__global__ void k_scan3(int* __restrict__ rowptr, const int* __restrict__ bsum) {
    int i = blockIdx.x * 256 + threadIdx.x;
    if (i == 0) rowptr[NN] = NE;
    if (i >= NN) return;
    rowptr[i] += bsum[blockIdx.x];
}

// chunk-major radix pass 1: per-chunk histogram over 391 dst buckets
__global__ void k_hist(const int* __restrict__ ei, int* __restrict__ ghist) {
    __shared__ int lh[NBUCK];
    int c = blockIdx.x, t = threadIdx.x;
    for (int b = t; b < NBUCK; b += 256) lh[b] = 0;
    __syncthreads();
    int e0 = c * CH_E;
#pragma unroll
    for (int i = 0; i < CH_E / 256; i++) {
        int d = ei[NE + e0 + t + i * 256];
        atomicAdd(&lh[d >> 8], 1);
    }
    __syncthreads();
    for (int b = t; b < NBUCK; b += 256) ghist[c * NBUCK + b] = lh[b];
}

// pass 2: per-bucket serial prefix over chunks (in place: ghist -> offsets)
__global__ void k_chunkscan(int* __restrict__ ghist, const int* __restrict__ rowptr) {
    int b = blockIdx.x * blockDim.x + threadIdx.x;
    if (b >= NBUCK) return;
    int run = rowptr[b * 256];           // bucket base in csr order
    for (int c = 0; c < NCHUNK; c++) {
        int h = ghist[c * NBUCK + b];
        ghist[c * NBUCK + b] = run;
        run += h;
    }
}

// pass 3: scatter into bucket-major staged array (packed (dlow<<17)|src)
__global__ void k_scatter2(const int* __restrict__ ei, const int* __restrict__ ghist,
                           unsigned* __restrict__ staged) {
    __shared__ int lcur[NBUCK];
    int c = blockIdx.x, t = threadIdx.x;
    for (int b = t; b < NBUCK; b += 256) lcur[b] = ghist[c * NBUCK + b];
    __syncthreads();
    int e0 = c * CH_E;
#pragma unroll
    for (int i = 0; i < CH_E / 256; i++) {
        int e = e0 + t + i * 256;
        int s = ei[e];
        int d = ei[NE + e];
        int pos = atomicAdd(&lcur[d >> 8], 1);
        staged[pos] = (((unsigned)(d & 255)) << 17) | (unsigned)s;
    }
}

// pass 4: per-bucket LDS counting sort by low 8 dst bits -> coalesced csr_src
__global__ void k_bucket_sort(const unsigned* __restrict__ staged,
                              const int* __restrict__ rowptr, int* __restrict__ csr_src) {
    __shared__ unsigned ein[CAPB];
    __shared__ unsigned sout[CAPB];
    __shared__ int lcur[256];
    int b = blockIdx.x, t = threadIdx.x;
    int n0 = b * 256;
    int nend = min(n0 + 256, NN);
    int nn = nend - n0;
    int g0 = rowptr[n0];
    int m = rowptr[nend] - g0;
    if (t < nn) lcur[t] = rowptr[n0 + t] - g0;
    __syncthreads();
    if (m <= CAPB) {
        for (int i = t; i < m; i += 256) ein[i] = staged[g0 + i];
        __syncthreads();
        for (int i = t; i < m; i += 256) {
            unsigned u = ein[i];
            int pos = atomicAdd(&lcur[u >> 17], 1);
            sout[pos] = u & 0x1FFFFu;
        }
        __syncthreads();
        for (int i = t; i < m; i += 256) csr_src[g0 + i] = (int)sout[i];
    } else {
        // statistically unreachable fallback (bucket > CAPB)
        for (int i = t; i < m; i += 256) {
            unsigned u = staged[g0 + i];
            int pos = atomicAdd(&lcur[u >> 17], 1);
            csr_src[g0 + pos] = (int)(u & 0x1FFFFu);
        }
    }
}

// =================== GAT ===================
// xw (bf16) = x @ gat_w ; a_src/a_dst per-node attention logits
__global__ void k_xw(const float* __restrict__ x, const float* __restrict__ gw,
                     const float* __restrict__ aw_src, const float* __restrict__ aw_dst,
                     ushort* __restrict__ xw_bf, float* __restrict__ a_src,
                     float* __restrict__ a_dst) {
    int n = blockIdx.x;
    int f = threadIdx.x;                 // 128 threads, f = h*64+c
    __shared__ float w[F_IN * F1];
    __shared__ float xs[F_IN];
    for (int i = f; i < F_IN * F1; i += F1) w[i] = gw[i];
    if (f < F_IN) xs[f] = x[n * F_IN + f];
    __syncthreads();
    float acc = 0.f;
#pragma unroll
    for (int i = 0; i < F_IN; i++) acc += xs[i] * w[i * F1 + f];
    xw_bf[n * F1 + f] = f2bf(acc);
    int h = f >> 6, lane = f & 63;
    float p = acc * aw_src[f];
    float q = acc * aw_dst[f];
#pragma unroll
    for (int off = 32; off > 0; off >>= 1) {
        p += __shfl_down(p, off);
        q += __shfl_down(q, off);
    }
    if (lane == 0) { a_src[n * 2 + h] = p; a_dst[n * 2 + h] = q; }
}

// per-node softmax over incoming edges, ONE WAVE per node, lane-per-edge.
__global__ void k_alpha(const int* __restrict__ rowptr, const int* __restrict__ csr_src,
                        const float* __restrict__ a_src, const float* __restrict__ a_dst,
                        unsigned* __restrict__ alpha) {
    int n = blockIdx.x * 4 + (threadIdx.x >> 6);
    int lane = threadIdx.x & 63;
    if (n >= NN) return;
    int j0 = rowptr[n], j1 = rowptr[n + 1];
    int deg = j1 - j0;
    if (deg <= 0) return;
    float ad0 = a_dst[n * 2 + 0], ad1 = a_dst[n * 2 + 1];
    if (deg <= 64) {
        int j = j0 + lane;
        float l0 = -INFINITY, l1 = -INFINITY;
        if (lane < deg) {
            int s = csr_src[j];
            l0 = a_src[s * 2 + 0] + ad0;
            l1 = a_src[s * 2 + 1] + ad1;
            l0 = l0 > 0.f ? l0 : 0.2f * l0;
            l1 = l1 > 0.f ? l1 : 0.2f * l1;
        }
        float m0 = l0, m1 = l1;
#pragma unroll
        for (int off = 32; off > 0; off >>= 1) {
            m0 = fmaxf(m0, __shfl_xor(m0, off));
            m1 = fmaxf(m1, __shfl_xor(m1, off));
        }
        float e0 = 0.f, e1 = 0.f;
        if (lane < deg) { e0 = expf(l0 - m0); e1 = expf(l1 - m1); }
        float s0 = e0, s1 = e1;
#pragma unroll
        for (int off = 32; off > 0; off >>= 1) {
            s0 += __shfl_xor(s0, off);
            s1 += __shfl_xor(s1, off);
        }
        if (lane < deg)
            alpha[j] = pack2bf(e0 / (s0 + 1e-16f), e1 / (s1 + 1e-16f));
    } else {
        float m0 = -INFINITY, m1 = -INFINITY;
        for (int base = j0; base < j1; base += 64) {
            int j = base + lane;
            float l0 = -INFINITY, l1 = -INFINITY;
            if (j < j1) {
                int s = csr_src[j];
                l0 = a_src[s * 2 + 0] + ad0;
                l1 = a_src[s * 2 + 1] + ad1;
                l0 = l0 > 0.f ? l0 : 0.2f * l0;
                l1 = l1 > 0.f ? l1 : 0.2f * l1;
            }
            m0 = fmaxf(m0, l0); m1 = fmaxf(m1, l1);
        }
#pragma unroll
        for (int off = 32; off > 0; off >>= 1) {
            m0 = fmaxf(m0, __shfl_xor(m0, off));
            m1 = fmaxf(m1, __shfl_xor(m1, off));
        }
        float s0 = 0.f, s1 = 0.f;
        for (int base = j0; base < j1; base += 64) {
            int j = base + lane;
            float e0 = 0.f, e1 = 0.f;
            if (j < j1) {
                int s = csr_src[j];
                float l0 = a_src[s * 2 + 0] + ad0;
                float l1 = a_src[s * 2 + 1] + ad1;
                l0 = l0 > 0.f ? l0 : 0.2f * l0;
                l1 = l1 > 0.f ? l1 : 0.2f * l1;
                e0 = expf(l0 - m0); e1 = expf(l1 - m1);
                alpha[j] = pack2bf(e0, e1);
            }
            s0 += e0; s1 += e1;
        }
#pragma unroll
        for (int off = 32; off > 0; off >>= 1) {
            s0 += __shfl_xor(s0, off);
            s1 += __shfl_xor(s1, off);
        }
        float r0 = 1.0f / (s0 + 1e-16f), r1 = 1.0f / (s1 + 1e-16f);
        for (int base = j0; base < j1; base += 64) {
            int j = base + lane;
            if (j < j1) {
                unsigned a = alpha[j];
                alpha[j] = pack2bf(lo_bf(a) * r0, hi_bf(a) * r1);
            }
        }
    }
}

// gather-accumulate with lane-preloaded indices + 4-deep row-load pipeline.
__global__ void k_gat_gather(const int* __restrict__ rowptr, const int* __restrict__ csr_src,
                             const unsigned* __restrict__ alpha,
                             const unsigned* __restrict__ xw32, float* __restrict__ h1) {
    int n = blockIdx.x * 4 + (threadIdx.x >> 6);
    int lane = threadIdx.x & 63;
    if (n >= NN) return;
    int j0 = rowptr[n], j1 = rowptr[n + 1];
    float acc0 = 0.f, acc1 = 0.f;
    bool lo = (lane < 32);
    for (int base = j0; base < j1; base += 64) {
        int cnt = min(64, j1 - base);
        int myj = base + lane;
        int sl = 0; unsigned al = 0;
        if (myj < j1) { sl = csr_src[myj]; al = alpha[myj]; }
        int e = 0;
        for (; e + 4 <= cnt; e += 4) {
            int s0 = __shfl(sl, e + 0), s1 = __shfl(sl, e + 1),
                s2 = __shfl(sl, e + 2), s3 = __shfl(sl, e + 3);
            unsigned b0 = __shfl(al, e + 0), b1 = __shfl(al, e + 1),
                     b2 = __shfl(al, e + 2), b3 = __shfl(al, e + 3);
            unsigned p0 = xw32[(size_t)s0 * 64 + lane];
            unsigned p1 = xw32[(size_t)s1 * 64 + lane];
            unsigned p2 = xw32[(size_t)s2 * 64 + lane];
            unsigned p3 = xw32[(size_t)s3 * 64 + lane];
            float w0 = lo ? lo_bf(b0) : hi_bf(b0);
            float w1 = lo ? lo_bf(b1) : hi_bf(b1);
            float w2 = lo ? lo_bf(b2) : hi_bf(b2);
            float w3 = lo ? lo_bf(b3) : hi_bf(b3);
            acc0 = fmaf(lo_bf(p0), w0, acc0); acc1 = fmaf(hi_bf(p0), w0, acc1);
            acc0 = fmaf(lo_bf(p1), w1, acc0); acc1 = fmaf(hi_bf(p1), w1, acc1);
            acc0 = fmaf(lo_bf(p2), w2, acc0); acc1 = fmaf(hi_bf(p2), w2, acc1);
            acc0 = fmaf(lo_bf(p3), w3, acc0); acc1 = fmaf(hi_bf(p3), w3, acc1);
        }
        for (; e < cnt; e++) {
            int s = __shfl(sl, e); unsigned b = __shfl(al, e);
            unsigned p = xw32[(size_t)s * 64 + lane];
            float w = lo ? lo_bf(b) : hi_bf(b);
            acc0 = fmaf(lo_bf(p), w, acc0);
            acc1 = fmaf(hi_bf(p), w, acc1);
        }
    }
    float2 o; o.x = acc0; o.y = acc1;
    *(float2*)&h1[(size_t)n * F1 + 2 * lane] = o;
}

// =================== BatchNorm ===================
__global__ void k_bn_stats(const float* __restrict__ h, int nfeat, float* __restrict__ sums) {
    int f = threadIdx.x;                       // blockDim.x == nfeat
    int rows = (NN + gridDim.x - 1) / gridDim.x;
    int r0 = blockIdx.x * rows;
    int r1 = min(NN, r0 + rows);
    float s = 0.f, ss = 0.f;
    for (int r = r0; r < r1; r++) {
        float v = h[r * nfeat + f];
        s += v; ss += v * v;
    }
    atomicAdd(&sums[f], s);
    atomicAdd(&sums[nfeat + f], ss);
}

// per-feature affine coefficients: co[f] = scale, co[nfeat+f] = shift
__global__ void k_bnco(const float* __restrict__ sums, const float* __restrict__ g,
                       const float* __restrict__ b, int nfeat, float* __restrict__ co) {
    int f = threadIdx.x;
    if (f >= nfeat) return;
    float m = sums[f] * (1.0f / NN);
    float var = sums[nfeat + f] * (1.0f / NN) - m * m;
    float s = rsqrtf(var + 1e-5f) * g[f];
    co[f] = s;
    co[nfeat + f] = b[f] - m * s;
}

__device__ __forceinline__ float elu_aff(float raw, float sc, float sh) {
    float z = fmaf(raw, sc, sh);
    return z > 0.f ? z : expm1f(z);
}

// =================== SAGE ===================
// u (bf16) = elu(bn1(h1raw)) @ wl ; v (f32) = elu(bn1(h1raw)) @ wr  (BN1+ELU fused)
__global__ void k_sage_dualgemm(const float* __restrict__ h1raw, const float* __restrict__ co1,
                                const float* __restrict__ wl, const float* __restrict__ wr,
                                ushort* __restrict__ u_bf, float* __restrict__ v) {
    __shared__ float swl[F1 * F2];   // 32 KB
    __shared__ float swr[F1 * F2];   // 32 KB
    int t = threadIdx.x;
    const float4* wl4 = (const float4*)wl;
    const float4* wr4 = (const float4*)wr;
    float4* swl4 = (float4*)swl;
    float4* swr4 = (float4*)swr;
    for (int i = t; i < F1 * F2 / 4; i += 256) { swl4[i] = wl4[i]; swr4[i] = wr4[i]; }
    __syncthreads();
    int w = t >> 6, j = t & 63;
    int row0 = blockIdx.x * GROWS + w * 8;
    float accu[8] = {0.f, 0.f, 0.f, 0.f, 0.f, 0.f, 0.f, 0.f};
    float accv[8] = {0.f, 0.f, 0.f, 0.f, 0.f, 0.f, 0.f, 0.f};
    for (int k = 0; k < F1; k += 4) {
        float sc0 = co1[k], sc1 = co1[k + 1], sc2 = co1[k + 2], sc3 = co1[k + 3];
        float sh0 = co1[F1 + k], sh1 = co1[F1 + k + 1],
              sh2 = co1[F1 + k + 2], sh3 = co1[F1 + k + 3];
        float4 a[8];
#pragma unroll
        for (int r = 0; r < 8; r++) {
            a[r] = *(const float4*)&h1raw[(size_t)(row0 + r) * F1 + k];
            a[r].x = elu_aff(a[r].x, sc0, sh0);
            a[r].y = elu_aff(a[r].y, sc1, sh1);
            a[r].z = elu_aff(a[r].z, sc2, sh2);
            a[r].w = elu_aff(a[r].w, sc3, sh3);
        }
#pragma unroll
        for (int kk = 0; kk < 4; kk++) {
            float wlj = swl[(k + kk) * F2 + j];
            float wrj = swr[(k + kk) * F2 + j];
#pragma unroll
            for (int r = 0; r < 8; r++) {
                float av = (&a[r].x)[kk];
                accu[r] += av * wlj;
                accv[r] += av * wrj;
            }
        }
    }
#pragma unroll
    for (int r = 0; r < 8; r++) {
        u_bf[(size_t)(row0 + r) * F2 + j] = f2bf(accu[r]);
        v[(size_t)(row0 + r) * F2 + j] = accv[r];
    }
}

// h2raw[n] = mean-gather(u_bf16) + v[n] + bl
__global__ void k_sage_gather2(const int* __restrict__ rowptr, const int* __restrict__ csr_src,
                               const ushort* __restrict__ u_bf, const float* __restrict__ v,
                               const float* __restrict__ bl, float* __restrict__ h2) {
    int n = blockIdx.x * 4 + (threadIdx.x >> 6);
    int lane = threadIdx.x & 63;
    if (n >= NN) return;
    int j0 = rowptr[n], j1 = rowptr[n + 1];
    float a = 0.f;
    for (int base = j0; base < j1; base += 64) {
        int cnt = min(64, j1 - base);
        int myj = base + lane;
        int sl = (myj < j1) ? csr_src[myj] : 0;
        int e = 0;
        for (; e + 4 <= cnt; e += 4) {
            int s0 = __shfl(sl, e + 0), s1 = __shfl(sl, e + 1),
                s2 = __shfl(sl, e + 2), s3 = __shfl(sl, e + 3);
            float t0 = bf2f(u_bf[(size_t)s0 * F2 + lane]);
            float t1 = bf2f(u_bf[(size_t)s1 * F2 + lane]);
            float t2 = bf2f(u_bf[(size_t)s2 * F2 + lane]);
            float t3 = bf2f(u_bf[(size_t)s3 * F2 + lane]);
            a += (t0 + t1) + (t2 + t3);
        }
        for (; e < cnt; e++) {
            int s = __shfl(sl, e);
            a += bf2f(u_bf[(size_t)s * F2 + lane]);
        }
    }
    float inv = 1.0f / fmaxf((float)(j1 - j0), 1.0f);
    h2[(size_t)n * F2 + lane] = a * inv + v[(size_t)n * F2 + lane] + bl[lane];
}

__global__ void k_dinv(const int* __restrict__ degi, float* __restrict__ dinv) {
    int i = blockIdx.x * blockDim.x + threadIdx.x;
    if (i < NN) dinv[i] = rsqrtf((float)degi[i] + 1.0f);
}

// =================== GCN ===================
// hwd (bf16) = (elu(bn2(h2raw)) @ gcn_w) * dinv[row]  (BN2+ELU fused)
__global__ void k_gcn_gemm(const float* __restrict__ h2raw, const float* __restrict__ co2,
                           const float* __restrict__ wmat, const float* __restrict__ dinv,
                           ushort* __restrict__ hwd_bf) {
    __shared__ float sw[F2 * F2];    // 16 KB
    int t = threadIdx.x;
    const float4* w4 = (const float4*)wmat;
    float4* sw4 = (float4*)sw;
    for (int i = t; i < F2 * F2 / 4; i += 256) sw4[i] = w4[i];
    __syncthreads();
    int w = t >> 6, j = t & 63;
    int row0 = blockIdx.x * GROWS + w * 8;
    float acc[8] = {0.f, 0.f, 0.f, 0.f, 0.f, 0.f, 0.f, 0.f};
    for (int k = 0; k < F2; k += 4) {
        float sc0 = co2[k], sc1 = co2[k + 1], sc2 = co2[k + 2], sc3 = co2[k + 3];
        float sh0 = co2[F2 + k], sh1 = co2[F2 + k + 1],
              sh2 = co2[F2 + k + 2], sh3 = co2[F2 + k + 3];
        float4 a[8];
#pragma unroll
        for (int r = 0; r < 8; r++) {
            a[r] = *(const float4*)&h2raw[(size_t)(row0 + r) * F2 + k];
            a[r].x = elu_aff(a[r].x, sc0, sh0);
            a[r].y = elu_aff(a[r].y, sc1, sh1);
            a[r].z = elu_aff(a[r].z, sc2, sh2);
            a[r].w = elu_aff(a[r].w, sc3, sh3);
        }
#pragma unroll
        for (int kk = 0; kk < 4; kk++) {
            float wkj = sw[(k + kk) * F2 + j];
#pragma unroll
            for (int r = 0; r < 8; r++)
                acc[r] += (&a[r].x)[kk] * wkj;
        }
    }
#pragma unroll
    for (int r = 0; r < 8; r++)
        hwd_bf[(size_t)(row0 + r) * F2 + j] = f2bf(acc[r] * dinv[row0 + r]);
}

// h3 = dinv[n]*(sum_src hwd[s] + hwd[n]) + gb
__global__ void k_gcn_gather(const int* __restrict__ rowptr, const int* __restrict__ csr_src,
                             const ushort* __restrict__ hwd_bf, const float* __restrict__ dinv,
                             const float* __restrict__ gb, float* __restrict__ h3) {
    int n = blockIdx.x * 4 + (threadIdx.x >> 6);
    int lane = threadIdx.x & 63;
    if (n >= NN) return;
    int j0 = rowptr[n], j1 = rowptr[n + 1];
    float acc = 0.f;
    for (int base = j0; base < j1; base += 64) {
        int cnt = min(64, j1 - base);
        int myj = base + lane;
        int sl = (myj < j1) ? csr_src[myj] : 0;
        int e = 0;
        for (; e + 4 <= cnt; e += 4) {
            int s0 = __shfl(sl, e + 0), s1 = __shfl(sl, e + 1),
                s2 = __shfl(sl, e + 2), s3 = __shfl(sl, e + 3);
            float t0 = bf2f(hwd_bf[(size_t)s0 * F2 + lane]);
            float t1 = bf2f(hwd_bf[(size_t)s1 * F2 + lane]);
            float t2 = bf2f(hwd_bf[(size_t)s2 * F2 + lane]);
            float t3 = bf2f(hwd_bf[(size_t)s3 * F2 + lane]);
            acc += (t0 + t1) + (t2 + t3);
        }
        for (; e < cnt; e++) {
            int s = __shfl(sl, e);
            acc += bf2f(hwd_bf[(size_t)s * F2 + lane]);
        }
    }
    float di = dinv[n];
    acc += bf2f(hwd_bf[(size_t)n * F2 + lane]);
    h3[(size_t)n * F2 + lane] = acc * di + gb[lane];
}

// =================== fused BN3-apply + ELU + segmented pool ===================
__global__ void k_bn3_pool(const float* __restrict__ h3raw, const float* __restrict__ sums,
                           const float* __restrict__ g3, const float* __restrict__ b3,
                           const int* __restrict__ batch, float* __restrict__ psum,
                           unsigned* __restrict__ pmax, float* __restrict__ cnt) {
    int lane = threadIdx.x;   // 64 threads = one wave, lane = feature
    int rows = (NN + gridDim.x - 1) / gridDim.x;
    int r0 = blockIdx.x * rows;
    int r1 = min(NN, r0 + rows);
    if (r0 >= r1) return;
    float m = sums[lane] * (1.0f / NN);
    float var = sums[F2 + lane] * (1.0f / NN) - m * m;
    float sc = rsqrtf(var + 1e-5f) * g3[lane];
    float bb = b3[lane];
    int curg = batch[r0];
    float ls = 0.f, lm = -INFINITY;
    int run = 0;
    for (int r = r0; r < r1; r++) {
        int gg = batch[r];
        if (gg != curg) {
            atomicAdd(&psum[curg * F2 + lane], ls);
            atomicMax(&pmax[curg * F2 + lane], enc_f(lm));
            if (lane == 0) atomicAdd(&cnt[curg], (float)run);
            curg = gg; ls = 0.f; lm = -INFINITY; run = 0;
        }
        float v = (h3raw[r * F2 + lane] - m) * sc + bb;
        v = v > 0.f ? v : expm1f(v);
        ls += v; lm = fmaxf(lm, v); run++;
    }
    atomicAdd(&psum[curg * F2 + lane], ls);
    atomicMax(&pmax[curg * F2 + lane], enc_f(lm));
    if (lane == 0) atomicAdd(&cnt[curg], (float)run);
}

// =================== classifier ===================
__global__ void k_cls(const float* __restrict__ psum, const unsigned* __restrict__ pmax,
                      const float* __restrict__ cnt, const float* __restrict__ w1,
                      const float* __restrict__ b1, const float* __restrict__ w2,
                      const float* __restrict__ b2, float* __restrict__ out) {
    int g = blockIdx.x;
    int j = threadIdx.x;  // 64 threads
    __shared__ float z[2 * F2];
    __shared__ float hid[F2];
    float c = fmaxf(cnt[g], 1.0f);
    z[j] = psum[g * F2 + j] / c;
    float mv = dec_f(pmax[g * F2 + j]);
    z[F2 + j] = isfinite(mv) ? mv : 0.f;
    __syncthreads();
    float acc = b1[j];
#pragma unroll 8
    for (int k = 0; k < 2 * F2; k++) acc += z[k] * w1[k * F2 + j];
    hid[j] = fmaxf(acc, 0.f);
    __syncthreads();
    if (j < NCLS) {
        float o = b2[j];
#pragma unroll 8
        for (int k = 0; k < F2; k++) o += hid[k] * w2[k * NCLS + j];
        out[g * NCLS + j] = o;
    }
}

extern "C" void kernel_launch(void* const* d_in, const int* in_sizes, int n_in,
                              void* d_out, int out_size, void* d_ws, size_t ws_size,
                              hipStream_t stream) {
    const float* x       = (const float*)d_in[0];
    const int*   ei      = (const int*)d_in[1];
    const int*   batch   = (const int*)d_in[2];
    const float* gat_w   = (const float*)d_in[3];
    const float* att_src = (const float*)d_in[4];
    const float* att_dst = (const float*)d_in[5];
    // d_in[6] gat_b: cancels inside BN1 (constant shift removed by mean subtraction)
    const float* bn1_g   = (const float*)d_in[7];
    const float* bn1_b   = (const float*)d_in[8];
    const float* sage_wl = (const float*)d_in[9];
    const float* sage_bl = (const float*)d_in[10];
    const float* sage_wr = (const float*)d_in[11];
    const float* bn2_g   = (const float*)d_in[12];
    const float* bn2_b   = (const float*)d_in[13];
    const float* gcn_w   = (const float*)d_in[14];
    const float* gcn_b   = (const float*)d_in[15];
    const float* bn3_g   = (const float*)d_in[16];
    const float* bn3_b   = (const float*)d_in[17];
    const float* w1      = (const float*)d_in[18];
    const float* b1      = (const float*)d_in[19];
    const float* w2      = (const float*)d_in[20];
    const float* b2      = (const float*)d_in[21];
    float* out = (float*)d_out;

    float* ws = (float*)d_ws;
    // workspace layout (4-byte units)
    size_t o_A    = 0;                        // NN*F1 floats region, aliased (see below)
    size_t o_h1   = o_A   + (size_t)NN * F1;  // NN*F1 f32: GAT output (raw, pre-BN1)
    size_t o_h2   = o_h1  + (size_t)NN * F1;  // NN*F2 f32 (raw, pre-BN2)
    size_t o_csr  = o_h2  + (size_t)NN * F2;  // E ints (csr_src)
    size_t o_rp   = o_csr + (size_t)NE;       // N+1 ints (rowptr)
    size_t o_deg  = o_rp  + (size_t)(NN + 1); // N ints (degi)
    size_t o_bs   = o_deg + (size_t)NN;       // 512 ints (block sums)
    size_t o_asrc = o_bs  + 512;              // N*2
    size_t o_adst = o_asrc + (size_t)NN * 2;  // N*2
    size_t o_dinv = o_adst + (size_t)NN * 2;  // N
    size_t o_sums = o_dinv + (size_t)NN;      // 256
    size_t o_co   = o_sums + 256;             // 256 (bn affine coefficients)
    size_t o_psum = o_co   + 256;             // G*F2
    size_t o_pmax = o_psum + (size_t)NG * F2; // G*F2
    size_t o_cnt  = o_pmax + (size_t)NG * F2; // G
    size_t o_alp  = o_cnt + (size_t)NG;       // E uints (packed 2xbf16 alpha)

    float* A    = ws + o_A;
    float* h1   = ws + o_h1;
    float* h2   = ws + o_h2;
    int* csr_src = (int*)(ws + o_csr);
    int* rowptr  = (int*)(ws + o_rp);
    int* degi    = (int*)(ws + o_deg);
    int* bsum    = (int*)(ws + o_bs);
    float* asr  = ws + o_asrc;
    float* ads  = ws + o_adst;
    float* dinv = ws + o_dinv;
    float* sums = ws + o_sums;
    float* co   = ws + o_co;
    float* psum = ws + o_psum;
    unsigned* pmax = (unsigned*)(ws + o_pmax);
    float* cnt  = ws + o_cnt;
    unsigned* alpha = (unsigned*)(ws + o_alp);

    // region-A role aliases (lifetimes disjoint):
    unsigned* staged = (unsigned*)A;                    // CSR build: NE entries (6.4 MB)
    int*    ghist  = (int*)(A + 2 * 1024 * 1024);       // CSR build: NCHUNK*NBUCK ints
    ushort* xw_bf  = (ushort*)A;                        // GAT: NN*F1 bf16 (25.6 MB)
    ushort* u_bf   = (ushort*)A;                        // SAGE: NN*F2 bf16 (xw dead)
    float*  vmat   = A + (size_t)NN * F2 / 2;           // SAGE: NN*F2 f32
    ushort* hwd_bf = (ushort*)A;                        // GCN: NN*F2 bf16 (u dead)
    float*  h3     = A + (size_t)NN * F2 / 2;           // GCN out: NN*F2 f32 (v dead)

    // ---- CSR build: count + node scan, then chunk-major radix ----
    hipMemsetAsync(degi, 0, sizeof(int) * NN, stream);
    k_count<<<(NE + 255) / 256, 256, 0, stream>>>(ei, degi);
    k_scan1<<<NB_SCAN, 256, 0, stream>>>(degi, rowptr, bsum);
    k_scan2<<<1, 512, 0, stream>>>(bsum, NB_SCAN);
    k_scan3<<<NB_SCAN, 256, 0, stream>>>(rowptr, bsum);
    k_hist<<<NCHUNK, 256, 0, stream>>>(ei, ghist);
    k_chunkscan<<<(NBUCK + 255) / 256, 256, 0, stream>>>(ghist, rowptr);
    k_scatter2<<<NCHUNK, 256, 0, stream>>>(ei, ghist, staged);
    k_bucket_sort<<<NBUCK, 256, 0, stream>>>(staged, rowptr, csr_src);

    // ---- GAT ----
    k_xw<<<NN, F1, 0, stream>>>(x, gat_w, att_src, att_dst, xw_bf, asr, ads);
    k_alpha<<<(NN + 3) / 4, 256, 0, stream>>>(rowptr, csr_src, asr, ads, alpha);
    k_gat_gather<<<(NN + 3) / 4, 256, 0, stream>>>(rowptr, csr_src, alpha,
                                                   (const unsigned*)xw_bf, h1);
    hipMemsetAsync(sums, 0, sizeof(float) * 256, stream);
    k_bn_stats<<<512, F1, 0, stream>>>(h1, F1, sums);
    k_bnco<<<1, F1, 0, stream>>>(sums, bn1_g, bn1_b, F1, co);

    // ---- SAGE: BN1+ELU fused into dual-GEMM, then bf16 mean-gather ----
    k_sage_dualgemm<<<NN / GROWS, 256, 0, stream>>>(h1, co, sage_wl, sage_wr, u_bf, vmat);
    k_sage_gather2<<<(NN + 3) / 4, 256, 0, stream>>>(rowptr, csr_src, u_bf, vmat, sage_bl, h2);
    hipMemsetAsync(sums, 0, sizeof(float) * 256, stream);
    k_bn_stats<<<512, F2, 0, stream>>>(h2, F2, sums);
    k_bnco<<<1, F2, 0, stream>>>(sums, bn2_g, bn2_b, F2, co);

    // ---- GCN: BN2+ELU fused into GEMM ----
    k_dinv<<<(NN + 255) / 256, 256, 0, stream>>>(degi, dinv);
    k_gcn_gemm<<<NN / GROWS, 256, 0, stream>>>(h2, co, gcn_w, dinv, hwd_bf);
    k_gcn_gather<<<(NN + 3) / 4, 256, 0, stream>>>(rowptr, csr_src, hwd_bf, dinv, gcn_b, h3);
    hipMemsetAsync(sums, 0, sizeof(float) * 256, stream);
    k_bn_stats<<<512, F2, 0, stream>>>(h3, F2, sums);

    // ---- fused BN3 + ELU + pooling, then classifier ----
    hipMemsetAsync(psum, 0, sizeof(float) * NG * F2, stream);
    hipMemsetAsync(cnt, 0, sizeof(float) * NG, stream);
    k_fill_u32<<<(NG * F2 + 255) / 256, 256, 0, stream>>>(pmax, ENC_NEG_INF, NG * F2);
    k_bn3_pool<<<512, F2, 0, stream>>>(h3, sums, bn3_g, bn3_b, batch, psum, pmax, cnt);
    k_cls<<<NG, F2, 0, stream>>>(psum, pmax, cnt, w1, b1, w2, b2, out);
}

// Round 12
// 872.203 us; speedup vs baseline: 1.5581x; 1.5581x over previous
//
#include <hip/hip_runtime.h>
#include <hip/hip_bf16.h>
#include <math.h>

#define NN 100000      // nodes
#define NE 1600000     // edges
#define NG 64          // graphs
#define F_IN 5
#define F1 128         // H*HID
#define F2 64          // HID
#define NCLS 4
#define NB_SCAN ((NN + 255) / 256)   // 391 blocks in node scan level 1
#define GROWS 32                     // rows per block in register-blocked GEMMs
#define NCHUNK 250                   // edge chunks (250 * 6400 = NE)
#define CH_E 6400                    // edges per chunk
#define NBUCK ((NN + 255) / 256)     // 391 dst buckets of 256 nodes
#define CAPB 6144                    // bucket capacity in LDS sort (avg 4096, 32 sigma margin)

typedef unsigned short ushort;

// ---------- bf16 helpers (round-to-nearest-even pack) ----------
__device__ __forceinline__ ushort f2bf(float f) {
    unsigned u = __float_as_uint(f);
    u = (u + 0x7fffu + ((u >> 16) & 1u)) >> 16;
    return (ushort)u;
}
__device__ __forceinline__ float bf2f(ushort h) {
    return __uint_as_float(((unsigned)h) << 16);
}
__device__ __forceinline__ unsigned pack2bf(float a, float b) {
    return (unsigned)f2bf(a) | ((unsigned)f2bf(b) << 16);
}
__device__ __forceinline__ float lo_bf(unsigned p) { return __uint_as_float(p << 16); }
__device__ __forceinline__ float hi_bf(unsigned p) { return __uint_as_float(p & 0xffff0000u); }

// ---------- order-preserving float<->uint encoding for atomicMax ----------
__device__ __forceinline__ unsigned enc_f(float f) {
    unsigned b = __float_as_uint(f);
    return (b & 0x80000000u) ? ~b : (b | 0x80000000u);
}
__device__ __forceinline__ float dec_f(unsigned k) {
    unsigned b = (k & 0x80000000u) ? (k ^ 0x80000000u) : ~k;
    return __uint_as_float(b);
}
#define ENC_NEG_INF 0x007FFFFFu   // enc_f(-inf)

__global__ void k_fill_u32(unsigned* p, unsigned v, int n) {
    int i = blockIdx.x * blockDim.x + threadIdx.x;
    if (i < n) p[i] = v;
}

// =================== CSR build (chunk-major two-level counting sort) ===================
__global__ void k_count(const int* __restrict__ ei, int* __restrict__ degi) {
    int e = blockIdx.x * blockDim.x + threadIdx.x;
    if (e < NE) atomicAdd(&degi[ei[NE + e]], 1);
}

__global__ void k_scan1(const int* __restrict__ degi, int* __restrict__ rowptr,
                        int* __restrict__ bsum) {
    __shared__ int sh[256];
    int i = blockIdx.x * 256 + threadIdx.x;
    int v = (i < NN) ? degi[i] : 0;
    sh[threadIdx.x] = v;
    __syncthreads();
    for (int off = 1; off < 256; off <<= 1) {
        int t = (threadIdx.x >= off) ? sh[threadIdx.x - off] : 0;
        __syncthreads();
        sh[threadIdx.x] += t;
        __syncthreads();
    }
    if (i < NN) rowptr[i] = sh[threadIdx.x] - v;   // exclusive, block-local
    if (threadIdx.x == 255) bsum[blockIdx.x] = sh[255];
}

__global__ void k_scan2(int* __restrict__ bsum, int nb) {
    __shared__ int sh[512];
    int v = (threadIdx.x < nb) ? bsum[threadIdx.x] : 0;
    sh[threadIdx.x] = v;
    __syncthreads();
    for (int off = 1; off < 512; off <<= 1) {
        int t = (threadIdx.x >= off) ? sh[threadIdx.x - off] : 0;
        __syncthreads();
        sh[threadIdx.x] += t;
        __syncthreads();
    }
    if (threadIdx.x < nb) bsum[threadIdx.x] = sh[threadIdx.x] - v;   // exclusive
}

__global__ void k_scan3(int* __restrict__ rowptr, const int* __restrict__ bsum) {
    int i = blockIdx.x * 256 + threadIdx.x;
    if (i == 0) rowptr[NN] = NE;
    if (i >= NN) return;
    rowptr[i] += bsum[blockIdx.x];
}

// pass 1: per-chunk histogram over 391 dst buckets
__global__ void k_hist(const int* __restrict__ ei, int* __restrict__ ghist) {
    __shared__ int lh[NBUCK];
    int c = blockIdx.x, t = threadIdx.x;
    for (int b = t; b < NBUCK; b += 256) lh[b] = 0;
    __syncthreads();
    int e0 = c * CH_E;
#pragma unroll
    for (int i = 0; i < CH_E / 256; i++) {
        int d = ei[NE + e0 + t + i * 256];
        atomicAdd(&lh[d >> 8], 1);
    }
    __syncthreads();
    for (int b = t; b < NBUCK; b += 256) ghist[c * NBUCK + b] = lh[b];
}

// pass 2: per-bucket serial prefix over chunks (in place: ghist -> offsets)
__global__ void k_chunkscan(int* __restrict__ ghist, const int* __restrict__ rowptr) {
    int b = blockIdx.x * blockDim.x + threadIdx.x;
    if (b >= NBUCK) return;
    int run = rowptr[b * 256];           // bucket base in csr order
    for (int c = 0; c < NCHUNK; c++) {
        int h = ghist[c * NBUCK + b];
        ghist[c * NBUCK + b] = run;
        run += h;
    }
}

// pass 3: scatter into bucket-major staged array (packed (dlow<<17)|src)
__global__ void k_scatter2(const int* __restrict__ ei, const int* __restrict__ ghist,
                           unsigned* __restrict__ staged) {
    __shared__ int lcur[NBUCK];
    int c = blockIdx.x, t = threadIdx.x;
    for (int b = t; b < NBUCK; b += 256) lcur[b] = ghist[c * NBUCK + b];
    __syncthreads();
    int e0 = c * CH_E;
#pragma unroll
    for (int i = 0; i < CH_E / 256; i++) {
        int e = e0 + t + i * 256;
        int s = ei[e];
        int d = ei[NE + e];
        int pos = atomicAdd(&lcur[d >> 8], 1);
        staged[pos] = (((unsigned)(d & 255)) << 17) | (unsigned)s;
    }
}

// pass 4: per-bucket LDS counting sort by low 8 dst bits -> coalesced csr_src
__global__ void k_bucket_sort(const unsigned* __restrict__ staged,
                              const int* __restrict__ rowptr, int* __restrict__ csr_src) {
    __shared__ unsigned ein[CAPB];
    __shared__ unsigned sout[CAPB];
    __shared__ int lcur[256];
    int b = blockIdx.x, t = threadIdx.x;
    int n0 = b * 256;
    int nend = min(n0 + 256, NN);
    int nn = nend - n0;
    int g0 = rowptr[n0];
    int m = rowptr[nend] - g0;
    if (t < nn) lcur[t] = rowptr[n0 + t] - g0;
    __syncthreads();
    if (m <= CAPB) {
        for (int i = t; i < m; i += 256) ein[i] = staged[g0 + i];
        __syncthreads();
        for (int i = t; i < m; i += 256) {
            unsigned u = ein[i];
            int pos = atomicAdd(&lcur[u >> 17], 1);
            sout[pos] = u & 0x1FFFFu;
        }
        __syncthreads();
        for (int i = t; i < m; i += 256) csr_src[g0 + i] = (int)sout[i];
    } else {
        // statistically unreachable fallback (bucket > CAPB)
        for (int i = t; i < m; i += 256) {
            unsigned u = staged[g0 + i];
            int pos = atomicAdd(&lcur[u >> 17], 1);
            csr_src[g0 + pos] = (int)(u & 0x1FFFFu);
        }
    }
}

// =================== GAT ===================
// xw (bf16) = x @ gat_w ; a_src/a_dst per-node attention logits
__global__ void k_xw(const float* __restrict__ x, const float* __restrict__ gw,
                     const float* __restrict__ aw_src, const float* __restrict__ aw_dst,
                     ushort* __restrict__ xw_bf, float* __restrict__ a_src,
                     float* __restrict__ a_dst) {
    int n = blockIdx.x;
    int f = threadIdx.x;                 // 128 threads, f = h*64+c
    __shared__ float w[F_IN * F1];
    __shared__ float xs[F_IN];
    for (int i = f; i < F_IN * F1; i += F1) w[i] = gw[i];
    if (f < F_IN) xs[f] = x[n * F_IN + f];
    __syncthreads();
    float acc = 0.f;
#pragma unroll
    for (int i = 0; i < F_IN; i++) acc += xs[i] * w[i * F1 + f];
    xw_bf[n * F1 + f] = f2bf(acc);
    int h = f >> 6, lane = f & 63;
    float p = acc * aw_src[f];
    float q = acc * aw_dst[f];
#pragma unroll
    for (int off = 32; off > 0; off >>= 1) {
        p += __shfl_down(p, off);
        q += __shfl_down(q, off);
    }
    if (lane == 0) { a_src[n * 2 + h] = p; a_dst[n * 2 + h] = q; }
}

// per-node softmax over incoming edges, ONE WAVE per node, lane-per-edge.
__global__ void k_alpha(const int* __restrict__ rowptr, const int* __restrict__ csr_src,
                        const float* __restrict__ a_src, const float* __restrict__ a_dst,
                        unsigned* __restrict__ alpha) {
    int n = blockIdx.x * 4 + (threadIdx.x >> 6);
    int lane = threadIdx.x & 63;
    if (n >= NN) return;
    int j0 = rowptr[n], j1 = rowptr[n + 1];
    int deg = j1 - j0;
    if (deg <= 0) return;
    float ad0 = a_dst[n * 2 + 0], ad1 = a_dst[n * 2 + 1];
    if (deg <= 64) {
        int j = j0 + lane;
        float l0 = -INFINITY, l1 = -INFINITY;
        if (lane < deg) {
            int s = csr_src[j];
            l0 = a_src[s * 2 + 0] + ad0;
            l1 = a_src[s * 2 + 1] + ad1;
            l0 = l0 > 0.f ? l0 : 0.2f * l0;
            l1 = l1 > 0.f ? l1 : 0.2f * l1;
        }
        float m0 = l0, m1 = l1;
#pragma unroll
        for (int off = 32; off > 0; off >>= 1) {
            m0 = fmaxf(m0, __shfl_xor(m0, off));
            m1 = fmaxf(m1, __shfl_xor(m1, off));
        }
        float e0 = 0.f, e1 = 0.f;
        if (lane < deg) { e0 = expf(l0 - m0); e1 = expf(l1 - m1); }
        float s0 = e0, s1 = e1;
#pragma unroll
        for (int off = 32; off > 0; off >>= 1) {
            s0 += __shfl_xor(s0, off);
            s1 += __shfl_xor(s1, off);
        }
        if (lane < deg)
            alpha[j] = pack2bf(e0 / (s0 + 1e-16f), e1 / (s1 + 1e-16f));
    } else {
        float m0 = -INFINITY, m1 = -INFINITY;
        for (int base = j0; base < j1; base += 64) {
            int j = base + lane;
            float l0 = -INFINITY, l1 = -INFINITY;
            if (j < j1) {
                int s = csr_src[j];
                l0 = a_src[s * 2 + 0] + ad0;
                l1 = a_src[s * 2 + 1] + ad1;
                l0 = l0 > 0.f ? l0 : 0.2f * l0;
                l1 = l1 > 0.f ? l1 : 0.2f * l1;
            }
            m0 = fmaxf(m0, l0); m1 = fmaxf(m1, l1);
        }
#pragma unroll
        for (int off = 32; off > 0; off >>= 1) {
            m0 = fmaxf(m0, __shfl_xor(m0, off));
            m1 = fmaxf(m1, __shfl_xor(m1, off));
        }
        float s0 = 0.f, s1 = 0.f;
        for (int base = j0; base < j1; base += 64) {
            int j = base + lane;
            float e0 = 0.f, e1 = 0.f;
            if (j < j1) {
                int s = csr_src[j];
                float l0 = a_src[s * 2 + 0] + ad0;
                float l1 = a_src[s * 2 + 1] + ad1;
                l0 = l0 > 0.f ? l0 : 0.2f * l0;
                l1 = l1 > 0.f ? l1 : 0.2f * l1;
                e0 = expf(l0 - m0); e1 = expf(l1 - m1);
                alpha[j] = pack2bf(e0, e1);
            }
            s0 += e0; s1 += e1;
        }
#pragma unroll
        for (int off = 32; off > 0; off >>= 1) {
            s0 += __shfl_xor(s0, off);
            s1 += __shfl_xor(s1, off);
        }
        float r0 = 1.0f / (s0 + 1e-16f), r1 = 1.0f / (s1 + 1e-16f);
        for (int base = j0; base < j1; base += 64) {
            int j = base + lane;
            if (j < j1) {
                unsigned a = alpha[j];
                alpha[j] = pack2bf(lo_bf(a) * r0, hi_bf(a) * r1);
            }
        }
    }
}

// gather-accumulate with lane-preloaded indices + 4-deep row-load pipeline.
__global__ void k_gat_gather(const int* __restrict__ rowptr, const int* __restrict__ csr_src,
                             const unsigned* __restrict__ alpha,
                             const unsigned* __restrict__ xw32, float* __restrict__ h1) {
    int n = blockIdx.x * 4 + (threadIdx.x >> 6);
    int lane = threadIdx.x & 63;
    if (n >= NN) return;
    int j0 = rowptr[n], j1 = rowptr[n + 1];
    float acc0 = 0.f, acc1 = 0.f;
    bool lo = (lane < 32);
    for (int base = j0; base < j1; base += 64) {
        int cnt = min(64, j1 - base);
        int myj = base + lane;
        int sl = 0; unsigned al = 0;
        if (myj < j1) { sl = csr_src[myj]; al = alpha[myj]; }
        int e = 0;
        for (; e + 4 <= cnt; e += 4) {
            int s0 = __shfl(sl, e + 0), s1 = __shfl(sl, e + 1),
                s2 = __shfl(sl, e + 2), s3 = __shfl(sl, e + 3);
            unsigned b0 = __shfl(al, e + 0), b1 = __shfl(al, e + 1),
                     b2 = __shfl(al, e + 2), b3 = __shfl(al, e + 3);
            unsigned p0 = xw32[(size_t)s0 * 64 + lane];
            unsigned p1 = xw32[(size_t)s1 * 64 + lane];
            unsigned p2 = xw32[(size_t)s2 * 64 + lane];
            unsigned p3 = xw32[(size_t)s3 * 64 + lane];
            float w0 = lo ? lo_bf(b0) : hi_bf(b0);
            float w1 = lo ? lo_bf(b1) : hi_bf(b1);
            float w2 = lo ? lo_bf(b2) : hi_bf(b2);
            float w3 = lo ? lo_bf(b3) : hi_bf(b3);
            acc0 = fmaf(lo_bf(p0), w0, acc0); acc1 = fmaf(hi_bf(p0), w0, acc1);
            acc0 = fmaf(lo_bf(p1), w1, acc0); acc1 = fmaf(hi_bf(p1), w1, acc1);
            acc0 = fmaf(lo_bf(p2), w2, acc0); acc1 = fmaf(hi_bf(p2), w2, acc1);
            acc0 = fmaf(lo_bf(p3), w3, acc0); acc1 = fmaf(hi_bf(p3), w3, acc1);
        }
        for (; e < cnt; e++) {
            int s = __shfl(sl, e); unsigned b = __shfl(al, e);
            unsigned p = xw32[(size_t)s * 64 + lane];
            float w = lo ? lo_bf(b) : hi_bf(b);
            acc0 = fmaf(lo_bf(p), w, acc0);
            acc1 = fmaf(hi_bf(p), w, acc1);
        }
    }
    float2 o; o.x = acc0; o.y = acc1;
    *(float2*)&h1[(size_t)n * F1 + 2 * lane] = o;
}

// =================== BatchNorm ===================
__global__ void k_bn_stats(const float* __restrict__ h, int nfeat, float* __restrict__ sums) {
    int f = threadIdx.x;                       // blockDim.x == nfeat
    int rows = (NN + gridDim.x - 1) / gridDim.x;
    int r0 = blockIdx.x * rows;
    int r1 = min(NN, r0 + rows);
    float s = 0.f, ss = 0.f;
    for (int r = r0; r < r1; r++) {
        float v = h[r * nfeat + f];
        s += v; ss += v * v;
    }
    atomicAdd(&sums[f], s);
    atomicAdd(&sums[nfeat + f], ss);
}

__global__ void k_bn_apply(float* __restrict__ h, const float* __restrict__ sums,
                           const float* __restrict__ g, const float* __restrict__ b,
                           int nfeat, int total) {
    int i = blockIdx.x * blockDim.x + threadIdx.x;
    if (i >= total) return;
    int f = i & (nfeat - 1);
    float m = sums[f] * (1.0f / NN);
    float var = sums[nfeat + f] * (1.0f / NN) - m * m;
    float v = (h[i] - m) * rsqrtf(var + 1e-5f) * g[f] + b[f];
    h[i] = v > 0.f ? v : expm1f(v);
}

// =================== SAGE ===================
// u (bf16) = h1 @ wl ; v (f32) = h1 @ wr  — register-blocked dual GEMM (pre-activated h1).
__global__ void k_sage_dualgemm(const float* __restrict__ h1,
                                const float* __restrict__ wl, const float* __restrict__ wr,
                                ushort* __restrict__ u_bf, float* __restrict__ v) {
    __shared__ float swl[F1 * F2];   // 32 KB
    __shared__ float swr[F1 * F2];   // 32 KB
    int t = threadIdx.x;
    const float4* wl4 = (const float4*)wl;
    const float4* wr4 = (const float4*)wr;
    float4* swl4 = (float4*)swl;
    float4* swr4 = (float4*)swr;
    for (int i = t; i < F1 * F2 / 4; i += 256) { swl4[i] = wl4[i]; swr4[i] = wr4[i]; }
    __syncthreads();
    int w = t >> 6, j = t & 63;
    int row0 = blockIdx.x * GROWS + w * 8;
    float accu[8] = {0.f, 0.f, 0.f, 0.f, 0.f, 0.f, 0.f, 0.f};
    float accv[8] = {0.f, 0.f, 0.f, 0.f, 0.f, 0.f, 0.f, 0.f};
    for (int k = 0; k < F1; k += 4) {
        float4 a[8];
#pragma unroll
        for (int r = 0; r < 8; r++)
            a[r] = *(const float4*)&h1[(size_t)(row0 + r) * F1 + k];
#pragma unroll
        for (int kk = 0; kk < 4; kk++) {
            float wlj = swl[(k + kk) * F2 + j];
            float wrj = swr[(k + kk) * F2 + j];
#pragma unroll
            for (int r = 0; r < 8; r++) {
                float av = (&a[r].x)[kk];
                accu[r] += av * wlj;
                accv[r] += av * wrj;
            }
        }
    }
#pragma unroll
    for (int r = 0; r < 8; r++) {
        u_bf[(size_t)(row0 + r) * F2 + j] = f2bf(accu[r]);
        v[(size_t)(row0 + r) * F2 + j] = accv[r];
    }
}

// h2raw[n] = mean-gather(u_bf16) + v[n] + bl
__global__ void k_sage_gather2(const int* __restrict__ rowptr, const int* __restrict__ csr_src,
                               const ushort* __restrict__ u_bf, const float* __restrict__ v,
                               const float* __restrict__ bl, float* __restrict__ h2) {
    int n = blockIdx.x * 4 + (threadIdx.x >> 6);
    int lane = threadIdx.x & 63;
    if (n >= NN) return;
    int j0 = rowptr[n], j1 = rowptr[n + 1];
    float a = 0.f;
    for (int base = j0; base < j1; base += 64) {
        int cnt = min(64, j1 - base);
        int myj = base + lane;
        int sl = (myj < j1) ? csr_src[myj] : 0;
        int e = 0;
        for (; e + 4 <= cnt; e += 4) {
            int s0 = __shfl(sl, e + 0), s1 = __shfl(sl, e + 1),
                s2 = __shfl(sl, e + 2), s3 = __shfl(sl, e + 3);
            float t0 = bf2f(u_bf[(size_t)s0 * F2 + lane]);
            float t1 = bf2f(u_bf[(size_t)s1 * F2 + lane]);
            float t2 = bf2f(u_bf[(size_t)s2 * F2 + lane]);
            float t3 = bf2f(u_bf[(size_t)s3 * F2 + lane]);
            a += (t0 + t1) + (t2 + t3);
        }
        for (; e < cnt; e++) {
            int s = __shfl(sl, e);
            a += bf2f(u_bf[(size_t)s * F2 + lane]);
        }
    }
    float inv = 1.0f / fmaxf((float)(j1 - j0), 1.0f);
    h2[(size_t)n * F2 + lane] = a * inv + v[(size_t)n * F2 + lane] + bl[lane];
}

__global__ void k_dinv(const int* __restrict__ degi, float* __restrict__ dinv) {
    int i = blockIdx.x * blockDim.x + threadIdx.x;
    if (i < NN) dinv[i] = rsqrtf((float)degi[i] + 1.0f);
}

// =================== GCN ===================
// hwd (bf16) = (h2 @ gcn_w) * dinv[row]  (pre-activated h2)
__global__ void k_gcn_gemm(const float* __restrict__ h2, const float* __restrict__ wmat,
                           const float* __restrict__ dinv, ushort* __restrict__ hwd_bf) {
    __shared__ float sw[F2 * F2];    // 16 KB
    int t = threadIdx.x;
    const float4* w4 = (const float4*)wmat;
    float4* sw4 = (float4*)sw;
    for (int i = t; i < F2 * F2 / 4; i += 256) sw4[i] = w4[i];
    __syncthreads();
    int w = t >> 6, j = t & 63;
    int row0 = blockIdx.x * GROWS + w * 8;
    float acc[8] = {0.f, 0.f, 0.f, 0.f, 0.f, 0.f, 0.f, 0.f};
    for (int k = 0; k < F2; k += 4) {
        float4 a[8];
#pragma unroll
        for (int r = 0; r < 8; r++)
            a[r] = *(const float4*)&h2[(size_t)(row0 + r) * F2 + k];
#pragma unroll
        for (int kk = 0; kk < 4; kk++) {
            float wkj = sw[(k + kk) * F2 + j];
#pragma unroll
            for (int r = 0; r < 8; r++)
                acc[r] += (&a[r].x)[kk] * wkj;
        }
    }
#pragma unroll
    for (int r = 0; r < 8; r++)
        hwd_bf[(size_t)(row0 + r) * F2 + j] = f2bf(acc[r] * dinv[row0 + r]);
}

// h3 = dinv[n]*(sum_src hwd[s] + hwd[n]) + gb
__global__ void k_gcn_gather(const int* __restrict__ rowptr, const int* __restrict__ csr_src,
                             const ushort* __restrict__ hwd_bf, const float* __restrict__ dinv,
                             const float* __restrict__ gb, float* __restrict__ h3) {
    int n = blockIdx.x * 4 + (threadIdx.x >> 6);
    int lane = threadIdx.x & 63;
    if (n >= NN) return;
    int j0 = rowptr[n], j1 = rowptr[n + 1];
    float acc = 0.f;
    for (int base = j0; base < j1; base += 64) {
        int cnt = min(64, j1 - base);
        int myj = base + lane;
        int sl = (myj < j1) ? csr_src[myj] : 0;
        int e = 0;
        for (; e + 4 <= cnt; e += 4) {
            int s0 = __shfl(sl, e + 0), s1 = __shfl(sl, e + 1),
                s2 = __shfl(sl, e + 2), s3 = __shfl(sl, e + 3);
            float t0 = bf2f(hwd_bf[(size_t)s0 * F2 + lane]);
            float t1 = bf2f(hwd_bf[(size_t)s1 * F2 + lane]);
            float t2 = bf2f(hwd_bf[(size_t)s2 * F2 + lane]);
            float t3 = bf2f(hwd_bf[(size_t)s3 * F2 + lane]);
            acc += (t0 + t1) + (t2 + t3);
        }
        for (; e < cnt; e++) {
            int s = __shfl(sl, e);
            acc += bf2f(hwd_bf[(size_t)s * F2 + lane]);
        }
    }
    float di = dinv[n];
    acc += bf2f(hwd_bf[(size_t)n * F2 + lane]);
    h3[(size_t)n * F2 + lane] = acc * di + gb[lane];
}

// =================== fused BN3-apply + ELU + segmented pool ===================
__global__ void k_bn3_pool(const float* __restrict__ h3raw, const float* __restrict__ sums,
                           const float* __restrict__ g3, const float* __restrict__ b3,
                           const int* __restrict__ batch, float* __restrict__ psum,
                           unsigned* __restrict__ pmax, float* __restrict__ cnt) {
    int lane = threadIdx.x;   // 64 threads = one wave, lane = feature
    int rows = (NN + gridDim.x - 1) / gridDim.x;
    int r0 = blockIdx.x * rows;
    int r1 = min(NN, r0 + rows);
    if (r0 >= r1) return;
    float m = sums[lane] * (1.0f / NN);
    float var = sums[F2 + lane] * (1.0f / NN) - m * m;
    float sc = rsqrtf(var + 1e-5f) * g3[lane];
    float bb = b3[lane];
    int curg = batch[r0];
    float ls = 0.f, lm = -INFINITY;
    int run = 0;
    for (int r = r0; r < r1; r++) {
        int gg = batch[r];
        if (gg != curg) {
            atomicAdd(&psum[curg * F2 + lane], ls);
            atomicMax(&pmax[curg * F2 + lane], enc_f(lm));
            if (lane == 0) atomicAdd(&cnt[curg], (float)run);
            curg = gg; ls = 0.f; lm = -INFINITY; run = 0;
        }
        float v = (h3raw[r * F2 + lane] - m) * sc + bb;
        v = v > 0.f ? v : expm1f(v);
        ls += v; lm = fmaxf(lm, v); run++;
    }
    atomicAdd(&psum[curg * F2 + lane], ls);
    atomicMax(&pmax[curg * F2 + lane], enc_f(lm));
    if (lane == 0) atomicAdd(&cnt[curg], (float)run);
}

// =================== classifier ===================
__global__ void k_cls(const float* __restrict__ psum, const unsigned* __restrict__ pmax,
                      const float* __restrict__ cnt, const float* __restrict__ w1,
                      const float* __restrict__ b1, const float* __restrict__ w2,
                      const float* __restrict__ b2, float* __restrict__ out) {
    int g = blockIdx.x;
    int j = threadIdx.x;  // 64 threads
    __shared__ float z[2 * F2];
    __shared__ float hid[F2];
    float c = fmaxf(cnt[g], 1.0f);
    z[j] = psum[g * F2 + j] / c;
    float mv = dec_f(pmax[g * F2 + j]);
    z[F2 + j] = isfinite(mv) ? mv : 0.f;
    __syncthreads();
    float acc = b1[j];
#pragma unroll 8
    for (int k = 0; k < 2 * F2; k++) acc += z[k] * w1[k * F2 + j];
    hid[j] = fmaxf(acc, 0.f);
    __syncthreads();
    if (j < NCLS) {
        float o = b2[j];
#pragma unroll 8
        for (int k = 0; k < F2; k++) o += hid[k] * w2[k * NCLS + j];
        out[g * NCLS + j] = o;
    }
}

extern "C" void kernel_launch(void* const* d_in, const int* in_sizes, int n_in,
                              void* d_out, int out_size, void* d_ws, size_t ws_size,
                              hipStream_t stream) {
    const float* x       = (const float*)d_in[0];
    const int*   ei      = (const int*)d_in[1];
    const int*   batch   = (const int*)d_in[2];
    const float* gat_w   = (const float*)d_in[3];
    const float* att_src = (const float*)d_in[4];
    const float* att_dst = (const float*)d_in[5];
    // d_in[6] gat_b: cancels inside BN1 (constant shift removed by mean subtraction)
    const float* bn1_g   = (const float*)d_in[7];
    const float* bn1_b   = (const float*)d_in[8];
    const float* sage_wl = (const float*)d_in[9];
    const float* sage_bl = (const float*)d_in[10];
    const float* sage_wr = (const float*)d_in[11];
    const float* bn2_g   = (const float*)d_in[12];
    const float* bn2_b   = (const float*)d_in[13];
    const float* gcn_w   = (const float*)d_in[14];
    const float* gcn_b   = (const float*)d_in[15];
    const float* bn3_g   = (const float*)d_in[16];
    const float* bn3_b   = (const float*)d_in[17];
    const float* w1      = (const float*)d_in[18];
    const float* b1      = (const float*)d_in[19];
    const float* w2      = (const float*)d_in[20];
    const float* b2      = (const float*)d_in[21];
    float* out = (float*)d_out;

    float* ws = (float*)d_ws;
    // workspace layout (4-byte units)
    size_t o_A    = 0;                        // NN*F1 floats region, aliased (see below)
    size_t o_h1   = o_A   + (size_t)NN * F1;  // NN*F1 f32: GAT output (post-BN1 in place)
    size_t o_h2   = o_h1  + (size_t)NN * F1;  // NN*F2 f32 (post-BN2 in place)
    size_t o_csr  = o_h2  + (size_t)NN * F2;  // E ints (csr_src)
    size_t o_rp   = o_csr + (size_t)NE;       // N+1 ints (rowptr)
    size_t o_deg  = o_rp  + (size_t)(NN + 1); // N ints (degi)
    size_t o_bs   = o_deg + (size_t)NN;       // 512 ints (block sums)
    size_t o_asrc = o_bs  + 512;              // N*2
    size_t o_adst = o_asrc + (size_t)NN * 2;  // N*2
    size_t o_dinv = o_adst + (size_t)NN * 2;  // N
    size_t o_sums = o_dinv + (size_t)NN;      // 256
    size_t o_psum = o_sums + 256;             // G*F2
    size_t o_pmax = o_psum + (size_t)NG * F2; // G*F2
    size_t o_cnt  = o_pmax + (size_t)NG * F2; // G
    size_t o_alp  = o_cnt + (size_t)NG;       // E uints (packed 2xbf16 alpha)

    float* A    = ws + o_A;
    float* h1   = ws + o_h1;
    float* h2   = ws + o_h2;
    int* csr_src = (int*)(ws + o_csr);
    int* rowptr  = (int*)(ws + o_rp);
    int* degi    = (int*)(ws + o_deg);
    int* bsum    = (int*)(ws + o_bs);
    float* asr  = ws + o_asrc;
    float* ads  = ws + o_adst;
    float* dinv = ws + o_dinv;
    float* sums = ws + o_sums;
    float* psum = ws + o_psum;
    unsigned* pmax = (unsigned*)(ws + o_pmax);
    float* cnt  = ws + o_cnt;
    unsigned* alpha = (unsigned*)(ws + o_alp);

    // region-A role aliases (lifetimes disjoint):
    unsigned* staged = (unsigned*)A;                    // CSR build: NE entries (6.4 MB)
    int*    ghist  = (int*)(A + 2 * 1024 * 1024);       // CSR build: NCHUNK*NBUCK ints (at 8 MB)
    ushort* xw_bf  = (ushort*)A;                        // GAT: NN*F1 bf16 (25.6 MB)
    ushort* u_bf   = (ushort*)A;                        // SAGE: NN*F2 bf16 (xw dead)
    float*  vmat   = A + (size_t)NN * F2 / 2;           // SAGE: NN*F2 f32
    ushort* hwd_bf = (ushort*)A;                        // GCN: NN*F2 bf16 (u dead)
    float*  h3     = A + (size_t)NN * F2 / 2;           // GCN out: NN*F2 f32 (v dead)

    // ---- CSR build: count + node scan, then chunk-major radix ----
    hipMemsetAsync(degi, 0, sizeof(int) * NN, stream);
    k_count<<<(NE + 255) / 256, 256, 0, stream>>>(ei, degi);
    k_scan1<<<NB_SCAN, 256, 0, stream>>>(degi, rowptr, bsum);
    k_scan2<<<1, 512, 0, stream>>>(bsum, NB_SCAN);
    k_scan3<<<NB_SCAN, 256, 0, stream>>>(rowptr, bsum);
    k_hist<<<NCHUNK, 256, 0, stream>>>(ei, ghist);
    k_chunkscan<<<(NBUCK + 255) / 256, 256, 0, stream>>>(ghist, rowptr);
    k_scatter2<<<NCHUNK, 256, 0, stream>>>(ei, ghist, staged);
    k_bucket_sort<<<NBUCK, 256, 0, stream>>>(staged, rowptr, csr_src);

    // ---- GAT ----
    k_xw<<<NN, F1, 0, stream>>>(x, gat_w, att_src, att_dst, xw_bf, asr, ads);
    k_alpha<<<(NN + 3) / 4, 256, 0, stream>>>(rowptr, csr_src, asr, ads, alpha);
    k_gat_gather<<<(NN + 3) / 4, 256, 0, stream>>>(rowptr, csr_src, alpha,
                                                   (const unsigned*)xw_bf, h1);
    hipMemsetAsync(sums, 0, sizeof(float) * 256, stream);
    k_bn_stats<<<512, F1, 0, stream>>>(h1, F1, sums);
    k_bn_apply<<<(NN * F1 + 255) / 256, 256, 0, stream>>>(h1, sums, bn1_g, bn1_b, F1, NN * F1);

    // ---- SAGE: dense dual-GEMM first, then bf16 mean-gather (linearity) ----
    k_sage_dualgemm<<<NN / GROWS, 256, 0, stream>>>(h1, sage_wl, sage_wr, u_bf, vmat);
    k_sage_gather2<<<(NN + 3) / 4, 256, 0, stream>>>(rowptr, csr_src, u_bf, vmat, sage_bl, h2);
    hipMemsetAsync(sums, 0, sizeof(float) * 256, stream);
    k_bn_stats<<<512, F2, 0, stream>>>(h2, F2, sums);
    k_bn_apply<<<(NN * F2 + 255) / 256, 256, 0, stream>>>(h2, sums, bn2_g, bn2_b, F2, NN * F2);

    // ---- GCN ----
    k_dinv<<<(NN + 255) / 256, 256, 0, stream>>>(degi, dinv);
    k_gcn_gemm<<<NN / GROWS, 256, 0, stream>>>(h2, gcn_w, dinv, hwd_bf);
    k_gcn_gather<<<(NN + 3) / 4, 256, 0, stream>>>(rowptr, csr_src, hwd_bf, dinv, gcn_b, h3);
    hipMemsetAsync(sums, 0, sizeof(float) * 256, stream);
    k_bn_stats<<<512, F2, 0, stream>>>(h3, F2, sums);

    // ---- fused BN3 + ELU + pooling, then classifier ----
    hipMemsetAsync(psum, 0, sizeof(float) * NG * F2, stream);
    hipMemsetAsync(cnt, 0, sizeof(float) * NG, stream);
    k_fill_u32<<<(NG * F2 + 255) / 256, 256, 0, stream>>>(pmax, ENC_NEG_INF, NG * F2);
    k_bn3_pool<<<512, F2, 0, stream>>>(h3, sums, bn3_g, bn3_b, batch, psum, pmax, cnt);
    k_cls<<<NG, F2, 0, stream>>>(psum, pmax, cnt, w1, b1, w2, b2, out);
}

// Round 13
// 867.900 us; speedup vs baseline: 1.5659x; 1.0050x over previous
//
#include <hip/hip_runtime.h>
#include <hip/hip_bf16.h>
#include <math.h>

#define NN 100000      // nodes
#define NE 1600000     // edges
#define NG 64          // graphs
#define F_IN 5
#define F1 128         // H*HID
#define F2 64          // HID
#define NCLS 4
#define NB_SCAN ((NN + 255) / 256)   // 391 blocks in node scan level 1
#define GROWS 32                     // rows per block in register-blocked GEMMs
#define NCHUNK 250                   // edge chunks (250 * 6400 = NE)
#define CH_E 6400                    // edges per chunk
#define NBUCK ((NN + 255) / 256)     // 391 dst buckets of 256 nodes
#define CAPB 6144                    // bucket capacity in LDS sort (avg 4096, 32 sigma margin)

typedef unsigned short ushort;

// ---------- bf16 helpers (round-to-nearest-even pack) ----------
__device__ __forceinline__ ushort f2bf(float f) {
    unsigned u = __float_as_uint(f);
    u = (u + 0x7fffu + ((u >> 16) & 1u)) >> 16;
    return (ushort)u;
}
__device__ __forceinline__ float bf2f(ushort h) {
    return __uint_as_float(((unsigned)h) << 16);
}
__device__ __forceinline__ unsigned pack2bf(float a, float b) {
    return (unsigned)f2bf(a) | ((unsigned)f2bf(b) << 16);
}
__device__ __forceinline__ float lo_bf(unsigned p) { return __uint_as_float(p << 16); }
__device__ __forceinline__ float hi_bf(unsigned p) { return __uint_as_float(p & 0xffff0000u); }

// ---------- order-preserving float<->uint encoding for atomicMax ----------
__device__ __forceinline__ unsigned enc_f(float f) {
    unsigned b = __float_as_uint(f);
    return (b & 0x80000000u) ? ~b : (b | 0x80000000u);
}
__device__ __forceinline__ float dec_f(unsigned k) {
    unsigned b = (k & 0x80000000u) ? (k ^ 0x80000000u) : ~k;
    return __uint_as_float(b);
}
#define ENC_NEG_INF 0x007FFFFFu   // enc_f(-inf)

__global__ void k_fill_u32(unsigned* p, unsigned v, int n) {
    int i = blockIdx.x * blockDim.x + threadIdx.x;
    if (i < n) p[i] = v;
}

// pack two f32 weight matrices element-wise into u32 (lo=bf16(a), hi=bf16(b))
__global__ void k_packw(const float* __restrict__ a, const float* __restrict__ b,
                        unsigned* __restrict__ p, int n) {
    int i = blockIdx.x * blockDim.x + threadIdx.x;
    if (i < n) p[i] = pack2bf(a[i], b[i]);
}

// =================== CSR build (chunk-major two-level counting sort) ===================
__global__ void k_count(const int* __restrict__ ei, int* __restrict__ degi) {
    int e = blockIdx.x * blockDim.x + threadIdx.x;
    if (e < NE) atomicAdd(&degi[ei[NE + e]], 1);
}

__global__ void k_scan1(const int* __restrict__ degi, int* __restrict__ rowptr,
                        int* __restrict__ bsum) {
    __shared__ int sh[256];
    int i = blockIdx.x * 256 + threadIdx.x;
    int v = (i < NN) ? degi[i] : 0;
    sh[threadIdx.x] = v;
    __syncthreads();
    for (int off = 1; off < 256; off <<= 1) {
        int t = (threadIdx.x >= off) ? sh[threadIdx.x - off] : 0;
        __syncthreads();
        sh[threadIdx.x] += t;
        __syncthreads();
    }
    if (i < NN) rowptr[i] = sh[threadIdx.x] - v;   // exclusive, block-local
    if (threadIdx.x == 255) bsum[blockIdx.x] = sh[255];
}

__global__ void k_scan2(int* __restrict__ bsum, int nb) {
    __shared__ int sh[512];
    int v = (threadIdx.x < nb) ? bsum[threadIdx.x] : 0;
    sh[threadIdx.x] = v;
    __syncthreads();
    for (int off = 1; off < 512; off <<= 1) {
        int t = (threadIdx.x >= off) ? sh[threadIdx.x - off] : 0;
        __syncthreads();
        sh[threadIdx.x] += t;
        __syncthreads();
    }
    if (threadIdx.x < nb) bsum[threadIdx.x] = sh[threadIdx.x] - v;   // exclusive
}

__global__ void k_scan3(int* __restrict__ rowptr, const int* __restrict__ bsum) {
    int i = blockIdx.x * 256 + threadIdx.x;
    if (i == 0) rowptr[NN] = NE;
    if (i >= NN) return;
    rowptr[i] += bsum[blockIdx.x];
}

// pass 1: per-chunk histogram over 391 dst buckets
__global__ void k_hist(const int* __restrict__ ei, int* __restrict__ ghist) {
    __shared__ int lh[NBUCK];
    int c = blockIdx.x, t = threadIdx.x;
    for (int b = t; b < NBUCK; b += 256) lh[b] = 0;
    __syncthreads();
    int e0 = c * CH_E;
#pragma unroll
    for (int i = 0; i < CH_E / 256; i++) {
        int d = ei[NE + e0 + t + i * 256];
        atomicAdd(&lh[d >> 8], 1);
    }
    __syncthreads();
    for (int b = t; b < NBUCK; b += 256) ghist[c * NBUCK + b] = lh[b];
}

// pass 2: per-bucket serial prefix over chunks (in place: ghist -> offsets)
__global__ void k_chunkscan(int* __restrict__ ghist, const int* __restrict__ rowptr) {
    int b = blockIdx.x * blockDim.x + threadIdx.x;
    if (b >= NBUCK) return;
    int run = rowptr[b * 256];           // bucket base in csr order
    for (int c = 0; c < NCHUNK; c++) {
        int h = ghist[c * NBUCK + b];
        ghist[c * NBUCK + b] = run;
        run += h;
    }
}

// pass 3: scatter into bucket-major staged array (packed (dlow<<17)|src)
__global__ void k_scatter2(const int* __restrict__ ei, const int* __restrict__ ghist,
                           unsigned* __restrict__ staged) {
    __shared__ int lcur[NBUCK];
    int c = blockIdx.x, t = threadIdx.x;
    for (int b = t; b < NBUCK; b += 256) lcur[b] = ghist[c * NBUCK + b];
    __syncthreads();
    int e0 = c * CH_E;
#pragma unroll
    for (int i = 0; i < CH_E / 256; i++) {
        int e = e0 + t + i * 256;
        int s = ei[e];
        int d = ei[NE + e];
        int pos = atomicAdd(&lcur[d >> 8], 1);
        staged[pos] = (((unsigned)(d & 255)) << 17) | (unsigned)s;
    }
}

// pass 4: per-bucket LDS counting sort by low 8 dst bits -> coalesced csr_src
__global__ void k_bucket_sort(const unsigned* __restrict__ staged,
                              const int* __restrict__ rowptr, int* __restrict__ csr_src) {
    __shared__ unsigned ein[CAPB];
    __shared__ unsigned sout[CAPB];
    __shared__ int lcur[256];
    int b = blockIdx.x, t = threadIdx.x;
    int n0 = b * 256;
    int nend = min(n0 + 256, NN);
    int nn = nend - n0;
    int g0 = rowptr[n0];
    int m = rowptr[nend] - g0;
    if (t < nn) lcur[t] = rowptr[n0 + t] - g0;
    __syncthreads();
    if (m <= CAPB) {
        for (int i = t; i < m; i += 256) ein[i] = staged[g0 + i];
        __syncthreads();
        for (int i = t; i < m; i += 256) {
            unsigned u = ein[i];
            int pos = atomicAdd(&lcur[u >> 17], 1);
            sout[pos] = u & 0x1FFFFu;
        }
        __syncthreads();
        for (int i = t; i < m; i += 256) csr_src[g0 + i] = (int)sout[i];
    } else {
        // statistically unreachable fallback (bucket > CAPB)
        for (int i = t; i < m; i += 256) {
            unsigned u = staged[g0 + i];
            int pos = atomicAdd(&lcur[u >> 17], 1);
            csr_src[g0 + pos] = (int)(u & 0x1FFFFu);
        }
    }
}

// =================== GAT ===================
// xw (bf16) = x @ gat_w ; a_src/a_dst per-node attention logits
__global__ void k_xw(const float* __restrict__ x, const float* __restrict__ gw,
                     const float* __restrict__ aw_src, const float* __restrict__ aw_dst,
                     ushort* __restrict__ xw_bf, float* __restrict__ a_src,
                     float* __restrict__ a_dst) {
    int n = blockIdx.x;
    int f = threadIdx.x;                 // 128 threads, f = h*64+c
    __shared__ float w[F_IN * F1];
    __shared__ float xs[F_IN];
    for (int i = f; i < F_IN * F1; i += F1) w[i] = gw[i];
    if (f < F_IN) xs[f] = x[n * F_IN + f];
    __syncthreads();
    float acc = 0.f;
#pragma unroll
    for (int i = 0; i < F_IN; i++) acc += xs[i] * w[i * F1 + f];
    xw_bf[n * F1 + f] = f2bf(acc);
    int h = f >> 6, lane = f & 63;
    float p = acc * aw_src[f];
    float q = acc * aw_dst[f];
#pragma unroll
    for (int off = 32; off > 0; off >>= 1) {
        p += __shfl_down(p, off);
        q += __shfl_down(q, off);
    }
    if (lane == 0) { a_src[n * 2 + h] = p; a_dst[n * 2 + h] = q; }
}

// per-node softmax over incoming edges, ONE WAVE per node, lane-per-edge.
__global__ void k_alpha(const int* __restrict__ rowptr, const int* __restrict__ csr_src,
                        const float* __restrict__ a_src, const float* __restrict__ a_dst,
                        unsigned* __restrict__ alpha) {
    int n = blockIdx.x * 4 + (threadIdx.x >> 6);
    int lane = threadIdx.x & 63;
    if (n >= NN) return;
    int j0 = rowptr[n], j1 = rowptr[n + 1];
    int deg = j1 - j0;
    if (deg <= 0) return;
    float ad0 = a_dst[n * 2 + 0], ad1 = a_dst[n * 2 + 1];
    if (deg <= 64) {
        int j = j0 + lane;
        float l0 = -INFINITY, l1 = -INFINITY;
        if (lane < deg) {
            int s = csr_src[j];
            l0 = a_src[s * 2 + 0] + ad0;
            l1 = a_src[s * 2 + 1] + ad1;
            l0 = l0 > 0.f ? l0 : 0.2f * l0;
            l1 = l1 > 0.f ? l1 : 0.2f * l1;
        }
        float m0 = l0, m1 = l1;
#pragma unroll
        for (int off = 32; off > 0; off >>= 1) {
            m0 = fmaxf(m0, __shfl_xor(m0, off));
            m1 = fmaxf(m1, __shfl_xor(m1, off));
        }
        float e0 = 0.f, e1 = 0.f;
        if (lane < deg) { e0 = expf(l0 - m0); e1 = expf(l1 - m1); }
        float s0 = e0, s1 = e1;
#pragma unroll
        for (int off = 32; off > 0; off >>= 1) {
            s0 += __shfl_xor(s0, off);
            s1 += __shfl_xor(s1, off);
        }
        if (lane < deg)
            alpha[j] = pack2bf(e0 / (s0 + 1e-16f), e1 / (s1 + 1e-16f));
    } else {
        float m0 = -INFINITY, m1 = -INFINITY;
        for (int base = j0; base < j1; base += 64) {
            int j = base + lane;
            float l0 = -INFINITY, l1 = -INFINITY;
            if (j < j1) {
                int s = csr_src[j];
                l0 = a_src[s * 2 + 0] + ad0;
                l1 = a_src[s * 2 + 1] + ad1;
                l0 = l0 > 0.f ? l0 : 0.2f * l0;
                l1 = l1 > 0.f ? l1 : 0.2f * l1;
            }
            m0 = fmaxf(m0, l0); m1 = fmaxf(m1, l1);
        }
#pragma unroll
        for (int off = 32; off > 0; off >>= 1) {
            m0 = fmaxf(m0, __shfl_xor(m0, off));
            m1 = fmaxf(m1, __shfl_xor(m1, off));
        }
        float s0 = 0.f, s1 = 0.f;
        for (int base = j0; base < j1; base += 64) {
            int j = base + lane;
            float e0 = 0.f, e1 = 0.f;
            if (j < j1) {
                int s = csr_src[j];
                float l0 = a_src[s * 2 + 0] + ad0;
                float l1 = a_src[s * 2 + 1] + ad1;
                l0 = l0 > 0.f ? l0 : 0.2f * l0;
                l1 = l1 > 0.f ? l1 : 0.2f * l1;
                e0 = expf(l0 - m0); e1 = expf(l1 - m1);
                alpha[j] = pack2bf(e0, e1);
            }
            s0 += e0; s1 += e1;
        }
#pragma unroll
        for (int off = 32; off > 0; off >>= 1) {
            s0 += __shfl_xor(s0, off);
            s1 += __shfl_xor(s1, off);
        }
        float r0 = 1.0f / (s0 + 1e-16f), r1 = 1.0f / (s1 + 1e-16f);
        for (int base = j0; base < j1; base += 64) {
            int j = base + lane;
            if (j < j1) {
                unsigned a = alpha[j];
                alpha[j] = pack2bf(lo_bf(a) * r0, hi_bf(a) * r1);
            }
        }
    }
}

// gather-accumulate with lane-preloaded indices + 4-deep row-load pipeline.
__global__ void k_gat_gather(const int* __restrict__ rowptr, const int* __restrict__ csr_src,
                             const unsigned* __restrict__ alpha,
                             const unsigned* __restrict__ xw32, float* __restrict__ h1) {
    int n = blockIdx.x * 4 + (threadIdx.x >> 6);
    int lane = threadIdx.x & 63;
    if (n >= NN) return;
    int j0 = rowptr[n], j1 = rowptr[n + 1];
    float acc0 = 0.f, acc1 = 0.f;
    bool lo = (lane < 32);
    for (int base = j0; base < j1; base += 64) {
        int cnt = min(64, j1 - base);
        int myj = base + lane;
        int sl = 0; unsigned al = 0;
        if (myj < j1) { sl = csr_src[myj]; al = alpha[myj]; }
        int e = 0;
        for (; e + 4 <= cnt; e += 4) {
            int s0 = __shfl(sl, e + 0), s1 = __shfl(sl, e + 1),
                s2 = __shfl(sl, e + 2), s3 = __shfl(sl, e + 3);
            unsigned b0 = __shfl(al, e + 0), b1 = __shfl(al, e + 1),
                     b2 = __shfl(al, e + 2), b3 = __shfl(al, e + 3);
            unsigned p0 = xw32[(size_t)s0 * 64 + lane];
            unsigned p1 = xw32[(size_t)s1 * 64 + lane];
            unsigned p2 = xw32[(size_t)s2 * 64 + lane];
            unsigned p3 = xw32[(size_t)s3 * 64 + lane];
            float w0 = lo ? lo_bf(b0) : hi_bf(b0);
            float w1 = lo ? lo_bf(b1) : hi_bf(b1);
            float w2 = lo ? lo_bf(b2) : hi_bf(b2);
            float w3 = lo ? lo_bf(b3) : hi_bf(b3);
            acc0 = fmaf(lo_bf(p0), w0, acc0); acc1 = fmaf(hi_bf(p0), w0, acc1);
            acc0 = fmaf(lo_bf(p1), w1, acc0); acc1 = fmaf(hi_bf(p1), w1, acc1);
            acc0 = fmaf(lo_bf(p2), w2, acc0); acc1 = fmaf(hi_bf(p2), w2, acc1);
            acc0 = fmaf(lo_bf(p3), w3, acc0); acc1 = fmaf(hi_bf(p3), w3, acc1);
        }
        for (; e < cnt; e++) {
            int s = __shfl(sl, e); unsigned b = __shfl(al, e);
            unsigned p = xw32[(size_t)s * 64 + lane];
            float w = lo ? lo_bf(b) : hi_bf(b);
            acc0 = fmaf(lo_bf(p), w, acc0);
            acc1 = fmaf(hi_bf(p), w, acc1);
        }
    }
    float2 o; o.x = acc0; o.y = acc1;
    *(float2*)&h1[(size_t)n * F1 + 2 * lane] = o;
}

// =================== BatchNorm ===================
__global__ void k_bn_stats(const float* __restrict__ h, int nfeat, float* __restrict__ sums) {
    int f = threadIdx.x;                       // blockDim.x == nfeat
    int rows = (NN + gridDim.x - 1) / gridDim.x;
    int r0 = blockIdx.x * rows;
    int r1 = min(NN, r0 + rows);
    float s = 0.f, ss = 0.f;
    for (int r = r0; r < r1; r++) {
        float v = h[r * nfeat + f];
        s += v; ss += v * v;
    }
    atomicAdd(&sums[f], s);
    atomicAdd(&sums[nfeat + f], ss);
}

__global__ void k_bn_apply(float* __restrict__ h, const float* __restrict__ sums,
                           const float* __restrict__ g, const float* __restrict__ b,
                           int nfeat, int total) {
    int i = blockIdx.x * blockDim.x + threadIdx.x;
    if (i >= total) return;
    int f = i & (nfeat - 1);
    float m = sums[f] * (1.0f / NN);
    float var = sums[nfeat + f] * (1.0f / NN) - m * m;
    float v = (h[i] - m) * rsqrtf(var + 1e-5f) * g[f] + b[f];
    h[i] = v > 0.f ? v : expm1f(v);
}

// =================== SAGE ===================
// u (bf16) = h1 @ wl ; v (f32) = h1 @ wr  — dual GEMM with pair-packed bf16 weights.
// One 32 KB LDS buffer (lo=wl, hi=wr per element): 5 blocks/CU vs 2 with f32 pair.
__global__ void k_sage_dualgemm(const float* __restrict__ h1,
                                const unsigned* __restrict__ wpack,
                                ushort* __restrict__ u_bf, float* __restrict__ v) {
    __shared__ unsigned swp[F1 * F2];   // 32 KB (packed wl|wr)
    int t = threadIdx.x;
    const uint4* wp4 = (const uint4*)wpack;
    uint4* swp4 = (uint4*)swp;
    for (int i = t; i < F1 * F2 / 4; i += 256) swp4[i] = wp4[i];
    __syncthreads();
    int w = t >> 6, j = t & 63;
    int row0 = blockIdx.x * GROWS + w * 8;
    float accu[8] = {0.f, 0.f, 0.f, 0.f, 0.f, 0.f, 0.f, 0.f};
    float accv[8] = {0.f, 0.f, 0.f, 0.f, 0.f, 0.f, 0.f, 0.f};
    for (int k = 0; k < F1; k += 4) {
        float4 a[8];
#pragma unroll
        for (int r = 0; r < 8; r++)
            a[r] = *(const float4*)&h1[(size_t)(row0 + r) * F1 + k];
#pragma unroll
        for (int kk = 0; kk < 4; kk++) {
            unsigned wp = swp[(k + kk) * F2 + j];
            float wlj = lo_bf(wp);
            float wrj = hi_bf(wp);
#pragma unroll
            for (int r = 0; r < 8; r++) {
                float av = (&a[r].x)[kk];
                accu[r] += av * wlj;
                accv[r] += av * wrj;
            }
        }
    }
#pragma unroll
    for (int r = 0; r < 8; r++) {
        u_bf[(size_t)(row0 + r) * F2 + j] = f2bf(accu[r]);
        v[(size_t)(row0 + r) * F2 + j] = accv[r];
    }
}

// h2raw[n] = mean-gather(u_bf16) + v[n] + bl
__global__ void k_sage_gather2(const int* __restrict__ rowptr, const int* __restrict__ csr_src,
                               const ushort* __restrict__ u_bf, const float* __restrict__ v,
                               const float* __restrict__ bl, float* __restrict__ h2) {
    int n = blockIdx.x * 4 + (threadIdx.x >> 6);
    int lane = threadIdx.x & 63;
    if (n >= NN) return;
    int j0 = rowptr[n], j1 = rowptr[n + 1];
    float a = 0.f;
    for (int base = j0; base < j1; base += 64) {
        int cnt = min(64, j1 - base);
        int myj = base + lane;
        int sl = (myj < j1) ? csr_src[myj] : 0;
        int e = 0;
        for (; e + 4 <= cnt; e += 4) {
            int s0 = __shfl(sl, e + 0), s1 = __shfl(sl, e + 1),
                s2 = __shfl(sl, e + 2), s3 = __shfl(sl, e + 3);
            float t0 = bf2f(u_bf[(size_t)s0 * F2 + lane]);
            float t1 = bf2f(u_bf[(size_t)s1 * F2 + lane]);
            float t2 = bf2f(u_bf[(size_t)s2 * F2 + lane]);
            float t3 = bf2f(u_bf[(size_t)s3 * F2 + lane]);
            a += (t0 + t1) + (t2 + t3);
        }
        for (; e < cnt; e++) {
            int s = __shfl(sl, e);
            a += bf2f(u_bf[(size_t)s * F2 + lane]);
        }
    }
    float inv = 1.0f / fmaxf((float)(j1 - j0), 1.0f);
    h2[(size_t)n * F2 + lane] = a * inv + v[(size_t)n * F2 + lane] + bl[lane];
}

__global__ void k_dinv(const int* __restrict__ degi, float* __restrict__ dinv) {
    int i = blockIdx.x * blockDim.x + threadIdx.x;
    if (i < NN) dinv[i] = rsqrtf((float)degi[i] + 1.0f);
}

// =================== GCN ===================
// hwd (bf16) = (h2 @ gcn_w) * dinv[row]  (pre-activated h2)
__global__ void k_gcn_gemm(const float* __restrict__ h2, const float* __restrict__ wmat,
                           const float* __restrict__ dinv, ushort* __restrict__ hwd_bf) {
    __shared__ float sw[F2 * F2];    // 16 KB
    int t = threadIdx.x;
    const float4* w4 = (const float4*)wmat;
    float4* sw4 = (float4*)sw;
    for (int i = t; i < F2 * F2 / 4; i += 256) sw4[i] = w4[i];
    __syncthreads();
    int w = t >> 6, j = t & 63;
    int row0 = blockIdx.x * GROWS + w * 8;
    float acc[8] = {0.f, 0.f, 0.f, 0.f, 0.f, 0.f, 0.f, 0.f};
    for (int k = 0; k < F2; k += 4) {
        float4 a[8];
#pragma unroll
        for (int r = 0; r < 8; r++)
            a[r] = *(const float4*)&h2[(size_t)(row0 + r) * F2 + k];
#pragma unroll
        for (int kk = 0; kk < 4; kk++) {
            float wkj = sw[(k + kk) * F2 + j];
#pragma unroll
            for (int r = 0; r < 8; r++)
                acc[r] += (&a[r].x)[kk] * wkj;
        }
    }
#pragma unroll
    for (int r = 0; r < 8; r++)
        hwd_bf[(size_t)(row0 + r) * F2 + j] = f2bf(acc[r] * dinv[row0 + r]);
}

// h3 = dinv[n]*(sum_src hwd[s] + hwd[n]) + gb
__global__ void k_gcn_gather(const int* __restrict__ rowptr, const int* __restrict__ csr_src,
                             const ushort* __restrict__ hwd_bf, const float* __restrict__ dinv,
                             const float* __restrict__ gb, float* __restrict__ h3) {
    int n = blockIdx.x * 4 + (threadIdx.x >> 6);
    int lane = threadIdx.x & 63;
    if (n >= NN) return;
    int j0 = rowptr[n], j1 = rowptr[n + 1];
    float acc = 0.f;
    for (int base = j0; base < j1; base += 64) {
        int cnt = min(64, j1 - base);
        int myj = base + lane;
        int sl = (myj < j1) ? csr_src[myj] : 0;
        int e = 0;
        for (; e + 4 <= cnt; e += 4) {
            int s0 = __shfl(sl, e + 0), s1 = __shfl(sl, e + 1),
                s2 = __shfl(sl, e + 2), s3 = __shfl(sl, e + 3);
            float t0 = bf2f(hwd_bf[(size_t)s0 * F2 + lane]);
            float t1 = bf2f(hwd_bf[(size_t)s1 * F2 + lane]);
            float t2 = bf2f(hwd_bf[(size_t)s2 * F2 + lane]);
            float t3 = bf2f(hwd_bf[(size_t)s3 * F2 + lane]);
            acc += (t0 + t1) + (t2 + t3);
        }
        for (; e < cnt; e++) {
            int s = __shfl(sl, e);
            acc += bf2f(hwd_bf[(size_t)s * F2 + lane]);
        }
    }
    float di = dinv[n];
    acc += bf2f(hwd_bf[(size_t)n * F2 + lane]);
    h3[(size_t)n * F2 + lane] = acc * di + gb[lane];
}

// =================== fused BN3-apply + ELU + segmented pool ===================
__global__ void k_bn3_pool(const float* __restrict__ h3raw, const float* __restrict__ sums,
                           const float* __restrict__ g3, const float* __restrict__ b3,
                           const int* __restrict__ batch, float* __restrict__ psum,
                           unsigned* __restrict__ pmax, float* __restrict__ cnt) {
    int lane = threadIdx.x;   // 64 threads = one wave, lane = feature
    int rows = (NN + gridDim.x - 1) / gridDim.x;
    int r0 = blockIdx.x * rows;
    int r1 = min(NN, r0 + rows);
    if (r0 >= r1) return;
    float m = sums[lane] * (1.0f / NN);
    float var = sums[F2 + lane] * (1.0f / NN) - m * m;
    float sc = rsqrtf(var + 1e-5f) * g3[lane];
    float bb = b3[lane];
    int curg = batch[r0];
    float ls = 0.f, lm = -INFINITY;
    int run = 0;
    for (int r = r0; r < r1; r++) {
        int gg = batch[r];
        if (gg != curg) {
            atomicAdd(&psum[curg * F2 + lane], ls);
            atomicMax(&pmax[curg * F2 + lane], enc_f(lm));
            if (lane == 0) atomicAdd(&cnt[curg], (float)run);
            curg = gg; ls = 0.f; lm = -INFINITY; run = 0;
        }
        float v = (h3raw[r * F2 + lane] - m) * sc + bb;
        v = v > 0.f ? v : expm1f(v);
        ls += v; lm = fmaxf(lm, v); run++;
    }
    atomicAdd(&psum[curg * F2 + lane], ls);
    atomicMax(&pmax[curg * F2 + lane], enc_f(lm));
    if (lane == 0) atomicAdd(&cnt[curg], (float)run);
}

// =================== classifier ===================
__global__ void k_cls(const float* __restrict__ psum, const unsigned* __restrict__ pmax,
                      const float* __restrict__ cnt, const float* __restrict__ w1,
                      const float* __restrict__ b1, const float* __restrict__ w2,
                      const float* __restrict__ b2, float* __restrict__ out) {
    int g = blockIdx.x;
    int j = threadIdx.x;  // 64 threads
    __shared__ float z[2 * F2];
    __shared__ float hid[F2];
    float c = fmaxf(cnt[g], 1.0f);
    z[j] = psum[g * F2 + j] / c;
    float mv = dec_f(pmax[g * F2 + j]);
    z[F2 + j] = isfinite(mv) ? mv : 0.f;
    __syncthreads();
    float acc = b1[j];
#pragma unroll 8
    for (int k = 0; k < 2 * F2; k++) acc += z[k] * w1[k * F2 + j];
    hid[j] = fmaxf(acc, 0.f);
    __syncthreads();
    if (j < NCLS) {
        float o = b2[j];
#pragma unroll 8
        for (int k = 0; k < F2; k++) o += hid[k] * w2[k * NCLS + j];
        out[g * NCLS + j] = o;
    }
}

extern "C" void kernel_launch(void* const* d_in, const int* in_sizes, int n_in,
                              void* d_out, int out_size, void* d_ws, size_t ws_size,
                              hipStream_t stream) {
    const float* x       = (const float*)d_in[0];
    const int*   ei      = (const int*)d_in[1];
    const int*   batch   = (const int*)d_in[2];
    const float* gat_w   = (const float*)d_in[3];
    const float* att_src = (const float*)d_in[4];
    const float* att_dst = (const float*)d_in[5];
    // d_in[6] gat_b: cancels inside BN1 (constant shift removed by mean subtraction)
    const float* bn1_g   = (const float*)d_in[7];
    const float* bn1_b   = (const float*)d_in[8];
    const float* sage_wl = (const float*)d_in[9];
    const float* sage_bl = (const float*)d_in[10];
    const float* sage_wr = (const float*)d_in[11];
    const float* bn2_g   = (const float*)d_in[12];
    const float* bn2_b   = (const float*)d_in[13];
    const float* gcn_w   = (const float*)d_in[14];
    const float* gcn_b   = (const float*)d_in[15];
    const float* bn3_g   = (const float*)d_in[16];
    const float* bn3_b   = (const float*)d_in[17];
    const float* w1      = (const float*)d_in[18];
    const float* b1      = (const float*)d_in[19];
    const float* w2      = (const float*)d_in[20];
    const float* b2      = (const float*)d_in[21];
    float* out = (float*)d_out;

    float* ws = (float*)d_ws;
    // workspace layout (4-byte units)
    size_t o_A    = 0;                        // NN*F1 floats region, aliased (see below)
    size_t o_h1   = o_A   + (size_t)NN * F1;  // NN*F1 f32: GAT output (post-BN1 in place)
    size_t o_h2   = o_h1  + (size_t)NN * F1;  // NN*F2 f32 (post-BN2 in place)
    size_t o_csr  = o_h2  + (size_t)NN * F2;  // E ints (csr_src)
    size_t o_rp   = o_csr + (size_t)NE;       // N+1 ints (rowptr)
    size_t o_deg  = o_rp  + (size_t)(NN + 1); // N ints (degi)
    size_t o_bs   = o_deg + (size_t)NN;       // 512 ints (block sums)
    size_t o_asrc = o_bs  + 512;              // N*2
    size_t o_adst = o_asrc + (size_t)NN * 2;  // N*2
    size_t o_dinv = o_adst + (size_t)NN * 2;  // N
    size_t o_sums = o_dinv + (size_t)NN;      // 256
    size_t o_wp   = o_sums + 256;             // F1*F2 uints (packed sage weights)
    size_t o_psum = o_wp   + (size_t)F1 * F2; // G*F2
    size_t o_pmax = o_psum + (size_t)NG * F2; // G*F2
    size_t o_cnt  = o_pmax + (size_t)NG * F2; // G
    size_t o_alp  = o_cnt + (size_t)NG;       // E uints (packed 2xbf16 alpha)

    float* A    = ws + o_A;
    float* h1   = ws + o_h1;
    float* h2   = ws + o_h2;
    int* csr_src = (int*)(ws + o_csr);
    int* rowptr  = (int*)(ws + o_rp);
    int* degi    = (int*)(ws + o_deg);
    int* bsum    = (int*)(ws + o_bs);
    float* asr  = ws + o_asrc;
    float* ads  = ws + o_adst;
    float* dinv = ws + o_dinv;
    float* sums = ws + o_sums;
    unsigned* wpack = (unsigned*)(ws + o_wp);
    float* psum = ws + o_psum;
    unsigned* pmax = (unsigned*)(ws + o_pmax);
    float* cnt  = ws + o_cnt;
    unsigned* alpha = (unsigned*)(ws + o_alp);

    // region-A role aliases (lifetimes disjoint):
    unsigned* staged = (unsigned*)A;                    // CSR build: NE entries (6.4 MB)
    int*    ghist  = (int*)(A + 2 * 1024 * 1024);       // CSR build: NCHUNK*NBUCK ints (at 8 MB)
    ushort* xw_bf  = (ushort*)A;                        // GAT: NN*F1 bf16 (25.6 MB)
    ushort* u_bf   = (ushort*)A;                        // SAGE: NN*F2 bf16 (xw dead)
    float*  vmat   = A + (size_t)NN * F2 / 2;           // SAGE: NN*F2 f32
    ushort* hwd_bf = (ushort*)A;                        // GCN: NN*F2 bf16 (u dead)
    float*  h3     = A + (size_t)NN * F2 / 2;           // GCN out: NN*F2 f32 (v dead)

    // ---- CSR build: count + node scan, then chunk-major radix ----
    hipMemsetAsync(degi, 0, sizeof(int) * NN, stream);
    k_count<<<(NE + 255) / 256, 256, 0, stream>>>(ei, degi);
    k_scan1<<<NB_SCAN, 256, 0, stream>>>(degi, rowptr, bsum);
    k_scan2<<<1, 512, 0, stream>>>(bsum, NB_SCAN);
    k_scan3<<<NB_SCAN, 256, 0, stream>>>(rowptr, bsum);
    k_hist<<<NCHUNK, 256, 0, stream>>>(ei, ghist);
    k_chunkscan<<<(NBUCK + 255) / 256, 256, 0, stream>>>(ghist, rowptr);
    k_scatter2<<<NCHUNK, 256, 0, stream>>>(ei, ghist, staged);
    k_bucket_sort<<<NBUCK, 256, 0, stream>>>(staged, rowptr, csr_src);

    // ---- GAT ----
    k_xw<<<NN, F1, 0, stream>>>(x, gat_w, att_src, att_dst, xw_bf, asr, ads);
    k_alpha<<<(NN + 3) / 4, 256, 0, stream>>>(rowptr, csr_src, asr, ads, alpha);
    k_gat_gather<<<(NN + 3) / 4, 256, 0, stream>>>(rowptr, csr_src, alpha,
                                                   (const unsigned*)xw_bf, h1);
    hipMemsetAsync(sums, 0, sizeof(float) * 256, stream);
    k_bn_stats<<<512, F1, 0, stream>>>(h1, F1, sums);
    k_bn_apply<<<(NN * F1 + 255) / 256, 256, 0, stream>>>(h1, sums, bn1_g, bn1_b, F1, NN * F1);

    // ---- SAGE: dense dual-GEMM (packed bf16 weights) then bf16 mean-gather ----
    k_packw<<<(F1 * F2 + 255) / 256, 256, 0, stream>>>(sage_wl, sage_wr, wpack, F1 * F2);
    k_sage_dualgemm<<<NN / GROWS, 256, 0, stream>>>(h1, wpack, u_bf, vmat);
    k_sage_gather2<<<(NN + 3) / 4, 256, 0, stream>>>(rowptr, csr_src, u_bf, vmat, sage_bl, h2);
    hipMemsetAsync(sums, 0, sizeof(float) * 256, stream);
    k_bn_stats<<<512, F2, 0, stream>>>(h2, F2, sums);
    k_bn_apply<<<(NN * F2 + 255) / 256, 256, 0, stream>>>(h2, sums, bn2_g, bn2_b, F2, NN * F2);

    // ---- GCN ----
    k_dinv<<<(NN + 255) / 256, 256, 0, stream>>>(degi, dinv);
    k_gcn_gemm<<<NN / GROWS, 256, 0, stream>>>(h2, gcn_w, dinv, hwd_bf);
    k_gcn_gather<<<(NN + 3) / 4, 256, 0, stream>>>(rowptr, csr_src, hwd_bf, dinv, gcn_b, h3);
    hipMemsetAsync(sums, 0, sizeof(float) * 256, stream);
    k_bn_stats<<<512, F2, 0, stream>>>(h3, F2, sums);

    // ---- fused BN3 + ELU + pooling, then classifier ----
    hipMemsetAsync(psum, 0, sizeof(float) * NG * F2, stream);
    hipMemsetAsync(cnt, 0, sizeof(float) * NG, stream);
    k_fill_u32<<<(NG * F2 + 255) / 256, 256, 0, stream>>>(pmax, ENC_NEG_INF, NG * F2);
    k_bn3_pool<<<512, F2, 0, stream>>>(h3, sums, bn3_g, bn3_b, batch, psum, pmax, cnt);
    k_cls<<<NG, F2, 0, stream>>>(psum, pmax, cnt, w1, b1, w2, b2, out);
}

// Round 14
// 858.466 us; speedup vs baseline: 1.5831x; 1.0110x over previous
//
#include <hip/hip_runtime.h>
#include <hip/hip_bf16.h>
#include <math.h>

#define NN 100000      // nodes
#define NE 1600000     // edges
#define NG 64          // graphs
#define F_IN 5
#define F1 128         // H*HID
#define F2 64          // HID
#define NCLS 4
#define NB_SCAN ((NN + 255) / 256)   // 391 blocks in node scan level 1
#define GROWS 32                     // rows per block in register-blocked GEMMs
#define NCHUNK 250                   // edge chunks (250 * 6400 = NE)
#define CH_E 6400                    // edges per chunk
#define NBUCK ((NN + 255) / 256)     // 391 dst buckets of 256 nodes
#define CAPB 6144                    // bucket capacity in LDS sort (avg 4096, 32 sigma margin)

typedef unsigned short ushort;

// ---------- bf16 helpers (round-to-nearest-even pack) ----------
__device__ __forceinline__ ushort f2bf(float f) {
    unsigned u = __float_as_uint(f);
    u = (u + 0x7fffu + ((u >> 16) & 1u)) >> 16;
    return (ushort)u;
}
__device__ __forceinline__ float bf2f(ushort h) {
    return __uint_as_float(((unsigned)h) << 16);
}
__device__ __forceinline__ unsigned pack2bf(float a, float b) {
    return (unsigned)f2bf(a) | ((unsigned)f2bf(b) << 16);
}
__device__ __forceinline__ float lo_bf(unsigned p) { return __uint_as_float(p << 16); }
__device__ __forceinline__ float hi_bf(unsigned p) { return __uint_as_float(p & 0xffff0000u); }

// ---------- order-preserving float<->uint encoding for atomicMax ----------
__device__ __forceinline__ unsigned enc_f(float f) {
    unsigned b = __float_as_uint(f);
    return (b & 0x80000000u) ? ~b : (b | 0x80000000u);
}
__device__ __forceinline__ float dec_f(unsigned k) {
    unsigned b = (k & 0x80000000u) ? (k ^ 0x80000000u) : ~k;
    return __uint_as_float(b);
}
#define ENC_NEG_INF 0x007FFFFFu   // enc_f(-inf)

__global__ void k_fill_u32(unsigned* p, unsigned v, int n) {
    int i = blockIdx.x * blockDim.x + threadIdx.x;
    if (i < n) p[i] = v;
}

// pack two f32 weight matrices element-wise into u32 (lo=bf16(a), hi=bf16(b))
__global__ void k_packw(const float* __restrict__ a, const float* __restrict__ b,
                        unsigned* __restrict__ p, int n) {
    int i = blockIdx.x * blockDim.x + threadIdx.x;
    if (i < n) p[i] = pack2bf(a[i], b[i]);
}

// =================== CSR build (chunk-major two-level counting sort) ===================
__global__ void k_count(const int* __restrict__ ei, int* __restrict__ degi) {
    int e = blockIdx.x * blockDim.x + threadIdx.x;
    if (e < NE) atomicAdd(&degi[ei[NE + e]], 1);
}

__global__ void k_scan1(const int* __restrict__ degi, int* __restrict__ rowptr,
                        int* __restrict__ bsum) {
    __shared__ int sh[256];
    int i = blockIdx.x * 256 + threadIdx.x;
    int v = (i < NN) ? degi[i] : 0;
    sh[threadIdx.x] = v;
    __syncthreads();
    for (int off = 1; off < 256; off <<= 1) {
        int t = (threadIdx.x >= off) ? sh[threadIdx.x - off] : 0;
        __syncthreads();
        sh[threadIdx.x] += t;
        __syncthreads();
    }
    if (i < NN) rowptr[i] = sh[threadIdx.x] - v;   // exclusive, block-local
    if (threadIdx.x == 255) bsum[blockIdx.x] = sh[255];
}

__global__ void k_scan2(int* __restrict__ bsum, int nb) {
    __shared__ int sh[512];
    int v = (threadIdx.x < nb) ? bsum[threadIdx.x] : 0;
    sh[threadIdx.x] = v;
    __syncthreads();
    for (int off = 1; off < 512; off <<= 1) {
        int t = (threadIdx.x >= off) ? sh[threadIdx.x - off] : 0;
        __syncthreads();
        sh[threadIdx.x] += t;
        __syncthreads();
    }
    if (threadIdx.x < nb) bsum[threadIdx.x] = sh[threadIdx.x] - v;   // exclusive
}

__global__ void k_scan3(int* __restrict__ rowptr, const int* __restrict__ bsum) {
    int i = blockIdx.x * 256 + threadIdx.x;
    if (i == 0) rowptr[NN] = NE;
    if (i >= NN) return;
    rowptr[i] += bsum[blockIdx.x];
}

// pass 1: per-chunk histogram over 391 dst buckets
__global__ void k_hist(const int* __restrict__ ei, int* __restrict__ ghist) {
    __shared__ int lh[NBUCK];
    int c = blockIdx.x, t = threadIdx.x;
    for (int b = t; b < NBUCK; b += 256) lh[b] = 0;
    __syncthreads();
    int e0 = c * CH_E;
#pragma unroll
    for (int i = 0; i < CH_E / 256; i++) {
        int d = ei[NE + e0 + t + i * 256];
        atomicAdd(&lh[d >> 8], 1);
    }
    __syncthreads();
    for (int b = t; b < NBUCK; b += 256) ghist[c * NBUCK + b] = lh[b];
}

// pass 2: per-bucket serial prefix over chunks (in place: ghist -> offsets)
__global__ void k_chunkscan(int* __restrict__ ghist, const int* __restrict__ rowptr) {
    int b = blockIdx.x * blockDim.x + threadIdx.x;
    if (b >= NBUCK) return;
    int run = rowptr[b * 256];           // bucket base in csr order
    for (int c = 0; c < NCHUNK; c++) {
        int h = ghist[c * NBUCK + b];
        ghist[c * NBUCK + b] = run;
        run += h;
    }
}

// pass 3: scatter into bucket-major staged array (packed (dlow<<17)|src)
__global__ void k_scatter2(const int* __restrict__ ei, const int* __restrict__ ghist,
                           unsigned* __restrict__ staged) {
    __shared__ int lcur[NBUCK];
    int c = blockIdx.x, t = threadIdx.x;
    for (int b = t; b < NBUCK; b += 256) lcur[b] = ghist[c * NBUCK + b];
    __syncthreads();
    int e0 = c * CH_E;
#pragma unroll
    for (int i = 0; i < CH_E / 256; i++) {
        int e = e0 + t + i * 256;
        int s = ei[e];
        int d = ei[NE + e];
        int pos = atomicAdd(&lcur[d >> 8], 1);
        staged[pos] = (((unsigned)(d & 255)) << 17) | (unsigned)s;
    }
}

// pass 4: per-bucket LDS counting sort by low 8 dst bits -> coalesced csr_src
__global__ void k_bucket_sort(const unsigned* __restrict__ staged,
                              const int* __restrict__ rowptr, int* __restrict__ csr_src) {
    __shared__ unsigned ein[CAPB];
    __shared__ unsigned sout[CAPB];
    __shared__ int lcur[256];
    int b = blockIdx.x, t = threadIdx.x;
    int n0 = b * 256;
    int nend = min(n0 + 256, NN);
    int nn = nend - n0;
    int g0 = rowptr[n0];
    int m = rowptr[nend] - g0;
    if (t < nn) lcur[t] = rowptr[n0 + t] - g0;
    __syncthreads();
    if (m <= CAPB) {
        for (int i = t; i < m; i += 256) ein[i] = staged[g0 + i];
        __syncthreads();
        for (int i = t; i < m; i += 256) {
            unsigned u = ein[i];
            int pos = atomicAdd(&lcur[u >> 17], 1);
            sout[pos] = u & 0x1FFFFu;
        }
        __syncthreads();
        for (int i = t; i < m; i += 256) csr_src[g0 + i] = (int)sout[i];
    } else {
        // statistically unreachable fallback (bucket > CAPB)
        for (int i = t; i < m; i += 256) {
            unsigned u = staged[g0 + i];
            int pos = atomicAdd(&lcur[u >> 17], 1);
            csr_src[g0 + pos] = (int)(u & 0x1FFFFu);
        }
    }
}

// =================== GAT ===================
// xw (bf16) = x @ gat_w ; a_src/a_dst per-node attention logits
__global__ void k_xw(const float* __restrict__ x, const float* __restrict__ gw,
                     const float* __restrict__ aw_src, const float* __restrict__ aw_dst,
                     ushort* __restrict__ xw_bf, float* __restrict__ a_src,
                     float* __restrict__ a_dst) {
    int n = blockIdx.x;
    int f = threadIdx.x;                 // 128 threads, f = h*64+c
    __shared__ float w[F_IN * F1];
    __shared__ float xs[F_IN];
    for (int i = f; i < F_IN * F1; i += F1) w[i] = gw[i];
    if (f < F_IN) xs[f] = x[n * F_IN + f];
    __syncthreads();
    float acc = 0.f;
#pragma unroll
    for (int i = 0; i < F_IN; i++) acc += xs[i] * w[i * F1 + f];
    xw_bf[n * F1 + f] = f2bf(acc);
    int h = f >> 6, lane = f & 63;
    float p = acc * aw_src[f];
    float q = acc * aw_dst[f];
#pragma unroll
    for (int off = 32; off > 0; off >>= 1) {
        p += __shfl_down(p, off);
        q += __shfl_down(q, off);
    }
    if (lane == 0) { a_src[n * 2 + h] = p; a_dst[n * 2 + h] = q; }
}

// FUSED softmax + gather: one wave per dst node.
// Phase A (lane-per-edge): compute leaky logits, shfl-reduce max & sum -> alpha in reg.
// Phase B (lane-per-feature): broadcast alpha/src via shfl, 4-deep row-load pipeline.
__global__ void k_gat_gather(const int* __restrict__ rowptr, const int* __restrict__ csr_src,
                             const float* __restrict__ a_src, const float* __restrict__ a_dst,
                             const unsigned* __restrict__ xw32, float* __restrict__ h1) {
    int n = blockIdx.x * 4 + (threadIdx.x >> 6);
    int lane = threadIdx.x & 63;
    if (n >= NN) return;
    int j0 = rowptr[n], j1 = rowptr[n + 1];
    int deg = j1 - j0;
    float ad0 = a_dst[n * 2 + 0], ad1 = a_dst[n * 2 + 1];
    float acc0 = 0.f, acc1 = 0.f;
    bool lo = (lane < 32);
    if (deg <= 64) {
        // ---- phase A: in-register softmax ----
        int sl = 0;
        float l0 = -INFINITY, l1 = -INFINITY;
        if (lane < deg) {
            sl = csr_src[j0 + lane];
            l0 = a_src[sl * 2 + 0] + ad0;
            l1 = a_src[sl * 2 + 1] + ad1;
            l0 = l0 > 0.f ? l0 : 0.2f * l0;
            l1 = l1 > 0.f ? l1 : 0.2f * l1;
        }
        float m0 = l0, m1 = l1;
#pragma unroll
        for (int off = 32; off > 0; off >>= 1) {
            m0 = fmaxf(m0, __shfl_xor(m0, off));
            m1 = fmaxf(m1, __shfl_xor(m1, off));
        }
        float e0 = 0.f, e1 = 0.f;
        if (lane < deg) { e0 = expf(l0 - m0); e1 = expf(l1 - m1); }
        float s0 = e0, s1 = e1;
#pragma unroll
        for (int off = 32; off > 0; off >>= 1) {
            s0 += __shfl_xor(s0, off);
            s1 += __shfl_xor(s1, off);
        }
        unsigned al = pack2bf(e0 / (s0 + 1e-16f), e1 / (s1 + 1e-16f));
        // ---- phase B: gather ----
        int e = 0;
        for (; e + 4 <= deg; e += 4) {
            int s0i = __shfl(sl, e + 0), s1i = __shfl(sl, e + 1),
                s2i = __shfl(sl, e + 2), s3i = __shfl(sl, e + 3);
            unsigned b0 = __shfl(al, e + 0), b1 = __shfl(al, e + 1),
                     b2 = __shfl(al, e + 2), b3 = __shfl(al, e + 3);
            unsigned p0 = xw32[(size_t)s0i * 64 + lane];
            unsigned p1 = xw32[(size_t)s1i * 64 + lane];
            unsigned p2 = xw32[(size_t)s2i * 64 + lane];
            unsigned p3 = xw32[(size_t)s3i * 64 + lane];
            float w0 = lo ? lo_bf(b0) : hi_bf(b0);
            float w1 = lo ? lo_bf(b1) : hi_bf(b1);
            float w2 = lo ? lo_bf(b2) : hi_bf(b2);
            float w3 = lo ? lo_bf(b3) : hi_bf(b3);
            acc0 = fmaf(lo_bf(p0), w0, acc0); acc1 = fmaf(hi_bf(p0), w0, acc1);
            acc0 = fmaf(lo_bf(p1), w1, acc0); acc1 = fmaf(hi_bf(p1), w1, acc1);
            acc0 = fmaf(lo_bf(p2), w2, acc0); acc1 = fmaf(hi_bf(p2), w2, acc1);
            acc0 = fmaf(lo_bf(p3), w3, acc0); acc1 = fmaf(hi_bf(p3), w3, acc1);
        }
        for (; e < deg; e++) {
            int s = __shfl(sl, e); unsigned b = __shfl(al, e);
            unsigned p = xw32[(size_t)s * 64 + lane];
            float w = lo ? lo_bf(b) : hi_bf(b);
            acc0 = fmaf(lo_bf(p), w, acc0);
            acc1 = fmaf(hi_bf(p), w, acc1);
        }
    } else {
        // ---- rare deg>64: online max/sum pre-pass, then recompute alpha per chunk ----
        float m0 = -INFINITY, m1 = -INFINITY, s0 = 0.f, s1 = 0.f;
        for (int base = j0; base < j1; base += 64) {
            int myj = base + lane;
            float l0 = -INFINITY, l1 = -INFINITY;
            if (myj < j1) {
                int s = csr_src[myj];
                l0 = a_src[s * 2 + 0] + ad0;
                l1 = a_src[s * 2 + 1] + ad1;
                l0 = l0 > 0.f ? l0 : 0.2f * l0;
                l1 = l1 > 0.f ? l1 : 0.2f * l1;
            }
            float cm0 = l0, cm1 = l1;
#pragma unroll
            for (int off = 32; off > 0; off >>= 1) {
                cm0 = fmaxf(cm0, __shfl_xor(cm0, off));
                cm1 = fmaxf(cm1, __shfl_xor(cm1, off));
            }
            float nm0 = fmaxf(m0, cm0), nm1 = fmaxf(m1, cm1);
            float ce0 = (myj < j1) ? expf(l0 - nm0) : 0.f;
            float ce1 = (myj < j1) ? expf(l1 - nm1) : 0.f;
            float cs0 = ce0, cs1 = ce1;
#pragma unroll
            for (int off = 32; off > 0; off >>= 1) {
                cs0 += __shfl_xor(cs0, off);
                cs1 += __shfl_xor(cs1, off);
            }
            s0 = s0 * expf(m0 - nm0) + cs0;
            s1 = s1 * expf(m1 - nm1) + cs1;
            m0 = nm0; m1 = nm1;
        }
        float r0 = 1.0f / (s0 + 1e-16f), r1 = 1.0f / (s1 + 1e-16f);
        for (int base = j0; base < j1; base += 64) {
            int cnt = min(64, j1 - base);
            int myj = base + lane;
            int sl = 0; unsigned al = 0;
            if (myj < j1) {
                sl = csr_src[myj];
                float l0 = a_src[sl * 2 + 0] + ad0;
                float l1 = a_src[sl * 2 + 1] + ad1;
                l0 = l0 > 0.f ? l0 : 0.2f * l0;
                l1 = l1 > 0.f ? l1 : 0.2f * l1;
                al = pack2bf(expf(l0 - m0) * r0, expf(l1 - m1) * r1);
            }
            int e = 0;
            for (; e + 4 <= cnt; e += 4) {
                int s0i = __shfl(sl, e + 0), s1i = __shfl(sl, e + 1),
                    s2i = __shfl(sl, e + 2), s3i = __shfl(sl, e + 3);
                unsigned b0 = __shfl(al, e + 0), b1 = __shfl(al, e + 1),
                         b2 = __shfl(al, e + 2), b3 = __shfl(al, e + 3);
                unsigned p0 = xw32[(size_t)s0i * 64 + lane];
                unsigned p1 = xw32[(size_t)s1i * 64 + lane];
                unsigned p2 = xw32[(size_t)s2i * 64 + lane];
                unsigned p3 = xw32[(size_t)s3i * 64 + lane];
                float w0 = lo ? lo_bf(b0) : hi_bf(b0);
                float w1 = lo ? lo_bf(b1) : hi_bf(b1);
                float w2 = lo ? lo_bf(b2) : hi_bf(b2);
                float w3 = lo ? lo_bf(b3) : hi_bf(b3);
                acc0 = fmaf(lo_bf(p0), w0, acc0); acc1 = fmaf(hi_bf(p0), w0, acc1);
                acc0 = fmaf(lo_bf(p1), w1, acc0); acc1 = fmaf(hi_bf(p1), w1, acc1);
                acc0 = fmaf(lo_bf(p2), w2, acc0); acc1 = fmaf(hi_bf(p2), w2, acc1);
                acc0 = fmaf(lo_bf(p3), w3, acc0); acc1 = fmaf(hi_bf(p3), w3, acc1);
            }
            for (; e < cnt; e++) {
                int s = __shfl(sl, e); unsigned b = __shfl(al, e);
                unsigned p = xw32[(size_t)s * 64 + lane];
                float w = lo ? lo_bf(b) : hi_bf(b);
                acc0 = fmaf(lo_bf(p), w, acc0);
                acc1 = fmaf(hi_bf(p), w, acc1);
            }
        }
    }
    float2 o; o.x = acc0; o.y = acc1;
    *(float2*)&h1[(size_t)n * F1 + 2 * lane] = o;
}

// =================== BatchNorm ===================
__global__ void k_bn_stats(const float* __restrict__ h, int nfeat, float* __restrict__ sums) {
    int f = threadIdx.x;                       // blockDim.x == nfeat
    int rows = (NN + gridDim.x - 1) / gridDim.x;
    int r0 = blockIdx.x * rows;
    int r1 = min(NN, r0 + rows);
    float s = 0.f, ss = 0.f;
    for (int r = r0; r < r1; r++) {
        float v = h[r * nfeat + f];
        s += v; ss += v * v;
    }
    atomicAdd(&sums[f], s);
    atomicAdd(&sums[nfeat + f], ss);
}

__global__ void k_bn_apply(float* __restrict__ h, const float* __restrict__ sums,
                           const float* __restrict__ g, const float* __restrict__ b,
                           int nfeat, int total) {
    int i = blockIdx.x * blockDim.x + threadIdx.x;
    if (i >= total) return;
    int f = i & (nfeat - 1);
    float m = sums[f] * (1.0f / NN);
    float var = sums[nfeat + f] * (1.0f / NN) - m * m;
    float v = (h[i] - m) * rsqrtf(var + 1e-5f) * g[f] + b[f];
    h[i] = v > 0.f ? v : expm1f(v);
}

// =================== SAGE ===================
// u (bf16) = h1 @ wl ; v (f32) = h1 @ wr  — dual GEMM, packed bf16 weights,
// register double-buffered row loads (prefetch k+4 while computing k).
__global__ void k_sage_dualgemm(const float* __restrict__ h1,
                                const unsigned* __restrict__ wpack,
                                ushort* __restrict__ u_bf, float* __restrict__ v) {
    __shared__ unsigned swp[F1 * F2];   // 32 KB (packed wl|wr)
    int t = threadIdx.x;
    const uint4* wp4 = (const uint4*)wpack;
    uint4* swp4 = (uint4*)swp;
    for (int i = t; i < F1 * F2 / 4; i += 256) swp4[i] = wp4[i];
    __syncthreads();
    int w = t >> 6, j = t & 63;
    int row0 = blockIdx.x * GROWS + w * 8;
    float accu[8] = {0.f, 0.f, 0.f, 0.f, 0.f, 0.f, 0.f, 0.f};
    float accv[8] = {0.f, 0.f, 0.f, 0.f, 0.f, 0.f, 0.f, 0.f};
    float4 a[8], b[8];
#pragma unroll
    for (int r = 0; r < 8; r++)
        a[r] = *(const float4*)&h1[(size_t)(row0 + r) * F1];
    for (int k = 0; k < F1; k += 4) {
        if (k + 4 < F1) {
#pragma unroll
            for (int r = 0; r < 8; r++)
                b[r] = *(const float4*)&h1[(size_t)(row0 + r) * F1 + k + 4];
        }
#pragma unroll
        for (int kk = 0; kk < 4; kk++) {
            unsigned wp = swp[(k + kk) * F2 + j];
            float wlj = lo_bf(wp);
            float wrj = hi_bf(wp);
#pragma unroll
            for (int r = 0; r < 8; r++) {
                float av = (&a[r].x)[kk];
                accu[r] += av * wlj;
                accv[r] += av * wrj;
            }
        }
#pragma unroll
        for (int r = 0; r < 8; r++) a[r] = b[r];
    }
#pragma unroll
    for (int r = 0; r < 8; r++) {
        u_bf[(size_t)(row0 + r) * F2 + j] = f2bf(accu[r]);
        v[(size_t)(row0 + r) * F2 + j] = accv[r];
    }
}

// h2raw[n] = mean-gather(u_bf16) + v[n] + bl
__global__ void k_sage_gather2(const int* __restrict__ rowptr, const int* __restrict__ csr_src,
                               const ushort* __restrict__ u_bf, const float* __restrict__ v,
                               const float* __restrict__ bl, float* __restrict__ h2) {
    int n = blockIdx.x * 4 + (threadIdx.x >> 6);
    int lane = threadIdx.x & 63;
    if (n >= NN) return;
    int j0 = rowptr[n], j1 = rowptr[n + 1];
    float a = 0.f;
    for (int base = j0; base < j1; base += 64) {
        int cnt = min(64, j1 - base);
        int myj = base + lane;
        int sl = (myj < j1) ? csr_src[myj] : 0;
        int e = 0;
        for (; e + 4 <= cnt; e += 4) {
            int s0 = __shfl(sl, e + 0), s1 = __shfl(sl, e + 1),
                s2 = __shfl(sl, e + 2), s3 = __shfl(sl, e + 3);
            float t0 = bf2f(u_bf[(size_t)s0 * F2 + lane]);
            float t1 = bf2f(u_bf[(size_t)s1 * F2 + lane]);
            float t2 = bf2f(u_bf[(size_t)s2 * F2 + lane]);
            float t3 = bf2f(u_bf[(size_t)s3 * F2 + lane]);
            a += (t0 + t1) + (t2 + t3);
        }
        for (; e < cnt; e++) {
            int s = __shfl(sl, e);
            a += bf2f(u_bf[(size_t)s * F2 + lane]);
        }
    }
    float inv = 1.0f / fmaxf((float)(j1 - j0), 1.0f);
    h2[(size_t)n * F2 + lane] = a * inv + v[(size_t)n * F2 + lane] + bl[lane];
}

__global__ void k_dinv(const int* __restrict__ degi, float* __restrict__ dinv) {
    int i = blockIdx.x * blockDim.x + threadIdx.x;
    if (i < NN) dinv[i] = rsqrtf((float)degi[i] + 1.0f);
}

// =================== GCN ===================
// hwd (bf16) = (h2 @ gcn_w) * dinv[row]  — register double-buffered row loads
__global__ void k_gcn_gemm(const float* __restrict__ h2, const float* __restrict__ wmat,
                           const float* __restrict__ dinv, ushort* __restrict__ hwd_bf) {
    __shared__ float sw[F2 * F2];    // 16 KB
    int t = threadIdx.x;
    const float4* w4 = (const float4*)wmat;
    float4* sw4 = (float4*)sw;
    for (int i = t; i < F2 * F2 / 4; i += 256) sw4[i] = w4[i];
    __syncthreads();
    int w = t >> 6, j = t & 63;
    int row0 = blockIdx.x * GROWS + w * 8;
    float acc[8] = {0.f, 0.f, 0.f, 0.f, 0.f, 0.f, 0.f, 0.f};
    float4 a[8], b[8];
#pragma unroll
    for (int r = 0; r < 8; r++)
        a[r] = *(const float4*)&h2[(size_t)(row0 + r) * F2];
    for (int k = 0; k < F2; k += 4) {
        if (k + 4 < F2) {
#pragma unroll
            for (int r = 0; r < 8; r++)
                b[r] = *(const float4*)&h2[(size_t)(row0 + r) * F2 + k + 4];
        }
#pragma unroll
        for (int kk = 0; kk < 4; kk++) {
            float wkj = sw[(k + kk) * F2 + j];
#pragma unroll
            for (int r = 0; r < 8; r++)
                acc[r] += (&a[r].x)[kk] * wkj;
        }
#pragma unroll
        for (int r = 0; r < 8; r++) a[r] = b[r];
    }
#pragma unroll
    for (int r = 0; r < 8; r++)
        hwd_bf[(size_t)(row0 + r) * F2 + j] = f2bf(acc[r] * dinv[row0 + r]);
}

// h3 = dinv[n]*(sum_src hwd[s] + hwd[n]) + gb
__global__ void k_gcn_gather(const int* __restrict__ rowptr, const int* __restrict__ csr_src,
                             const ushort* __restrict__ hwd_bf, const float* __restrict__ dinv,
                             const float* __restrict__ gb, float* __restrict__ h3) {
    int n = blockIdx.x * 4 + (threadIdx.x >> 6);
    int lane = threadIdx.x & 63;
    if (n >= NN) return;
    int j0 = rowptr[n], j1 = rowptr[n + 1];
    float acc = 0.f;
    for (int base = j0; base < j1; base += 64) {
        int cnt = min(64, j1 - base);
        int myj = base + lane;
        int sl = (myj < j1) ? csr_src[myj] : 0;
        int e = 0;
        for (; e + 4 <= cnt; e += 4) {
            int s0 = __shfl(sl, e + 0), s1 = __shfl(sl, e + 1),
                s2 = __shfl(sl, e + 2), s3 = __shfl(sl, e + 3);
            float t0 = bf2f(hwd_bf[(size_t)s0 * F2 + lane]);
            float t1 = bf2f(hwd_bf[(size_t)s1 * F2 + lane]);
            float t2 = bf2f(hwd_bf[(size_t)s2 * F2 + lane]);
            float t3 = bf2f(hwd_bf[(size_t)s3 * F2 + lane]);
            acc += (t0 + t1) + (t2 + t3);
        }
        for (; e < cnt; e++) {
            int s = __shfl(sl, e);
            acc += bf2f(hwd_bf[(size_t)s * F2 + lane]);
        }
    }
    float di = dinv[n];
    acc += bf2f(hwd_bf[(size_t)n * F2 + lane]);
    h3[(size_t)n * F2 + lane] = acc * di + gb[lane];
}

// =================== fused BN3-apply + ELU + segmented pool ===================
__global__ void k_bn3_pool(const float* __restrict__ h3raw, const float* __restrict__ sums,
                           const float* __restrict__ g3, const float* __restrict__ b3,
                           const int* __restrict__ batch, float* __restrict__ psum,
                           unsigned* __restrict__ pmax, float* __restrict__ cnt) {
    int lane = threadIdx.x;   // 64 threads = one wave, lane = feature
    int rows = (NN + gridDim.x - 1) / gridDim.x;
    int r0 = blockIdx.x * rows;
    int r1 = min(NN, r0 + rows);
    if (r0 >= r1) return;
    float m = sums[lane] * (1.0f / NN);
    float var = sums[F2 + lane] * (1.0f / NN) - m * m;
    float sc = rsqrtf(var + 1e-5f) * g3[lane];
    float bb = b3[lane];
    int curg = batch[r0];
    float ls = 0.f, lm = -INFINITY;
    int run = 0;
    for (int r = r0; r < r1; r++) {
        int gg = batch[r];
        if (gg != curg) {
            atomicAdd(&psum[curg * F2 + lane], ls);
            atomicMax(&pmax[curg * F2 + lane], enc_f(lm));
            if (lane == 0) atomicAdd(&cnt[curg], (float)run);
            curg = gg; ls = 0.f; lm = -INFINITY; run = 0;
        }
        float v = (h3raw[r * F2 + lane] - m) * sc + bb;
        v = v > 0.f ? v : expm1f(v);
        ls += v; lm = fmaxf(lm, v); run++;
    }
    atomicAdd(&psum[curg * F2 + lane], ls);
    atomicMax(&pmax[curg * F2 + lane], enc_f(lm));
    if (lane == 0) atomicAdd(&cnt[curg], (float)run);
}

// =================== classifier ===================
__global__ void k_cls(const float* __restrict__ psum, const unsigned* __restrict__ pmax,
                      const float* __restrict__ cnt, const float* __restrict__ w1,
                      const float* __restrict__ b1, const float* __restrict__ w2,
                      const float* __restrict__ b2, float* __restrict__ out) {
    int g = blockIdx.x;
    int j = threadIdx.x;  // 64 threads
    __shared__ float z[2 * F2];
    __shared__ float hid[F2];
    float c = fmaxf(cnt[g], 1.0f);
    z[j] = psum[g * F2 + j] / c;
    float mv = dec_f(pmax[g * F2 + j]);
    z[F2 + j] = isfinite(mv) ? mv : 0.f;
    __syncthreads();
    float acc = b1[j];
#pragma unroll 8
    for (int k = 0; k < 2 * F2; k++) acc += z[k] * w1[k * F2 + j];
    hid[j] = fmaxf(acc, 0.f);
    __syncthreads();
    if (j < NCLS) {
        float o = b2[j];
#pragma unroll 8
        for (int k = 0; k < F2; k++) o += hid[k] * w2[k * NCLS + j];
        out[g * NCLS + j] = o;
    }
}

extern "C" void kernel_launch(void* const* d_in, const int* in_sizes, int n_in,
                              void* d_out, int out_size, void* d_ws, size_t ws_size,
                              hipStream_t stream) {
    const float* x       = (const float*)d_in[0];
    const int*   ei      = (const int*)d_in[1];
    const int*   batch   = (const int*)d_in[2];
    const float* gat_w   = (const float*)d_in[3];
    const float* att_src = (const float*)d_in[4];
    const float* att_dst = (const float*)d_in[5];
    // d_in[6] gat_b: cancels inside BN1 (constant shift removed by mean subtraction)
    const float* bn1_g   = (const float*)d_in[7];
    const float* bn1_b   = (const float*)d_in[8];
    const float* sage_wl = (const float*)d_in[9];
    const float* sage_bl = (const float*)d_in[10];
    const float* sage_wr = (const float*)d_in[11];
    const float* bn2_g   = (const float*)d_in[12];
    const float* bn2_b   = (const float*)d_in[13];
    const float* gcn_w   = (const float*)d_in[14];
    const float* gcn_b   = (const float*)d_in[15];
    const float* bn3_g   = (const float*)d_in[16];
    const float* bn3_b   = (const float*)d_in[17];
    const float* w1      = (const float*)d_in[18];
    const float* b1      = (const float*)d_in[19];
    const float* w2      = (const float*)d_in[20];
    const float* b2      = (const float*)d_in[21];
    float* out = (float*)d_out;

    float* ws = (float*)d_ws;
    // workspace layout (4-byte units)
    size_t o_A    = 0;                        // NN*F1 floats region, aliased (see below)
    size_t o_h1   = o_A   + (size_t)NN * F1;  // NN*F1 f32: GAT output (post-BN1 in place)
    size_t o_h2   = o_h1  + (size_t)NN * F1;  // NN*F2 f32 (post-BN2 in place)
    size_t o_csr  = o_h2  + (size_t)NN * F2;  // E ints (csr_src)
    size_t o_rp   = o_csr + (size_t)NE;       // N+1 ints (rowptr)
    size_t o_deg  = o_rp  + (size_t)(NN + 1); // N ints (degi)
    size_t o_bs   = o_deg + (size_t)NN;       // 512 ints (block sums)
    size_t o_asrc = o_bs  + 512;              // N*2
    size_t o_adst = o_asrc + (size_t)NN * 2;  // N*2
    size_t o_dinv = o_adst + (size_t)NN * 2;  // N
    size_t o_sums = o_dinv + (size_t)NN;      // 256
    size_t o_wp   = o_sums + 256;             // F1*F2 uints (packed sage weights)
    size_t o_psum = o_wp   + (size_t)F1 * F2; // G*F2
    size_t o_pmax = o_psum + (size_t)NG * F2; // G*F2
    size_t o_cnt  = o_pmax + (size_t)NG * F2; // G

    float* A    = ws + o_A;
    float* h1   = ws + o_h1;
    float* h2   = ws + o_h2;
    int* csr_src = (int*)(ws + o_csr);
    int* rowptr  = (int*)(ws + o_rp);
    int* degi    = (int*)(ws + o_deg);
    int* bsum    = (int*)(ws + o_bs);
    float* asr  = ws + o_asrc;
    float* ads  = ws + o_adst;
    float* dinv = ws + o_dinv;
    float* sums = ws + o_sums;
    unsigned* wpack = (unsigned*)(ws + o_wp);
    float* psum = ws + o_psum;
    unsigned* pmax = (unsigned*)(ws + o_pmax);
    float* cnt  = ws + o_cnt;

    // region-A role aliases (lifetimes disjoint):
    unsigned* staged = (unsigned*)A;                    // CSR build: NE entries (6.4 MB)
    int*    ghist  = (int*)(A + 2 * 1024 * 1024);       // CSR build: NCHUNK*NBUCK ints (at 8 MB)
    ushort* xw_bf  = (ushort*)A;                        // GAT: NN*F1 bf16 (25.6 MB)
    ushort* u_bf   = (ushort*)A;                        // SAGE: NN*F2 bf16 (xw dead)
    float*  vmat   = A + (size_t)NN * F2 / 2;           // SAGE: NN*F2 f32
    ushort* hwd_bf = (ushort*)A;                        // GCN: NN*F2 bf16 (u dead)
    float*  h3     = A + (size_t)NN * F2 / 2;           // GCN out: NN*F2 f32 (v dead)

    // ---- CSR build: count + node scan, then chunk-major radix ----
    hipMemsetAsync(degi, 0, sizeof(int) * NN, stream);
    k_count<<<(NE + 255) / 256, 256, 0, stream>>>(ei, degi);
    k_scan1<<<NB_SCAN, 256, 0, stream>>>(degi, rowptr, bsum);
    k_scan2<<<1, 512, 0, stream>>>(bsum, NB_SCAN);
    k_scan3<<<NB_SCAN, 256, 0, stream>>>(rowptr, bsum);
    k_hist<<<NCHUNK, 256, 0, stream>>>(ei, ghist);
    k_chunkscan<<<(NBUCK + 255) / 256, 256, 0, stream>>>(ghist, rowptr);
    k_scatter2<<<NCHUNK, 256, 0, stream>>>(ei, ghist, staged);
    k_bucket_sort<<<NBUCK, 256, 0, stream>>>(staged, rowptr, csr_src);

    // ---- GAT (softmax fused into gather) ----
    k_xw<<<NN, F1, 0, stream>>>(x, gat_w, att_src, att_dst, xw_bf, asr, ads);
    k_gat_gather<<<(NN + 3) / 4, 256, 0, stream>>>(rowptr, csr_src, asr, ads,
                                                   (const unsigned*)xw_bf, h1);
    hipMemsetAsync(sums, 0, sizeof(float) * 256, stream);
    k_bn_stats<<<512, F1, 0, stream>>>(h1, F1, sums);
    k_bn_apply<<<(NN * F1 + 255) / 256, 256, 0, stream>>>(h1, sums, bn1_g, bn1_b, F1, NN * F1);

    // ---- SAGE: dense dual-GEMM (packed bf16 weights, reg dbuf) then bf16 mean-gather ----
    k_packw<<<(F1 * F2 + 255) / 256, 256, 0, stream>>>(sage_wl, sage_wr, wpack, F1 * F2);
    k_sage_dualgemm<<<NN / GROWS, 256, 0, stream>>>(h1, wpack, u_bf, vmat);
    k_sage_gather2<<<(NN + 3) / 4, 256, 0, stream>>>(rowptr, csr_src, u_bf, vmat, sage_bl, h2);
    hipMemsetAsync(sums, 0, sizeof(float) * 256, stream);
    k_bn_stats<<<512, F2, 0, stream>>>(h2, F2, sums);
    k_bn_apply<<<(NN * F2 + 255) / 256, 256, 0, stream>>>(h2, sums, bn2_g, bn2_b, F2, NN * F2);

    // ---- GCN ----
    k_dinv<<<(NN + 255) / 256, 256, 0, stream>>>(degi, dinv);
    k_gcn_gemm<<<NN / GROWS, 256, 0, stream>>>(h2, gcn_w, dinv, hwd_bf);
    k_gcn_gather<<<(NN + 3) / 4, 256, 0, stream>>>(rowptr, csr_src, hwd_bf, dinv, gcn_b, h3);
    hipMemsetAsync(sums, 0, sizeof(float) * 256, stream);
    k_bn_stats<<<512, F2, 0, stream>>>(h3, F2, sums);

    // ---- fused BN3 + ELU + pooling, then classifier ----
    hipMemsetAsync(psum, 0, sizeof(float) * NG * F2, stream);
    hipMemsetAsync(cnt, 0, sizeof(float) * NG, stream);
    k_fill_u32<<<(NG * F2 + 255) / 256, 256, 0, stream>>>(pmax, ENC_NEG_INF, NG * F2);
    k_bn3_pool<<<512, F2, 0, stream>>>(h3, sums, bn3_g, bn3_b, batch, psum, pmax, cnt);
    k_cls<<<NG, F2, 0, stream>>>(psum, pmax, cnt, w1, b1, w2, b2, out);
}

// Round 15
// 692.052 us; speedup vs baseline: 1.9638x; 1.2405x over previous
//
#include <hip/hip_runtime.h>
#include <hip/hip_bf16.h>
#include <math.h>

#define NN 100000      // nodes
#define NE 1600000     // edges
#define NG 64          // graphs
#define F_IN 5
#define F1 128         // H*HID
#define F2 64          // HID
#define NCLS 4
#define NB_SCAN ((NN + 255) / 256)   // 391 blocks in node scan level 1
#define NCHUNK 250                   // edge chunks (250 * 6400 = NE)
#define CH_E 6400                    // edges per chunk
#define NBUCK ((NN + 255) / 256)     // 391 dst buckets of 256 nodes
#define CAPB 6144                    // bucket capacity in LDS sort

typedef unsigned short ushort;
typedef __bf16 bf16x8 __attribute__((ext_vector_type(8)));
typedef float f32x4 __attribute__((ext_vector_type(4)));

// ---------- bf16 helpers (round-to-nearest-even pack) ----------
__device__ __forceinline__ ushort f2bf(float f) {
    unsigned u = __float_as_uint(f);
    u = (u + 0x7fffu + ((u >> 16) & 1u)) >> 16;
    return (ushort)u;
}
__device__ __forceinline__ float bf2f(ushort h) {
    return __uint_as_float(((unsigned)h) << 16);
}
__device__ __forceinline__ unsigned pack2bf(float a, float b) {
    return (unsigned)f2bf(a) | ((unsigned)f2bf(b) << 16);
}
__device__ __forceinline__ float lo_bf(unsigned p) { return __uint_as_float(p << 16); }
__device__ __forceinline__ float hi_bf(unsigned p) { return __uint_as_float(p & 0xffff0000u); }

// ---------- order-preserving float<->uint encoding for atomicMax ----------
__device__ __forceinline__ unsigned enc_f(float f) {
    unsigned b = __float_as_uint(f);
    return (b & 0x80000000u) ? ~b : (b | 0x80000000u);
}
__device__ __forceinline__ float dec_f(unsigned k) {
    unsigned b = (k & 0x80000000u) ? (k ^ 0x80000000u) : ~k;
    return __uint_as_float(b);
}
#define ENC_NEG_INF 0x007FFFFFu   // enc_f(-inf)

__global__ void k_fill_u32(unsigned* p, unsigned v, int n) {
    int i = blockIdx.x * blockDim.x + threadIdx.x;
    if (i < n) p[i] = v;
}

// =================== MFMA B-fragment packing ===================
// layout idx = ((ks*CT + ct)*64 + lane)*8 + e ; value B[ks*32+(lane>>4)*8+e][ct*16+(lane&15)]
__global__ void k_packfrag_dual(const float* __restrict__ wl, const float* __restrict__ wr,
                                ushort* __restrict__ frag) {
    int idx = blockIdx.x * 256 + threadIdx.x;
    if (idx >= 4 * 8 * 64 * 8) return;
    int e = idx & 7;
    int lane = (idx >> 3) & 63;
    int ct = (idx >> 9) & 7;
    int ks = idx >> 12;
    int k = ks * 32 + (lane >> 4) * 8 + e;
    int n = ct * 16 + (lane & 15);
    float val = (n < 64) ? wl[k * 64 + n] : wr[k * 64 + (n - 64)];
    frag[idx] = f2bf(val);
}

__global__ void k_packfrag_gcn(const float* __restrict__ wm, ushort* __restrict__ frag) {
    int idx = blockIdx.x * 256 + threadIdx.x;
    if (idx >= 2 * 4 * 64 * 8) return;
    int e = idx & 7;
    int lane = (idx >> 3) & 63;
    int ct = (idx >> 9) & 3;
    int ks = idx >> 11;
    int k = ks * 32 + (lane >> 4) * 8 + e;
    int n = ct * 16 + (lane & 15);
    frag[idx] = f2bf(wm[k * 64 + n]);
}

// =================== CSR build (chunk-major two-level counting sort) ===================
__global__ void k_count(const int* __restrict__ ei, int* __restrict__ degi) {
    int e = blockIdx.x * blockDim.x + threadIdx.x;
    if (e < NE) atomicAdd(&degi[ei[NE + e]], 1);
}

__global__ void k_scan1(const int* __restrict__ degi, int* __restrict__ rowptr,
                        int* __restrict__ bsum) {
    __shared__ int sh[256];
    int i = blockIdx.x * 256 + threadIdx.x;
    int v = (i < NN) ? degi[i] : 0;
    sh[threadIdx.x] = v;
    __syncthreads();
    for (int off = 1; off < 256; off <<= 1) {
        int t = (threadIdx.x >= off) ? sh[threadIdx.x - off] : 0;
        __syncthreads();
        sh[threadIdx.x] += t;
        __syncthreads();
    }
    if (i < NN) rowptr[i] = sh[threadIdx.x] - v;   // exclusive, block-local
    if (threadIdx.x == 255) bsum[blockIdx.x] = sh[255];
}

__global__ void k_scan2(int* __restrict__ bsum, int nb) {
    __shared__ int sh[512];
    int v = (threadIdx.x < nb) ? bsum[threadIdx.x] : 0;
    sh[threadIdx.x] = v;
    __syncthreads();
    for (int off = 1; off < 512; off <<= 1) {
        int t = (threadIdx.x >= off) ? sh[threadIdx.x - off] : 0;
        __syncthreads();
        sh[threadIdx.x] += t;
        __syncthreads();
    }
    if (threadIdx.x < nb) bsum[threadIdx.x] = sh[threadIdx.x] - v;   // exclusive
}

__global__ void k_scan3(int* __restrict__ rowptr, const int* __restrict__ bsum) {
    int i = blockIdx.x * 256 + threadIdx.x;
    if (i == 0) rowptr[NN] = NE;
    if (i >= NN) return;
    rowptr[i] += bsum[blockIdx.x];
}

// pass 1: per-chunk histogram over 391 dst buckets
__global__ void k_hist(const int* __restrict__ ei, int* __restrict__ ghist) {
    __shared__ int lh[NBUCK];
    int c = blockIdx.x, t = threadIdx.x;
    for (int b = t; b < NBUCK; b += 256) lh[b] = 0;
    __syncthreads();
    int e0 = c * CH_E;
#pragma unroll
    for (int i = 0; i < CH_E / 256; i++) {
        int d = ei[NE + e0 + t + i * 256];
        atomicAdd(&lh[d >> 8], 1);
    }
    __syncthreads();
    for (int b = t; b < NBUCK; b += 256) ghist[c * NBUCK + b] = lh[b];
}

// pass 2: per-bucket serial prefix over chunks (in place: ghist -> offsets)
__global__ void k_chunkscan(int* __restrict__ ghist, const int* __restrict__ rowptr) {
    int b = blockIdx.x * blockDim.x + threadIdx.x;
    if (b >= NBUCK) return;
    int run = rowptr[b * 256];           // bucket base in csr order
    for (int c = 0; c < NCHUNK; c++) {
        int h = ghist[c * NBUCK + b];
        ghist[c * NBUCK + b] = run;
        run += h;
    }
}

// pass 3: scatter into bucket-major staged array (packed (dlow<<17)|src)
__global__ void k_scatter2(const int* __restrict__ ei, const int* __restrict__ ghist,
                           unsigned* __restrict__ staged) {
    __shared__ int lcur[NBUCK];
    int c = blockIdx.x, t = threadIdx.x;
    for (int b = t; b < NBUCK; b += 256) lcur[b] = ghist[c * NBUCK + b];
    __syncthreads();
    int e0 = c * CH_E;
#pragma unroll
    for (int i = 0; i < CH_E / 256; i++) {
        int e = e0 + t + i * 256;
        int s = ei[e];
        int d = ei[NE + e];
        int pos = atomicAdd(&lcur[d >> 8], 1);
        staged[pos] = (((unsigned)(d & 255)) << 17) | (unsigned)s;
    }
}

// pass 4: per-bucket LDS counting sort by low 8 dst bits -> coalesced csr_src
__global__ void k_bucket_sort(const unsigned* __restrict__ staged,
                              const int* __restrict__ rowptr, int* __restrict__ csr_src) {
    __shared__ unsigned ein[CAPB];
    __shared__ unsigned sout[CAPB];
    __shared__ int lcur[256];
    int b = blockIdx.x, t = threadIdx.x;
    int n0 = b * 256;
    int nend = min(n0 + 256, NN);
    int nn = nend - n0;
    int g0 = rowptr[n0];
    int m = rowptr[nend] - g0;
    if (t < nn) lcur[t] = rowptr[n0 + t] - g0;
    __syncthreads();
    if (m <= CAPB) {
        for (int i = t; i < m; i += 256) ein[i] = staged[g0 + i];
        __syncthreads();
        for (int i = t; i < m; i += 256) {
            unsigned u = ein[i];
            int pos = atomicAdd(&lcur[u >> 17], 1);
            sout[pos] = u & 0x1FFFFu;
        }
        __syncthreads();
        for (int i = t; i < m; i += 256) csr_src[g0 + i] = (int)sout[i];
    } else {
        for (int i = t; i < m; i += 256) {
            unsigned u = staged[g0 + i];
            int pos = atomicAdd(&lcur[u >> 17], 1);
            csr_src[g0 + pos] = (int)(u & 0x1FFFFu);
        }
    }
}

// =================== GAT ===================
// xw (bf16) = x @ gat_w ; a_src/a_dst per-node attention logits
__global__ void k_xw(const float* __restrict__ x, const float* __restrict__ gw,
                     const float* __restrict__ aw_src, const float* __restrict__ aw_dst,
                     ushort* __restrict__ xw_bf, float* __restrict__ a_src,
                     float* __restrict__ a_dst) {
    int n = blockIdx.x;
    int f = threadIdx.x;                 // 128 threads, f = h*64+c
    __shared__ float w[F_IN * F1];
    __shared__ float xs[F_IN];
    for (int i = f; i < F_IN * F1; i += F1) w[i] = gw[i];
    if (f < F_IN) xs[f] = x[n * F_IN + f];
    __syncthreads();
    float acc = 0.f;
#pragma unroll
    for (int i = 0; i < F_IN; i++) acc += xs[i] * w[i * F1 + f];
    xw_bf[n * F1 + f] = f2bf(acc);
    int h = f >> 6, lane = f & 63;
    float p = acc * aw_src[f];
    float q = acc * aw_dst[f];
#pragma unroll
    for (int off = 32; off > 0; off >>= 1) {
        p += __shfl_down(p, off);
        q += __shfl_down(q, off);
    }
    if (lane == 0) { a_src[n * 2 + h] = p; a_dst[n * 2 + h] = q; }
}

// FUSED softmax + gather: one wave per dst node.
__global__ void k_gat_gather(const int* __restrict__ rowptr, const int* __restrict__ csr_src,
                             const float* __restrict__ a_src, const float* __restrict__ a_dst,
                             const unsigned* __restrict__ xw32, float* __restrict__ h1) {
    int n = blockIdx.x * 4 + (threadIdx.x >> 6);
    int lane = threadIdx.x & 63;
    if (n >= NN) return;
    int j0 = rowptr[n], j1 = rowptr[n + 1];
    int deg = j1 - j0;
    float ad0 = a_dst[n * 2 + 0], ad1 = a_dst[n * 2 + 1];
    float acc0 = 0.f, acc1 = 0.f;
    bool lo = (lane < 32);
    if (deg <= 64) {
        int sl = 0;
        float l0 = -INFINITY, l1 = -INFINITY;
        if (lane < deg) {
            sl = csr_src[j0 + lane];
            l0 = a_src[sl * 2 + 0] + ad0;
            l1 = a_src[sl * 2 + 1] + ad1;
            l0 = l0 > 0.f ? l0 : 0.2f * l0;
            l1 = l1 > 0.f ? l1 : 0.2f * l1;
        }
        float m0 = l0, m1 = l1;
#pragma unroll
        for (int off = 32; off > 0; off >>= 1) {
            m0 = fmaxf(m0, __shfl_xor(m0, off));
            m1 = fmaxf(m1, __shfl_xor(m1, off));
        }
        float e0 = 0.f, e1 = 0.f;
        if (lane < deg) { e0 = expf(l0 - m0); e1 = expf(l1 - m1); }
        float s0 = e0, s1 = e1;
#pragma unroll
        for (int off = 32; off > 0; off >>= 1) {
            s0 += __shfl_xor(s0, off);
            s1 += __shfl_xor(s1, off);
        }
        unsigned al = pack2bf(e0 / (s0 + 1e-16f), e1 / (s1 + 1e-16f));
        int e = 0;
        for (; e + 4 <= deg; e += 4) {
            int s0i = __shfl(sl, e + 0), s1i = __shfl(sl, e + 1),
                s2i = __shfl(sl, e + 2), s3i = __shfl(sl, e + 3);
            unsigned b0 = __shfl(al, e + 0), b1 = __shfl(al, e + 1),
                     b2 = __shfl(al, e + 2), b3 = __shfl(al, e + 3);
            unsigned p0 = xw32[(size_t)s0i * 64 + lane];
            unsigned p1 = xw32[(size_t)s1i * 64 + lane];
            unsigned p2 = xw32[(size_t)s2i * 64 + lane];
            unsigned p3 = xw32[(size_t)s3i * 64 + lane];
            float w0 = lo ? lo_bf(b0) : hi_bf(b0);
            float w1 = lo ? lo_bf(b1) : hi_bf(b1);
            float w2 = lo ? lo_bf(b2) : hi_bf(b2);
            float w3 = lo ? lo_bf(b3) : hi_bf(b3);
            acc0 = fmaf(lo_bf(p0), w0, acc0); acc1 = fmaf(hi_bf(p0), w0, acc1);
            acc0 = fmaf(lo_bf(p1), w1, acc0); acc1 = fmaf(hi_bf(p1), w1, acc1);
            acc0 = fmaf(lo_bf(p2), w2, acc0); acc1 = fmaf(hi_bf(p2), w2, acc1);
            acc0 = fmaf(lo_bf(p3), w3, acc0); acc1 = fmaf(hi_bf(p3), w3, acc1);
        }
        for (; e < deg; e++) {
            int s = __shfl(sl, e); unsigned b = __shfl(al, e);
            unsigned p = xw32[(size_t)s * 64 + lane];
            float w = lo ? lo_bf(b) : hi_bf(b);
            acc0 = fmaf(lo_bf(p), w, acc0);
            acc1 = fmaf(hi_bf(p), w, acc1);
        }
    } else {
        float m0 = -INFINITY, m1 = -INFINITY, s0 = 0.f, s1 = 0.f;
        for (int base = j0; base < j1; base += 64) {
            int myj = base + lane;
            float l0 = -INFINITY, l1 = -INFINITY;
            if (myj < j1) {
                int s = csr_src[myj];
                l0 = a_src[s * 2 + 0] + ad0;
                l1 = a_src[s * 2 + 1] + ad1;
                l0 = l0 > 0.f ? l0 : 0.2f * l0;
                l1 = l1 > 0.f ? l1 : 0.2f * l1;
            }
            float cm0 = l0, cm1 = l1;
#pragma unroll
            for (int off = 32; off > 0; off >>= 1) {
                cm0 = fmaxf(cm0, __shfl_xor(cm0, off));
                cm1 = fmaxf(cm1, __shfl_xor(cm1, off));
            }
            float nm0 = fmaxf(m0, cm0), nm1 = fmaxf(m1, cm1);
            float ce0 = (myj < j1) ? expf(l0 - nm0) : 0.f;
            float ce1 = (myj < j1) ? expf(l1 - nm1) : 0.f;
            float cs0 = ce0, cs1 = ce1;
#pragma unroll
            for (int off = 32; off > 0; off >>= 1) {
                cs0 += __shfl_xor(cs0, off);
                cs1 += __shfl_xor(cs1, off);
            }
            s0 = s0 * expf(m0 - nm0) + cs0;
            s1 = s1 * expf(m1 - nm1) + cs1;
            m0 = nm0; m1 = nm1;
        }
        float r0 = 1.0f / (s0 + 1e-16f), r1 = 1.0f / (s1 + 1e-16f);
        for (int base = j0; base < j1; base += 64) {
            int cnt = min(64, j1 - base);
            int myj = base + lane;
            int sl = 0; unsigned al = 0;
            if (myj < j1) {
                sl = csr_src[myj];
                float l0 = a_src[sl * 2 + 0] + ad0;
                float l1 = a_src[sl * 2 + 1] + ad1;
                l0 = l0 > 0.f ? l0 : 0.2f * l0;
                l1 = l1 > 0.f ? l1 : 0.2f * l1;
                al = pack2bf(expf(l0 - m0) * r0, expf(l1 - m1) * r1);
            }
            int e = 0;
            for (; e + 4 <= cnt; e += 4) {
                int s0i = __shfl(sl, e + 0), s1i = __shfl(sl, e + 1),
                    s2i = __shfl(sl, e + 2), s3i = __shfl(sl, e + 3);
                unsigned b0 = __shfl(al, e + 0), b1 = __shfl(al, e + 1),
                         b2 = __shfl(al, e + 2), b3 = __shfl(al, e + 3);
                unsigned p0 = xw32[(size_t)s0i * 64 + lane];
                unsigned p1 = xw32[(size_t)s1i * 64 + lane];
                unsigned p2 = xw32[(size_t)s2i * 64 + lane];
                unsigned p3 = xw32[(size_t)s3i * 64 + lane];
                float w0 = lo ? lo_bf(b0) : hi_bf(b0);
                float w1 = lo ? lo_bf(b1) : hi_bf(b1);
                float w2 = lo ? lo_bf(b2) : hi_bf(b2);
                float w3 = lo ? lo_bf(b3) : hi_bf(b3);
                acc0 = fmaf(lo_bf(p0), w0, acc0); acc1 = fmaf(hi_bf(p0), w0, acc1);
                acc0 = fmaf(lo_bf(p1), w1, acc0); acc1 = fmaf(hi_bf(p1), w1, acc1);
                acc0 = fmaf(lo_bf(p2), w2, acc0); acc1 = fmaf(hi_bf(p2), w2, acc1);
                acc0 = fmaf(lo_bf(p3), w3, acc0); acc1 = fmaf(hi_bf(p3), w3, acc1);
            }
            for (; e < cnt; e++) {
                int s = __shfl(sl, e); unsigned b = __shfl(al, e);
                unsigned p = xw32[(size_t)s * 64 + lane];
                float w = lo ? lo_bf(b) : hi_bf(b);
                acc0 = fmaf(lo_bf(p), w, acc0);
                acc1 = fmaf(hi_bf(p), w, acc1);
            }
        }
    }
    float2 o; o.x = acc0; o.y = acc1;
    *(float2*)&h1[(size_t)n * F1 + 2 * lane] = o;
}

// =================== BatchNorm ===================
__global__ void k_bn_stats(const float* __restrict__ h, int nfeat, float* __restrict__ sums) {
    int f = threadIdx.x;                       // blockDim.x == nfeat
    int rows = (NN + gridDim.x - 1) / gridDim.x;
    int r0 = blockIdx.x * rows;
    int r1 = min(NN, r0 + rows);
    float s = 0.f, ss = 0.f;
    for (int r = r0; r < r1; r++) {
        float v = h[r * nfeat + f];
        s += v; ss += v * v;
    }
    atomicAdd(&sums[f], s);
    atomicAdd(&sums[nfeat + f], ss);
}

// BN apply + ELU, writing bf16 to a SEPARATE buffer (consumed by MFMA GEMMs)
__global__ void k_bn_apply_bf(const float* __restrict__ h, const float* __restrict__ sums,
                              const float* __restrict__ g, const float* __restrict__ b,
                              int nfeat, int total, ushort* __restrict__ hb) {
    int i = blockIdx.x * blockDim.x + threadIdx.x;
    if (i >= total) return;
    int f = i & (nfeat - 1);
    float m = sums[f] * (1.0f / NN);
    float var = sums[nfeat + f] * (1.0f / NN) - m * m;
    float v = (h[i] - m) * rsqrtf(var + 1e-5f) * g[f] + b[f];
    hb[i] = f2bf(v > 0.f ? v : expm1f(v));
}

// =================== SAGE dual GEMM via MFMA ===================
// [u|v] = h1b(bf16) @ [wl|wr](bf16 frags). Block = 4 waves x 16 rows = 64 rows.
__global__ void k_sage_dualgemm(const ushort* __restrict__ h1b, const ushort* __restrict__ fragd,
                                ushort* __restrict__ u_bf, float* __restrict__ v) {
    __shared__ uint4 sfrag[2048];               // 32 KB: [ks(4)][ct(8)][lane(64)] x 16B
    int t = threadIdx.x;
    const uint4* f4 = (const uint4*)fragd;
    for (int i = t; i < 2048; i += 256) sfrag[i] = f4[i];
    __syncthreads();
    int w = t >> 6, lane = t & 63;
    int row0 = blockIdx.x * 64 + w * 16;
    int arow = row0 + (lane & 15);
    if (arow >= NN) arow = NN - 1;              // clamp loads; stores guarded
    f32x4 acc[8];
#pragma unroll
    for (int c = 0; c < 8; c++) acc[c] = (f32x4){0.f, 0.f, 0.f, 0.f};
#pragma unroll
    for (int ks = 0; ks < 4; ks++) {
        union { uint4 u; bf16x8 f; } ua;
        ua.u = *(const uint4*)&h1b[(size_t)arow * F1 + ks * 32 + (lane >> 4) * 8];
#pragma unroll
        for (int ct = 0; ct < 8; ct++) {
            union { uint4 u; bf16x8 f; } ub;
            ub.u = sfrag[(ks * 8 + ct) * 64 + lane];
            acc[ct] = __builtin_amdgcn_mfma_f32_16x16x32_bf16(ua.f, ub.f, acc[ct], 0, 0, 0);
        }
    }
    int mrow0 = row0 + (lane >> 4) * 4;
    int n = lane & 15;
#pragma unroll
    for (int reg = 0; reg < 4; reg++) {
        int r = mrow0 + reg;
        if (r >= NN) continue;
#pragma unroll
        for (int ct = 0; ct < 4; ct++)
            u_bf[(size_t)r * F2 + ct * 16 + n] = f2bf(acc[ct][reg]);
#pragma unroll
        for (int ct = 4; ct < 8; ct++)
            v[(size_t)r * F2 + (ct - 4) * 16 + n] = acc[ct][reg];
    }
}

// h2raw[n] = mean-gather(u_bf16) + v[n] + bl
__global__ void k_sage_gather2(const int* __restrict__ rowptr, const int* __restrict__ csr_src,
                               const ushort* __restrict__ u_bf, const float* __restrict__ v,
                               const float* __restrict__ bl, float* __restrict__ h2) {
    int n = blockIdx.x * 4 + (threadIdx.x >> 6);
    int lane = threadIdx.x & 63;
    if (n >= NN) return;
    int j0 = rowptr[n], j1 = rowptr[n + 1];
    float a = 0.f;
    for (int base = j0; base < j1; base += 64) {
        int cnt = min(64, j1 - base);
        int myj = base + lane;
        int sl = (myj < j1) ? csr_src[myj] : 0;
        int e = 0;
        for (; e + 4 <= cnt; e += 4) {
            int s0 = __shfl(sl, e + 0), s1 = __shfl(sl, e + 1),
                s2 = __shfl(sl, e + 2), s3 = __shfl(sl, e + 3);
            float t0 = bf2f(u_bf[(size_t)s0 * F2 + lane]);
            float t1 = bf2f(u_bf[(size_t)s1 * F2 + lane]);
            float t2 = bf2f(u_bf[(size_t)s2 * F2 + lane]);
            float t3 = bf2f(u_bf[(size_t)s3 * F2 + lane]);
            a += (t0 + t1) + (t2 + t3);
        }
        for (; e < cnt; e++) {
            int s = __shfl(sl, e);
            a += bf2f(u_bf[(size_t)s * F2 + lane]);
        }
    }
    float inv = 1.0f / fmaxf((float)(j1 - j0), 1.0f);
    h2[(size_t)n * F2 + lane] = a * inv + v[(size_t)n * F2 + lane] + bl[lane];
}

__global__ void k_dinv(const int* __restrict__ degi, float* __restrict__ dinv) {
    int i = blockIdx.x * blockDim.x + threadIdx.x;
    if (i < NN) dinv[i] = rsqrtf((float)degi[i] + 1.0f);
}

// =================== GCN GEMM via MFMA ===================
// hwd(bf16) = (h2b(bf16) @ gcn_w(bf16 frags)) * dinv[row]
__global__ void k_gcn_gemm(const ushort* __restrict__ h2b, const ushort* __restrict__ fragg,
                           const float* __restrict__ dinv, ushort* __restrict__ hwd_bf) {
    __shared__ uint4 sfrag[512];                // 8 KB: [ks(2)][ct(4)][lane(64)] x 16B
    int t = threadIdx.x;
    const uint4* f4 = (const uint4*)fragg;
    for (int i = t; i < 512; i += 256) sfrag[i] = f4[i];
    __syncthreads();
    int w = t >> 6, lane = t & 63;
    int row0 = blockIdx.x * 64 + w * 16;
    int arow = row0 + (lane & 15);
    if (arow >= NN) arow = NN - 1;
    f32x4 acc[4];
#pragma unroll
    for (int c = 0; c < 4; c++) acc[c] = (f32x4){0.f, 0.f, 0.f, 0.f};
#pragma unroll
    for (int ks = 0; ks < 2; ks++) {
        union { uint4 u; bf16x8 f; } ua;
        ua.u = *(const uint4*)&h2b[(size_t)arow * F2 + ks * 32 + (lane >> 4) * 8];
#pragma unroll
        for (int ct = 0; ct < 4; ct++) {
            union { uint4 u; bf16x8 f; } ub;
            ub.u = sfrag[(ks * 4 + ct) * 64 + lane];
            acc[ct] = __builtin_amdgcn_mfma_f32_16x16x32_bf16(ua.f, ub.f, acc[ct], 0, 0, 0);
        }
    }
    int mrow0 = row0 + (lane >> 4) * 4;
    int n = lane & 15;
#pragma unroll
    for (int reg = 0; reg < 4; reg++) {
        int r = mrow0 + reg;
        if (r >= NN) continue;
        float d = dinv[r];
#pragma unroll
        for (int ct = 0; ct < 4; ct++)
            hwd_bf[(size_t)r * F2 + ct * 16 + n] = f2bf(acc[ct][reg] * d);
    }
}

// h3 = dinv[n]*(sum_src hwd[s] + hwd[n]) + gb
__global__ void k_gcn_gather(const int* __restrict__ rowptr, const int* __restrict__ csr_src,
                             const ushort* __restrict__ hwd_bf, const float* __restrict__ dinv,
                             const float* __restrict__ gb, float* __restrict__ h3) {
    int n = blockIdx.x * 4 + (threadIdx.x >> 6);
    int lane = threadIdx.x & 63;
    if (n >= NN) return;
    int j0 = rowptr[n], j1 = rowptr[n + 1];
    float acc = 0.f;
    for (int base = j0; base < j1; base += 64) {
        int cnt = min(64, j1 - base);
        int myj = base + lane;
        int sl = (myj < j1) ? csr_src[myj] : 0;
        int e = 0;
        for (; e + 4 <= cnt; e += 4) {
            int s0 = __shfl(sl, e + 0), s1 = __shfl(sl, e + 1),
                s2 = __shfl(sl, e + 2), s3 = __shfl(sl, e + 3);
            float t0 = bf2f(hwd_bf[(size_t)s0 * F2 + lane]);
            float t1 = bf2f(hwd_bf[(size_t)s1 * F2 + lane]);
            float t2 = bf2f(hwd_bf[(size_t)s2 * F2 + lane]);
            float t3 = bf2f(hwd_bf[(size_t)s3 * F2 + lane]);
            acc += (t0 + t1) + (t2 + t3);
        }
        for (; e < cnt; e++) {
            int s = __shfl(sl, e);
            acc += bf2f(hwd_bf[(size_t)s * F2 + lane]);
        }
    }
    float di = dinv[n];
    acc += bf2f(hwd_bf[(size_t)n * F2 + lane]);
    h3[(size_t)n * F2 + lane] = acc * di + gb[lane];
}

// =================== fused BN3-apply + ELU + segmented pool ===================
__global__ void k_bn3_pool(const float* __restrict__ h3raw, const float* __restrict__ sums,
                           const float* __restrict__ g3, const float* __restrict__ b3,
                           const int* __restrict__ batch, float* __restrict__ psum,
                           unsigned* __restrict__ pmax, float* __restrict__ cnt) {
    int lane = threadIdx.x;   // 64 threads = one wave, lane = feature
    int rows = (NN + gridDim.x - 1) / gridDim.x;
    int r0 = blockIdx.x * rows;
    int r1 = min(NN, r0 + rows);
    if (r0 >= r1) return;
    float m = sums[lane] * (1.0f / NN);
    float var = sums[F2 + lane] * (1.0f / NN) - m * m;
    float sc = rsqrtf(var + 1e-5f) * g3[lane];
    float bb = b3[lane];
    int curg = batch[r0];
    float ls = 0.f, lm = -INFINITY;
    int run = 0;
    for (int r = r0; r < r1; r++) {
        int gg = batch[r];
        if (gg != curg) {
            atomicAdd(&psum[curg * F2 + lane], ls);
            atomicMax(&pmax[curg * F2 + lane], enc_f(lm));
            if (lane == 0) atomicAdd(&cnt[curg], (float)run);
            curg = gg; ls = 0.f; lm = -INFINITY; run = 0;
        }
        float v = (h3raw[r * F2 + lane] - m) * sc + bb;
        v = v > 0.f ? v : expm1f(v);
        ls += v; lm = fmaxf(lm, v); run++;
    }
    atomicAdd(&psum[curg * F2 + lane], ls);
    atomicMax(&pmax[curg * F2 + lane], enc_f(lm));
    if (lane == 0) atomicAdd(&cnt[curg], (float)run);
}

// =================== classifier ===================
__global__ void k_cls(const float* __restrict__ psum, const unsigned* __restrict__ pmax,
                      const float* __restrict__ cnt, const float* __restrict__ w1,
                      const float* __restrict__ b1, const float* __restrict__ w2,
                      const float* __restrict__ b2, float* __restrict__ out) {
    int g = blockIdx.x;
    int j = threadIdx.x;  // 64 threads
    __shared__ float z[2 * F2];
    __shared__ float hid[F2];
    float c = fmaxf(cnt[g], 1.0f);
    z[j] = psum[g * F2 + j] / c;
    float mv = dec_f(pmax[g * F2 + j]);
    z[F2 + j] = isfinite(mv) ? mv : 0.f;
    __syncthreads();
    float acc = b1[j];
#pragma unroll 8
    for (int k = 0; k < 2 * F2; k++) acc += z[k] * w1[k * F2 + j];
    hid[j] = fmaxf(acc, 0.f);
    __syncthreads();
    if (j < NCLS) {
        float o = b2[j];
#pragma unroll 8
        for (int k = 0; k < F2; k++) o += hid[k] * w2[k * NCLS + j];
        out[g * NCLS + j] = o;
    }
}

extern "C" void kernel_launch(void* const* d_in, const int* in_sizes, int n_in,
                              void* d_out, int out_size, void* d_ws, size_t ws_size,
                              hipStream_t stream) {
    const float* x       = (const float*)d_in[0];
    const int*   ei      = (const int*)d_in[1];
    const int*   batch   = (const int*)d_in[2];
    const float* gat_w   = (const float*)d_in[3];
    const float* att_src = (const float*)d_in[4];
    const float* att_dst = (const float*)d_in[5];
    // d_in[6] gat_b: cancels inside BN1
    const float* bn1_g   = (const float*)d_in[7];
    const float* bn1_b   = (const float*)d_in[8];
    const float* sage_wl = (const float*)d_in[9];
    const float* sage_bl = (const float*)d_in[10];
    const float* sage_wr = (const float*)d_in[11];
    const float* bn2_g   = (const float*)d_in[12];
    const float* bn2_b   = (const float*)d_in[13];
    const float* gcn_w   = (const float*)d_in[14];
    const float* gcn_b   = (const float*)d_in[15];
    const float* bn3_g   = (const float*)d_in[16];
    const float* bn3_b   = (const float*)d_in[17];
    const float* w1      = (const float*)d_in[18];
    const float* b1      = (const float*)d_in[19];
    const float* w2      = (const float*)d_in[20];
    const float* b2      = (const float*)d_in[21];
    float* out = (float*)d_out;

    float* ws = (float*)d_ws;
    // workspace layout (4-byte units; 16B alignment maintained)
    size_t o_A    = 0;                        // NN*F1 floats region, aliased (see below)
    size_t o_h1   = o_A   + (size_t)NN * F1;  // NN*F1 f32: GAT raw out; later h2b (bf16)
    size_t o_h2   = o_h1  + (size_t)NN * F1;  // NN*F2 f32: h1b (bf16) first, then h2 raw
    size_t o_csr  = o_h2  + (size_t)NN * F2;  // E ints (csr_src)
    size_t o_rp   = o_csr + (size_t)NE;       // N+4 ints (rowptr, padded for alignment)
    size_t o_deg  = o_rp  + (size_t)(NN + 4); // N ints (degi)
    size_t o_bs   = o_deg + (size_t)NN;       // 512 ints (block sums)
    size_t o_asrc = o_bs  + 512;              // N*2
    size_t o_adst = o_asrc + (size_t)NN * 2;  // N*2
    size_t o_dinv = o_adst + (size_t)NN * 2;  // N
    size_t o_sums = o_dinv + (size_t)NN;      // 256
    size_t o_frd  = o_sums + 256;             // 8192 floats = 32KB dual B-frags
    size_t o_frg  = o_frd  + 8192;            // 2048 floats = 8KB gcn B-frags
    size_t o_psum = o_frg  + 2048;            // G*F2
    size_t o_pmax = o_psum + (size_t)NG * F2; // G*F2
    size_t o_cnt  = o_pmax + (size_t)NG * F2; // G

    float* A    = ws + o_A;
    float* h1   = ws + o_h1;
    float* h2   = ws + o_h2;
    int* csr_src = (int*)(ws + o_csr);
    int* rowptr  = (int*)(ws + o_rp);
    int* degi    = (int*)(ws + o_deg);
    int* bsum    = (int*)(ws + o_bs);
    float* asr  = ws + o_asrc;
    float* ads  = ws + o_adst;
    float* dinv = ws + o_dinv;
    float* sums = ws + o_sums;
    ushort* fragd = (ushort*)(ws + o_frd);
    ushort* fragg = (ushort*)(ws + o_frg);
    float* psum = ws + o_psum;
    unsigned* pmax = (unsigned*)(ws + o_pmax);
    float* cnt  = ws + o_cnt;

    // region aliases (lifetimes disjoint):
    unsigned* staged = (unsigned*)A;                    // CSR build: NE entries (6.4 MB)
    int*    ghist  = (int*)(A + 2 * 1024 * 1024);       // CSR build: NCHUNK*NBUCK ints
    ushort* xw_bf  = (ushort*)A;                        // GAT: NN*F1 bf16 (25.6 MB)
    ushort* u_bf   = (ushort*)A;                        // SAGE: NN*F2 bf16 (xw dead)
    float*  vmat   = A + (size_t)NN * F2 / 2;           // SAGE: NN*F2 f32
    ushort* hwd_bf = (ushort*)A;                        // GCN: NN*F2 bf16 (u dead)
    float*  h3     = A + (size_t)NN * F2 / 2;           // GCN out: NN*F2 f32 (v dead)
    ushort* h1b    = (ushort*)h2;                       // post-BN1 bf16 (25.6MB, = h2 region;
                                                        //   dead before sage_gather2 writes h2)
    ushort* h2b    = (ushort*)h1;                       // post-BN2 bf16 (h1 dead after dualgemm)

    // ---- CSR build: count + node scan, then chunk-major radix ----
    hipMemsetAsync(degi, 0, sizeof(int) * NN, stream);
    k_count<<<(NE + 255) / 256, 256, 0, stream>>>(ei, degi);
    k_scan1<<<NB_SCAN, 256, 0, stream>>>(degi, rowptr, bsum);
    k_scan2<<<1, 512, 0, stream>>>(bsum, NB_SCAN);
    k_scan3<<<NB_SCAN, 256, 0, stream>>>(rowptr, bsum);
    k_hist<<<NCHUNK, 256, 0, stream>>>(ei, ghist);
    k_chunkscan<<<(NBUCK + 255) / 256, 256, 0, stream>>>(ghist, rowptr);
    k_scatter2<<<NCHUNK, 256, 0, stream>>>(ei, ghist, staged);
    k_bucket_sort<<<NBUCK, 256, 0, stream>>>(staged, rowptr, csr_src);

    // ---- GAT (softmax fused into gather) ----
    k_xw<<<NN, F1, 0, stream>>>(x, gat_w, att_src, att_dst, xw_bf, asr, ads);
    k_gat_gather<<<(NN + 3) / 4, 256, 0, stream>>>(rowptr, csr_src, asr, ads,
                                                   (const unsigned*)xw_bf, h1);
    hipMemsetAsync(sums, 0, sizeof(float) * 256, stream);
    k_bn_stats<<<512, F1, 0, stream>>>(h1, F1, sums);
    k_bn_apply_bf<<<(NN * F1 + 255) / 256, 256, 0, stream>>>(h1, sums, bn1_g, bn1_b,
                                                             F1, NN * F1, h1b);

    // ---- SAGE: MFMA dual-GEMM then bf16 mean-gather ----
    k_packfrag_dual<<<(16384 + 255) / 256, 256, 0, stream>>>(sage_wl, sage_wr, fragd);
    k_sage_dualgemm<<<(NN + 63) / 64, 256, 0, stream>>>(h1b, fragd, u_bf, vmat);
    k_sage_gather2<<<(NN + 3) / 4, 256, 0, stream>>>(rowptr, csr_src, u_bf, vmat, sage_bl, h2);
    hipMemsetAsync(sums, 0, sizeof(float) * 256, stream);
    k_bn_stats<<<512, F2, 0, stream>>>(h2, F2, sums);
    k_bn_apply_bf<<<(NN * F2 + 255) / 256, 256, 0, stream>>>(h2, sums, bn2_g, bn2_b,
                                                             F2, NN * F2, h2b);

    // ---- GCN: MFMA GEMM (dinv folded) then gather ----
    k_dinv<<<(NN + 255) / 256, 256, 0, stream>>>(degi, dinv);
    k_packfrag_gcn<<<(4096 + 255) / 256, 256, 0, stream>>>(gcn_w, fragg);
    k_gcn_gemm<<<(NN + 63) / 64, 256, 0, stream>>>(h2b, fragg, dinv, hwd_bf);
    k_gcn_gather<<<(NN + 3) / 4, 256, 0, stream>>>(rowptr, csr_src, hwd_bf, dinv, gcn_b, h3);
    hipMemsetAsync(sums, 0, sizeof(float) * 256, stream);
    k_bn_stats<<<512, F2, 0, stream>>>(h3, F2, sums);

    // ---- fused BN3 + ELU + pooling, then classifier ----
    hipMemsetAsync(psum, 0, sizeof(float) * NG * F2, stream);
    hipMemsetAsync(cnt, 0, sizeof(float) * NG, stream);
    k_fill_u32<<<(NG * F2 + 255) / 256, 256, 0, stream>>>(pmax, ENC_NEG_INF, NG * F2);
    k_bn3_pool<<<512, F2, 0, stream>>>(h3, sums, bn3_g, bn3_b, batch, psum, pmax, cnt);
    k_cls<<<NG, F2, 0, stream>>>(psum, pmax, cnt, w1, b1, w2, b2, out);
}

// Round 16
// 589.722 us; speedup vs baseline: 2.3045x; 1.1735x over previous
//
#include <hip/hip_runtime.h>
#include <hip/hip_bf16.h>
#include <math.h>

#define NN 100000      // nodes
#define NE 1600000     // edges
#define NG 64          // graphs
#define F_IN 5
#define F1 128         // H*HID
#define F2 64          // HID
#define NCLS 4
#define NB_SCAN ((NN + 255) / 256)   // 391 blocks in node scan level 1
#define NCHUNK 250                   // edge chunks (250 * 6400 = NE)
#define CH_E 6400                    // edges per chunk
#define NBUCK ((NN + 255) / 256)     // 391 dst buckets of 256 nodes
#define CAPB 6144                    // bucket capacity in LDS sort

typedef unsigned short ushort;
typedef __bf16 bf16x8 __attribute__((ext_vector_type(8)));
typedef float f32x4 __attribute__((ext_vector_type(4)));

// ---------- bf16 helpers (round-to-nearest-even pack) ----------
__device__ __forceinline__ ushort f2bf(float f) {
    unsigned u = __float_as_uint(f);
    u = (u + 0x7fffu + ((u >> 16) & 1u)) >> 16;
    return (ushort)u;
}
__device__ __forceinline__ float bf2f(ushort h) {
    return __uint_as_float(((unsigned)h) << 16);
}
__device__ __forceinline__ unsigned pack2bf(float a, float b) {
    return (unsigned)f2bf(a) | ((unsigned)f2bf(b) << 16);
}
__device__ __forceinline__ float lo_bf(unsigned p) { return __uint_as_float(p << 16); }
__device__ __forceinline__ float hi_bf(unsigned p) { return __uint_as_float(p & 0xffff0000u); }

// ---------- order-preserving float<->uint encoding for atomicMax ----------
__device__ __forceinline__ unsigned enc_f(float f) {
    unsigned b = __float_as_uint(f);
    return (b & 0x80000000u) ? ~b : (b | 0x80000000u);
}
__device__ __forceinline__ float dec_f(unsigned k) {
    unsigned b = (k & 0x80000000u) ? (k ^ 0x80000000u) : ~k;
    return __uint_as_float(b);
}
#define ENC_NEG_INF 0x007FFFFFu   // enc_f(-inf)

__global__ void k_fill_u32(unsigned* p, unsigned v, int n) {
    int i = blockIdx.x * blockDim.x + threadIdx.x;
    if (i < n) p[i] = v;
}

// =================== MFMA B-fragment packing ===================
// layout idx = ((ks*CT + ct)*64 + lane)*8 + e ; value B[ks*32+(lane>>4)*8+e][ct*16+(lane&15)]
__global__ void k_packfrag_dual(const float* __restrict__ wl, const float* __restrict__ wr,
                                ushort* __restrict__ frag) {
    int idx = blockIdx.x * 256 + threadIdx.x;
    if (idx >= 4 * 8 * 64 * 8) return;
    int e = idx & 7;
    int lane = (idx >> 3) & 63;
    int ct = (idx >> 9) & 7;
    int ks = idx >> 12;
    int k = ks * 32 + (lane >> 4) * 8 + e;
    int n = ct * 16 + (lane & 15);
    float val = (n < 64) ? wl[k * 64 + n] : wr[k * 64 + (n - 64)];
    frag[idx] = f2bf(val);
}

__global__ void k_packfrag_gcn(const float* __restrict__ wm, ushort* __restrict__ frag) {
    int idx = blockIdx.x * 256 + threadIdx.x;
    if (idx >= 2 * 4 * 64 * 8) return;
    int e = idx & 7;
    int lane = (idx >> 3) & 63;
    int ct = (idx >> 9) & 3;
    int ks = idx >> 11;
    int k = ks * 32 + (lane >> 4) * 8 + e;
    int n = ct * 16 + (lane & 15);
    frag[idx] = f2bf(wm[k * 64 + n]);
}

// =================== CSR build (chunk-major two-level counting sort) ===================
__global__ void k_count(const int* __restrict__ ei, int* __restrict__ degi) {
    int e = blockIdx.x * blockDim.x + threadIdx.x;
    if (e < NE) atomicAdd(&degi[ei[NE + e]], 1);
}

__global__ void k_scan1(const int* __restrict__ degi, int* __restrict__ rowptr,
                        int* __restrict__ bsum) {
    __shared__ int sh[256];
    int i = blockIdx.x * 256 + threadIdx.x;
    int v = (i < NN) ? degi[i] : 0;
    sh[threadIdx.x] = v;
    __syncthreads();
    for (int off = 1; off < 256; off <<= 1) {
        int t = (threadIdx.x >= off) ? sh[threadIdx.x - off] : 0;
        __syncthreads();
        sh[threadIdx.x] += t;
        __syncthreads();
    }
    if (i < NN) rowptr[i] = sh[threadIdx.x] - v;   // exclusive, block-local
    if (threadIdx.x == 255) bsum[blockIdx.x] = sh[255];
}

__global__ void k_scan2(int* __restrict__ bsum, int nb) {
    __shared__ int sh[512];
    int v = (threadIdx.x < nb) ? bsum[threadIdx.x] : 0;
    sh[threadIdx.x] = v;
    __syncthreads();
    for (int off = 1; off < 512; off <<= 1) {
        int t = (threadIdx.x >= off) ? sh[threadIdx.x - off] : 0;
        __syncthreads();
        sh[threadIdx.x] += t;
        __syncthreads();
    }
    if (threadIdx.x < nb) bsum[threadIdx.x] = sh[threadIdx.x] - v;   // exclusive
}

__global__ void k_scan3(int* __restrict__ rowptr, const int* __restrict__ bsum) {
    int i = blockIdx.x * 256 + threadIdx.x;
    if (i == 0) rowptr[NN] = NE;
    if (i >= NN) return;
    rowptr[i] += bsum[blockIdx.x];
}

// pass 1: per-chunk histogram over 391 dst buckets
__global__ void k_hist(const int* __restrict__ ei, int* __restrict__ ghist) {
    __shared__ int lh[NBUCK];
    int c = blockIdx.x, t = threadIdx.x;
    for (int b = t; b < NBUCK; b += 256) lh[b] = 0;
    __syncthreads();
    int e0 = c * CH_E;
#pragma unroll
    for (int i = 0; i < CH_E / 256; i++) {
        int d = ei[NE + e0 + t + i * 256];
        atomicAdd(&lh[d >> 8], 1);
    }
    __syncthreads();
    for (int b = t; b < NBUCK; b += 256) ghist[c * NBUCK + b] = lh[b];
}

// pass 2: per-bucket serial prefix over chunks (in place: ghist -> offsets)
__global__ void k_chunkscan(int* __restrict__ ghist, const int* __restrict__ rowptr) {
    int b = blockIdx.x * blockDim.x + threadIdx.x;
    if (b >= NBUCK) return;
    int run = rowptr[b * 256];           // bucket base in csr order
    for (int c = 0; c < NCHUNK; c++) {
        int h = ghist[c * NBUCK + b];
        ghist[c * NBUCK + b] = run;
        run += h;
    }
}

// pass 3: scatter into bucket-major staged array (packed (dlow<<17)|src)
__global__ void k_scatter2(const int* __restrict__ ei, const int* __restrict__ ghist,
                           unsigned* __restrict__ staged) {
    __shared__ int lcur[NBUCK];
    int c = blockIdx.x, t = threadIdx.x;
    for (int b = t; b < NBUCK; b += 256) lcur[b] = ghist[c * NBUCK + b];
    __syncthreads();
    int e0 = c * CH_E;
#pragma unroll
    for (int i = 0; i < CH_E / 256; i++) {
        int e = e0 + t + i * 256;
        int s = ei[e];
        int d = ei[NE + e];
        int pos = atomicAdd(&lcur[d >> 8], 1);
        staged[pos] = (((unsigned)(d & 255)) << 17) | (unsigned)s;
    }
}

// pass 4: per-bucket LDS counting sort by low 8 dst bits -> coalesced csr_src
__global__ void k_bucket_sort(const unsigned* __restrict__ staged,
                              const int* __restrict__ rowptr, int* __restrict__ csr_src) {
    __shared__ unsigned ein[CAPB];
    __shared__ unsigned sout[CAPB];
    __shared__ int lcur[256];
    int b = blockIdx.x, t = threadIdx.x;
    int n0 = b * 256;
    int nend = min(n0 + 256, NN);
    int nn = nend - n0;
    int g0 = rowptr[n0];
    int m = rowptr[nend] - g0;
    if (t < nn) lcur[t] = rowptr[n0 + t] - g0;
    __syncthreads();
    if (m <= CAPB) {
        for (int i = t; i < m; i += 256) ein[i] = staged[g0 + i];
        __syncthreads();
        for (int i = t; i < m; i += 256) {
            unsigned u = ein[i];
            int pos = atomicAdd(&lcur[u >> 17], 1);
            sout[pos] = u & 0x1FFFFu;
        }
        __syncthreads();
        for (int i = t; i < m; i += 256) csr_src[g0 + i] = (int)sout[i];
    } else {
        for (int i = t; i < m; i += 256) {
            unsigned u = staged[g0 + i];
            int pos = atomicAdd(&lcur[u >> 17], 1);
            csr_src[g0 + pos] = (int)(u & 0x1FFFFu);
        }
    }
}

// =================== GAT ===================
// xw (bf16) = x @ gat_w ; a_src/a_dst per-node attention logits
__global__ void k_xw(const float* __restrict__ x, const float* __restrict__ gw,
                     const float* __restrict__ aw_src, const float* __restrict__ aw_dst,
                     ushort* __restrict__ xw_bf, float* __restrict__ a_src,
                     float* __restrict__ a_dst) {
    int n = blockIdx.x;
    int f = threadIdx.x;                 // 128 threads, f = h*64+c
    __shared__ float w[F_IN * F1];
    __shared__ float xs[F_IN];
    for (int i = f; i < F_IN * F1; i += F1) w[i] = gw[i];
    if (f < F_IN) xs[f] = x[n * F_IN + f];
    __syncthreads();
    float acc = 0.f;
#pragma unroll
    for (int i = 0; i < F_IN; i++) acc += xs[i] * w[i * F1 + f];
    xw_bf[n * F1 + f] = f2bf(acc);
    int h = f >> 6, lane = f & 63;
    float p = acc * aw_src[f];
    float q = acc * aw_dst[f];
#pragma unroll
    for (int off = 32; off > 0; off >>= 1) {
        p += __shfl_down(p, off);
        q += __shfl_down(q, off);
    }
    if (lane == 0) { a_src[n * 2 + h] = p; a_dst[n * 2 + h] = q; }
}

// FUSED softmax + gather: one wave per dst node.
__global__ void k_gat_gather(const int* __restrict__ rowptr, const int* __restrict__ csr_src,
                             const float* __restrict__ a_src, const float* __restrict__ a_dst,
                             const unsigned* __restrict__ xw32, float* __restrict__ h1) {
    int n = blockIdx.x * 4 + (threadIdx.x >> 6);
    int lane = threadIdx.x & 63;
    if (n >= NN) return;
    int j0 = rowptr[n], j1 = rowptr[n + 1];
    int deg = j1 - j0;
    float ad0 = a_dst[n * 2 + 0], ad1 = a_dst[n * 2 + 1];
    float acc0 = 0.f, acc1 = 0.f;
    bool lo = (lane < 32);
    if (deg <= 64) {
        int sl = 0;
        float l0 = -INFINITY, l1 = -INFINITY;
        if (lane < deg) {
            sl = csr_src[j0 + lane];
            l0 = a_src[sl * 2 + 0] + ad0;
            l1 = a_src[sl * 2 + 1] + ad1;
            l0 = l0 > 0.f ? l0 : 0.2f * l0;
            l1 = l1 > 0.f ? l1 : 0.2f * l1;
        }
        float m0 = l0, m1 = l1;
#pragma unroll
        for (int off = 32; off > 0; off >>= 1) {
            m0 = fmaxf(m0, __shfl_xor(m0, off));
            m1 = fmaxf(m1, __shfl_xor(m1, off));
        }
        float e0 = 0.f, e1 = 0.f;
        if (lane < deg) { e0 = expf(l0 - m0); e1 = expf(l1 - m1); }
        float s0 = e0, s1 = e1;
#pragma unroll
        for (int off = 32; off > 0; off >>= 1) {
            s0 += __shfl_xor(s0, off);
            s1 += __shfl_xor(s1, off);
        }
        unsigned al = pack2bf(e0 / (s0 + 1e-16f), e1 / (s1 + 1e-16f));
        int e = 0;
        for (; e + 4 <= deg; e += 4) {
            int s0i = __shfl(sl, e + 0), s1i = __shfl(sl, e + 1),
                s2i = __shfl(sl, e + 2), s3i = __shfl(sl, e + 3);
            unsigned b0 = __shfl(al, e + 0), b1 = __shfl(al, e + 1),
                     b2 = __shfl(al, e + 2), b3 = __shfl(al, e + 3);
            unsigned p0 = xw32[(size_t)s0i * 64 + lane];
            unsigned p1 = xw32[(size_t)s1i * 64 + lane];
            unsigned p2 = xw32[(size_t)s2i * 64 + lane];
            unsigned p3 = xw32[(size_t)s3i * 64 + lane];
            float w0 = lo ? lo_bf(b0) : hi_bf(b0);
            float w1 = lo ? lo_bf(b1) : hi_bf(b1);
            float w2 = lo ? lo_bf(b2) : hi_bf(b2);
            float w3 = lo ? lo_bf(b3) : hi_bf(b3);
            acc0 = fmaf(lo_bf(p0), w0, acc0); acc1 = fmaf(hi_bf(p0), w0, acc1);
            acc0 = fmaf(lo_bf(p1), w1, acc0); acc1 = fmaf(hi_bf(p1), w1, acc1);
            acc0 = fmaf(lo_bf(p2), w2, acc0); acc1 = fmaf(hi_bf(p2), w2, acc1);
            acc0 = fmaf(lo_bf(p3), w3, acc0); acc1 = fmaf(hi_bf(p3), w3, acc1);
        }
        for (; e < deg; e++) {
            int s = __shfl(sl, e); unsigned b = __shfl(al, e);
            unsigned p = xw32[(size_t)s * 64 + lane];
            float w = lo ? lo_bf(b) : hi_bf(b);
            acc0 = fmaf(lo_bf(p), w, acc0);
            acc1 = fmaf(hi_bf(p), w, acc1);
        }
    } else {
        float m0 = -INFINITY, m1 = -INFINITY, s0 = 0.f, s1 = 0.f;
        for (int base = j0; base < j1; base += 64) {
            int myj = base + lane;
            float l0 = -INFINITY, l1 = -INFINITY;
            if (myj < j1) {
                int s = csr_src[myj];
                l0 = a_src[s * 2 + 0] + ad0;
                l1 = a_src[s * 2 + 1] + ad1;
                l0 = l0 > 0.f ? l0 : 0.2f * l0;
                l1 = l1 > 0.f ? l1 : 0.2f * l1;
            }
            float cm0 = l0, cm1 = l1;
#pragma unroll
            for (int off = 32; off > 0; off >>= 1) {
                cm0 = fmaxf(cm0, __shfl_xor(cm0, off));
                cm1 = fmaxf(cm1, __shfl_xor(cm1, off));
            }
            float nm0 = fmaxf(m0, cm0), nm1 = fmaxf(m1, cm1);
            float ce0 = (myj < j1) ? expf(l0 - nm0) : 0.f;
            float ce1 = (myj < j1) ? expf(l1 - nm1) : 0.f;
            float cs0 = ce0, cs1 = ce1;
#pragma unroll
            for (int off = 32; off > 0; off >>= 1) {
                cs0 += __shfl_xor(cs0, off);
                cs1 += __shfl_xor(cs1, off);
            }
            s0 = s0 * expf(m0 - nm0) + cs0;
            s1 = s1 * expf(m1 - nm1) + cs1;
            m0 = nm0; m1 = nm1;
        }
        float r0 = 1.0f / (s0 + 1e-16f), r1 = 1.0f / (s1 + 1e-16f);
        for (int base = j0; base < j1; base += 64) {
            int cnt = min(64, j1 - base);
            int myj = base + lane;
            int sl = 0; unsigned al = 0;
            if (myj < j1) {
                sl = csr_src[myj];
                float l0 = a_src[sl * 2 + 0] + ad0;
                float l1 = a_src[sl * 2 + 1] + ad1;
                l0 = l0 > 0.f ? l0 : 0.2f * l0;
                l1 = l1 > 0.f ? l1 : 0.2f * l1;
                al = pack2bf(expf(l0 - m0) * r0, expf(l1 - m1) * r1);
            }
            int e = 0;
            for (; e + 4 <= cnt; e += 4) {
                int s0i = __shfl(sl, e + 0), s1i = __shfl(sl, e + 1),
                    s2i = __shfl(sl, e + 2), s3i = __shfl(sl, e + 3);
                unsigned b0 = __shfl(al, e + 0), b1 = __shfl(al, e + 1),
                         b2 = __shfl(al, e + 2), b3 = __shfl(al, e + 3);
                unsigned p0 = xw32[(size_t)s0i * 64 + lane];
                unsigned p1 = xw32[(size_t)s1i * 64 + lane];
                unsigned p2 = xw32[(size_t)s2i * 64 + lane];
                unsigned p3 = xw32[(size_t)s3i * 64 + lane];
                float w0 = lo ? lo_bf(b0) : hi_bf(b0);
                float w1 = lo ? lo_bf(b1) : hi_bf(b1);
                float w2 = lo ? lo_bf(b2) : hi_bf(b2);
                float w3 = lo ? lo_bf(b3) : hi_bf(b3);
                acc0 = fmaf(lo_bf(p0), w0, acc0); acc1 = fmaf(hi_bf(p0), w0, acc1);
                acc0 = fmaf(lo_bf(p1), w1, acc0); acc1 = fmaf(hi_bf(p1), w1, acc1);
                acc0 = fmaf(lo_bf(p2), w2, acc0); acc1 = fmaf(hi_bf(p2), w2, acc1);
                acc0 = fmaf(lo_bf(p3), w3, acc0); acc1 = fmaf(hi_bf(p3), w3, acc1);
            }
            for (; e < cnt; e++) {
                int s = __shfl(sl, e); unsigned b = __shfl(al, e);
                unsigned p = xw32[(size_t)s * 64 + lane];
                float w = lo ? lo_bf(b) : hi_bf(b);
                acc0 = fmaf(lo_bf(p), w, acc0);
                acc1 = fmaf(hi_bf(p), w, acc1);
            }
        }
    }
    float2 o; o.x = acc0; o.y = acc1;
    *(float2*)&h1[(size_t)n * F1 + 2 * lane] = o;
}

// =================== BatchNorm ===================
// 256 threads: R=256/nfeat row-groups in flight; LDS-reduce, 1 atomic/feature/block
__global__ void k_bn_stats(const float* __restrict__ h, int nfeat, float* __restrict__ sums) {
    __shared__ float sh[512];
    int t = threadIdx.x;
    int f = t & (nfeat - 1);
    int rg = t / nfeat;
    int R = 256 / nfeat;
    int rows = (NN + gridDim.x - 1) / gridDim.x;
    int rbase = blockIdx.x * rows;
    int r1 = min(NN, rbase + rows);
    float s = 0.f, ss = 0.f;
    for (int r = rbase + rg; r < r1; r += R) {
        float v = h[(size_t)r * nfeat + f];
        s += v; ss += v * v;
    }
    sh[t] = s; sh[256 + t] = ss;
    __syncthreads();
    if (rg == 0) {
        for (int g = 1; g < R; g++) {
            s += sh[g * nfeat + f];
            ss += sh[256 + g * nfeat + f];
        }
        atomicAdd(&sums[f], s);
        atomicAdd(&sums[nfeat + f], ss);
    }
}

// BN apply + ELU, writing bf16 to a SEPARATE buffer (consumed by MFMA GEMMs)
__global__ void k_bn_apply_bf(const float* __restrict__ h, const float* __restrict__ sums,
                              const float* __restrict__ g, const float* __restrict__ b,
                              int nfeat, int total, ushort* __restrict__ hb) {
    int i = blockIdx.x * blockDim.x + threadIdx.x;
    if (i >= total) return;
    int f = i & (nfeat - 1);
    float m = sums[f] * (1.0f / NN);
    float var = sums[nfeat + f] * (1.0f / NN) - m * m;
    float v = (h[i] - m) * rsqrtf(var + 1e-5f) * g[f] + b[f];
    hb[i] = f2bf(v > 0.f ? v : expm1f(v));
}

// =================== SAGE dual GEMM via MFMA ===================
__global__ void k_sage_dualgemm(const ushort* __restrict__ h1b, const ushort* __restrict__ fragd,
                                ushort* __restrict__ u_bf, float* __restrict__ v) {
    __shared__ uint4 sfrag[2048];               // 32 KB: [ks(4)][ct(8)][lane(64)] x 16B
    int t = threadIdx.x;
    const uint4* f4 = (const uint4*)fragd;
    for (int i = t; i < 2048; i += 256) sfrag[i] = f4[i];
    __syncthreads();
    int w = t >> 6, lane = t & 63;
    int row0 = blockIdx.x * 64 + w * 16;
    int arow = row0 + (lane & 15);
    if (arow >= NN) arow = NN - 1;              // clamp loads; stores guarded
    f32x4 acc[8];
#pragma unroll
    for (int c = 0; c < 8; c++) acc[c] = (f32x4){0.f, 0.f, 0.f, 0.f};
#pragma unroll
    for (int ks = 0; ks < 4; ks++) {
        union { uint4 u; bf16x8 f; } ua;
        ua.u = *(const uint4*)&h1b[(size_t)arow * F1 + ks * 32 + (lane >> 4) * 8];
#pragma unroll
        for (int ct = 0; ct < 8; ct++) {
            union { uint4 u; bf16x8 f; } ub;
            ub.u = sfrag[(ks * 8 + ct) * 64 + lane];
            acc[ct] = __builtin_amdgcn_mfma_f32_16x16x32_bf16(ua.f, ub.f, acc[ct], 0, 0, 0);
        }
    }
    int mrow0 = row0 + (lane >> 4) * 4;
    int n = lane & 15;
#pragma unroll
    for (int reg = 0; reg < 4; reg++) {
        int r = mrow0 + reg;
        if (r >= NN) continue;
#pragma unroll
        for (int ct = 0; ct < 4; ct++)
            u_bf[(size_t)r * F2 + ct * 16 + n] = f2bf(acc[ct][reg]);
#pragma unroll
        for (int ct = 4; ct < 8; ct++)
            v[(size_t)r * F2 + (ct - 4) * 16 + n] = acc[ct][reg];
    }
}

// h2raw[n] = mean-gather(u_bf16) + v[n] + bl
__global__ void k_sage_gather2(const int* __restrict__ rowptr, const int* __restrict__ csr_src,
                               const ushort* __restrict__ u_bf, const float* __restrict__ v,
                               const float* __restrict__ bl, float* __restrict__ h2) {
    int n = blockIdx.x * 4 + (threadIdx.x >> 6);
    int lane = threadIdx.x & 63;
    if (n >= NN) return;
    int j0 = rowptr[n], j1 = rowptr[n + 1];
    float a = 0.f;
    for (int base = j0; base < j1; base += 64) {
        int cnt = min(64, j1 - base);
        int myj = base + lane;
        int sl = (myj < j1) ? csr_src[myj] : 0;
        int e = 0;
        for (; e + 4 <= cnt; e += 4) {
            int s0 = __shfl(sl, e + 0), s1 = __shfl(sl, e + 1),
                s2 = __shfl(sl, e + 2), s3 = __shfl(sl, e + 3);
            float t0 = bf2f(u_bf[(size_t)s0 * F2 + lane]);
            float t1 = bf2f(u_bf[(size_t)s1 * F2 + lane]);
            float t2 = bf2f(u_bf[(size_t)s2 * F2 + lane]);
            float t3 = bf2f(u_bf[(size_t)s3 * F2 + lane]);
            a += (t0 + t1) + (t2 + t3);
        }
        for (; e < cnt; e++) {
            int s = __shfl(sl, e);
            a += bf2f(u_bf[(size_t)s * F2 + lane]);
        }
    }
    float inv = 1.0f / fmaxf((float)(j1 - j0), 1.0f);
    h2[(size_t)n * F2 + lane] = a * inv + v[(size_t)n * F2 + lane] + bl[lane];
}

__global__ void k_dinv(const int* __restrict__ degi, float* __restrict__ dinv) {
    int i = blockIdx.x * blockDim.x + threadIdx.x;
    if (i < NN) dinv[i] = rsqrtf((float)degi[i] + 1.0f);
}

// =================== GCN GEMM via MFMA ===================
__global__ void k_gcn_gemm(const ushort* __restrict__ h2b, const ushort* __restrict__ fragg,
                           const float* __restrict__ dinv, ushort* __restrict__ hwd_bf) {
    __shared__ uint4 sfrag[512];                // 8 KB: [ks(2)][ct(4)][lane(64)] x 16B
    int t = threadIdx.x;
    const uint4* f4 = (const uint4*)fragg;
    for (int i = t; i < 512; i += 256) sfrag[i] = f4[i];
    __syncthreads();
    int w = t >> 6, lane = t & 63;
    int row0 = blockIdx.x * 64 + w * 16;
    int arow = row0 + (lane & 15);
    if (arow >= NN) arow = NN - 1;
    f32x4 acc[4];
#pragma unroll
    for (int c = 0; c < 4; c++) acc[c] = (f32x4){0.f, 0.f, 0.f, 0.f};
#pragma unroll
    for (int ks = 0; ks < 2; ks++) {
        union { uint4 u; bf16x8 f; } ua;
        ua.u = *(const uint4*)&h2b[(size_t)arow * F2 + ks * 32 + (lane >> 4) * 8];
#pragma unroll
        for (int ct = 0; ct < 4; ct++) {
            union { uint4 u; bf16x8 f; } ub;
            ub.u = sfrag[(ks * 4 + ct) * 64 + lane];
            acc[ct] = __builtin_amdgcn_mfma_f32_16x16x32_bf16(ua.f, ub.f, acc[ct], 0, 0, 0);
        }
    }
    int mrow0 = row0 + (lane >> 4) * 4;
    int n = lane & 15;
#pragma unroll
    for (int reg = 0; reg < 4; reg++) {
        int r = mrow0 + reg;
        if (r >= NN) continue;
        float d = dinv[r];
#pragma unroll
        for (int ct = 0; ct < 4; ct++)
            hwd_bf[(size_t)r * F2 + ct * 16 + n] = f2bf(acc[ct][reg] * d);
    }
}

// h3 = dinv[n]*(sum_src hwd[s] + hwd[n]) + gb
__global__ void k_gcn_gather(const int* __restrict__ rowptr, const int* __restrict__ csr_src,
                             const ushort* __restrict__ hwd_bf, const float* __restrict__ dinv,
                             const float* __restrict__ gb, float* __restrict__ h3) {
    int n = blockIdx.x * 4 + (threadIdx.x >> 6);
    int lane = threadIdx.x & 63;
    if (n >= NN) return;
    int j0 = rowptr[n], j1 = rowptr[n + 1];
    float acc = 0.f;
    for (int base = j0; base < j1; base += 64) {
        int cnt = min(64, j1 - base);
        int myj = base + lane;
        int sl = (myj < j1) ? csr_src[myj] : 0;
        int e = 0;
        for (; e + 4 <= cnt; e += 4) {
            int s0 = __shfl(sl, e + 0), s1 = __shfl(sl, e + 1),
                s2 = __shfl(sl, e + 2), s3 = __shfl(sl, e + 3);
            float t0 = bf2f(hwd_bf[(size_t)s0 * F2 + lane]);
            float t1 = bf2f(hwd_bf[(size_t)s1 * F2 + lane]);
            float t2 = bf2f(hwd_bf[(size_t)s2 * F2 + lane]);
            float t3 = bf2f(hwd_bf[(size_t)s3 * F2 + lane]);
            acc += (t0 + t1) + (t2 + t3);
        }
        for (; e < cnt; e++) {
            int s = __shfl(sl, e);
            acc += bf2f(hwd_bf[(size_t)s * F2 + lane]);
        }
    }
    float di = dinv[n];
    acc += bf2f(hwd_bf[(size_t)n * F2 + lane]);
    h3[(size_t)n * F2 + lane] = acc * di + gb[lane];
}

// =================== fused BN3-apply + ELU + segmented pool ===================
// 256 threads = 4 waves; each wave owns one contiguous row chunk.
__global__ void k_bn3_pool(const float* __restrict__ h3raw, const float* __restrict__ sums,
                           const float* __restrict__ g3, const float* __restrict__ b3,
                           const int* __restrict__ batch, float* __restrict__ psum,
                           unsigned* __restrict__ pmax, float* __restrict__ cnt) {
    int w = threadIdx.x >> 6;
    int lane = threadIdx.x & 63;   // lane = feature
    int chunk = blockIdx.x * 4 + w;
    int nchunks = gridDim.x * 4;
    int rows = (NN + nchunks - 1) / nchunks;
    int r0 = chunk * rows;
    int r1 = min(NN, r0 + rows);
    if (r0 >= r1) return;
    float m = sums[lane] * (1.0f / NN);
    float var = sums[F2 + lane] * (1.0f / NN) - m * m;
    float sc = rsqrtf(var + 1e-5f) * g3[lane];
    float bb = b3[lane];
    int curg = batch[r0];
    float ls = 0.f, lm = -INFINITY;
    int run = 0;
    for (int r = r0; r < r1; r++) {
        int gg = batch[r];
        if (gg != curg) {
            atomicAdd(&psum[curg * F2 + lane], ls);
            atomicMax(&pmax[curg * F2 + lane], enc_f(lm));
            if (lane == 0) atomicAdd(&cnt[curg], (float)run);
            curg = gg; ls = 0.f; lm = -INFINITY; run = 0;
        }
        float v = (h3raw[(size_t)r * F2 + lane] - m) * sc + bb;
        v = v > 0.f ? v : expm1f(v);
        ls += v; lm = fmaxf(lm, v); run++;
    }
    atomicAdd(&psum[curg * F2 + lane], ls);
    atomicMax(&pmax[curg * F2 + lane], enc_f(lm));
    if (lane == 0) atomicAdd(&cnt[curg], (float)run);
}

// =================== classifier ===================
__global__ void k_cls(const float* __restrict__ psum, const unsigned* __restrict__ pmax,
                      const float* __restrict__ cnt, const float* __restrict__ w1,
                      const float* __restrict__ b1, const float* __restrict__ w2,
                      const float* __restrict__ b2, float* __restrict__ out) {
    int g = blockIdx.x;
    int j = threadIdx.x;  // 64 threads
    __shared__ float z[2 * F2];
    __shared__ float hid[F2];
    float c = fmaxf(cnt[g], 1.0f);
    z[j] = psum[g * F2 + j] / c;
    float mv = dec_f(pmax[g * F2 + j]);
    z[F2 + j] = isfinite(mv) ? mv : 0.f;
    __syncthreads();
    float acc = b1[j];
#pragma unroll 8
    for (int k = 0; k < 2 * F2; k++) acc += z[k] * w1[k * F2 + j];
    hid[j] = fmaxf(acc, 0.f);
    __syncthreads();
    if (j < NCLS) {
        float o = b2[j];
#pragma unroll 8
        for (int k = 0; k < F2; k++) o += hid[k] * w2[k * NCLS + j];
        out[g * NCLS + j] = o;
    }
}

extern "C" void kernel_launch(void* const* d_in, const int* in_sizes, int n_in,
                              void* d_out, int out_size, void* d_ws, size_t ws_size,
                              hipStream_t stream) {
    const float* x       = (const float*)d_in[0];
    const int*   ei      = (const int*)d_in[1];
    const int*   batch   = (const int*)d_in[2];
    const float* gat_w   = (const float*)d_in[3];
    const float* att_src = (const float*)d_in[4];
    const float* att_dst = (const float*)d_in[5];
    // d_in[6] gat_b: cancels inside BN1
    const float* bn1_g   = (const float*)d_in[7];
    const float* bn1_b   = (const float*)d_in[8];
    const float* sage_wl = (const float*)d_in[9];
    const float* sage_bl = (const float*)d_in[10];
    const float* sage_wr = (const float*)d_in[11];
    const float* bn2_g   = (const float*)d_in[12];
    const float* bn2_b   = (const float*)d_in[13];
    const float* gcn_w   = (const float*)d_in[14];
    const float* gcn_b   = (const float*)d_in[15];
    const float* bn3_g   = (const float*)d_in[16];
    const float* bn3_b   = (const float*)d_in[17];
    const float* w1      = (const float*)d_in[18];
    const float* b1      = (const float*)d_in[19];
    const float* w2      = (const float*)d_in[20];
    const float* b2      = (const float*)d_in[21];
    float* out = (float*)d_out;

    float* ws = (float*)d_ws;
    // workspace layout (4-byte units; 16B alignment maintained)
    size_t o_A    = 0;                        // NN*F1 floats region, aliased (see below)
    size_t o_h1   = o_A   + (size_t)NN * F1;  // NN*F1 f32: GAT raw out; later h2b (bf16)
    size_t o_h2   = o_h1  + (size_t)NN * F1;  // NN*F2 f32: h1b (bf16) first, then h2 raw
    size_t o_csr  = o_h2  + (size_t)NN * F2;  // E ints (csr_src)
    size_t o_rp   = o_csr + (size_t)NE;       // N+4 ints (rowptr, padded for alignment)
    size_t o_deg  = o_rp  + (size_t)(NN + 4); // N ints (degi)
    size_t o_bs   = o_deg + (size_t)NN;       // 512 ints (block sums)
    size_t o_asrc = o_bs  + 512;              // N*2
    size_t o_adst = o_asrc + (size_t)NN * 2;  // N*2
    size_t o_dinv = o_adst + (size_t)NN * 2;  // N
    size_t o_sums = o_dinv + (size_t)NN;      // 256
    size_t o_frd  = o_sums + 256;             // 8192 floats = 32KB dual B-frags
    size_t o_frg  = o_frd  + 8192;            // 2048 floats = 8KB gcn B-frags
    size_t o_psum = o_frg  + 2048;            // G*F2
    size_t o_pmax = o_psum + (size_t)NG * F2; // G*F2
    size_t o_cnt  = o_pmax + (size_t)NG * F2; // G

    float* A    = ws + o_A;
    float* h1   = ws + o_h1;
    float* h2   = ws + o_h2;
    int* csr_src = (int*)(ws + o_csr);
    int* rowptr  = (int*)(ws + o_rp);
    int* degi    = (int*)(ws + o_deg);
    int* bsum    = (int*)(ws + o_bs);
    float* asr  = ws + o_asrc;
    float* ads  = ws + o_adst;
    float* dinv = ws + o_dinv;
    float* sums = ws + o_sums;
    ushort* fragd = (ushort*)(ws + o_frd);
    ushort* fragg = (ushort*)(ws + o_frg);
    float* psum = ws + o_psum;
    unsigned* pmax = (unsigned*)(ws + o_pmax);
    float* cnt  = ws + o_cnt;

    // region aliases (lifetimes disjoint):
    unsigned* staged = (unsigned*)A;                    // CSR build: NE entries (6.4 MB)
    int*    ghist  = (int*)(A + 2 * 1024 * 1024);       // CSR build: NCHUNK*NBUCK ints
    ushort* xw_bf  = (ushort*)A;                        // GAT: NN*F1 bf16 (25.6 MB)
    ushort* u_bf   = (ushort*)A;                        // SAGE: NN*F2 bf16 (xw dead)
    float*  vmat   = A + (size_t)NN * F2 / 2;           // SAGE: NN*F2 f32
    ushort* hwd_bf = (ushort*)A;                        // GCN: NN*F2 bf16 (u dead)
    float*  h3     = A + (size_t)NN * F2 / 2;           // GCN out: NN*F2 f32 (v dead)
    ushort* h1b    = (ushort*)h2;                       // post-BN1 bf16 (= h2 region;
                                                        //   dead before sage_gather2 writes h2)
    ushort* h2b    = (ushort*)h1;                       // post-BN2 bf16 (h1 dead after dualgemm)

    // ---- CSR build: count + node scan, then chunk-major radix ----
    hipMemsetAsync(degi, 0, sizeof(int) * NN, stream);
    k_count<<<(NE + 255) / 256, 256, 0, stream>>>(ei, degi);
    k_scan1<<<NB_SCAN, 256, 0, stream>>>(degi, rowptr, bsum);
    k_scan2<<<1, 512, 0, stream>>>(bsum, NB_SCAN);
    k_scan3<<<NB_SCAN, 256, 0, stream>>>(rowptr, bsum);
    k_hist<<<NCHUNK, 256, 0, stream>>>(ei, ghist);
    k_chunkscan<<<(NBUCK + 255) / 256, 256, 0, stream>>>(ghist, rowptr);
    k_scatter2<<<NCHUNK, 256, 0, stream>>>(ei, ghist, staged);
    k_bucket_sort<<<NBUCK, 256, 0, stream>>>(staged, rowptr, csr_src);

    // ---- GAT (softmax fused into gather) ----
    k_xw<<<NN, F1, 0, stream>>>(x, gat_w, att_src, att_dst, xw_bf, asr, ads);
    k_gat_gather<<<(NN + 3) / 4, 256, 0, stream>>>(rowptr, csr_src, asr, ads,
                                                   (const unsigned*)xw_bf, h1);
    hipMemsetAsync(sums, 0, sizeof(float) * 256, stream);
    k_bn_stats<<<1024, 256, 0, stream>>>(h1, F1, sums);
    k_bn_apply_bf<<<(NN * F1 + 255) / 256, 256, 0, stream>>>(h1, sums, bn1_g, bn1_b,
                                                             F1, NN * F1, h1b);

    // ---- SAGE: MFMA dual-GEMM then bf16 mean-gather ----
    k_packfrag_dual<<<(16384 + 255) / 256, 256, 0, stream>>>(sage_wl, sage_wr, fragd);
    k_sage_dualgemm<<<(NN + 63) / 64, 256, 0, stream>>>(h1b, fragd, u_bf, vmat);
    k_sage_gather2<<<(NN + 3) / 4, 256, 0, stream>>>(rowptr, csr_src, u_bf, vmat, sage_bl, h2);
    hipMemsetAsync(sums, 0, sizeof(float) * 256, stream);
    k_bn_stats<<<1024, 256, 0, stream>>>(h2, F2, sums);
    k_bn_apply_bf<<<(NN * F2 + 255) / 256, 256, 0, stream>>>(h2, sums, bn2_g, bn2_b,
                                                             F2, NN * F2, h2b);

    // ---- GCN: MFMA GEMM (dinv folded) then gather ----
    k_dinv<<<(NN + 255) / 256, 256, 0, stream>>>(degi, dinv);
    k_packfrag_gcn<<<(4096 + 255) / 256, 256, 0, stream>>>(gcn_w, fragg);
    k_gcn_gemm<<<(NN + 63) / 64, 256, 0, stream>>>(h2b, fragg, dinv, hwd_bf);
    k_gcn_gather<<<(NN + 3) / 4, 256, 0, stream>>>(rowptr, csr_src, hwd_bf, dinv, gcn_b, h3);
    hipMemsetAsync(sums, 0, sizeof(float) * 256, stream);
    k_bn_stats<<<1024, 256, 0, stream>>>(h3, F2, sums);

    // ---- fused BN3 + ELU + pooling, then classifier ----
    hipMemsetAsync(psum, 0, sizeof(float) * NG * F2, stream);
    hipMemsetAsync(cnt, 0, sizeof(float) * NG, stream);
    k_fill_u32<<<(NG * F2 + 255) / 256, 256, 0, stream>>>(pmax, ENC_NEG_INF, NG * F2);
    k_bn3_pool<<<1024, 256, 0, stream>>>(h3, sums, bn3_g, bn3_b, batch, psum, pmax, cnt);
    k_cls<<<NG, F2, 0, stream>>>(psum, pmax, cnt, w1, b1, w2, b2, out);
}

// Round 17
// 494.153 us; speedup vs baseline: 2.7502x; 1.1934x over previous
//
#include <hip/hip_runtime.h>
#include <hip/hip_bf16.h>
#include <math.h>

#define NN 100000      // nodes
#define NE 1600000     // edges
#define NG 64          // graphs
#define F_IN 5
#define F1 128         // H*HID
#define F2 64          // HID
#define NCLS 4
#define NCHUNK 250                   // edge chunks (250 * 6400 = NE)
#define CH_E 6400                    // edges per chunk
#define NBUCK ((NN + 255) / 256)     // 391 dst buckets of 256 nodes
#define CAPB 6144                    // bucket capacity in LDS sort

typedef unsigned short ushort;
typedef __bf16 bf16x8 __attribute__((ext_vector_type(8)));
typedef float f32x4 __attribute__((ext_vector_type(4)));

// ---------- bf16 helpers (round-to-nearest-even pack) ----------
__device__ __forceinline__ ushort f2bf(float f) {
    unsigned u = __float_as_uint(f);
    u = (u + 0x7fffu + ((u >> 16) & 1u)) >> 16;
    return (ushort)u;
}
__device__ __forceinline__ float bf2f(ushort h) {
    return __uint_as_float(((unsigned)h) << 16);
}
__device__ __forceinline__ unsigned pack2bf(float a, float b) {
    return (unsigned)f2bf(a) | ((unsigned)f2bf(b) << 16);
}
__device__ __forceinline__ float lo_bf(unsigned p) { return __uint_as_float(p << 16); }
__device__ __forceinline__ float hi_bf(unsigned p) { return __uint_as_float(p & 0xffff0000u); }

// ---------- order-preserving float<->uint encoding for atomicMax ----------
__device__ __forceinline__ unsigned enc_f(float f) {
    unsigned b = __float_as_uint(f);
    return (b & 0x80000000u) ? ~b : (b | 0x80000000u);
}
__device__ __forceinline__ float dec_f(unsigned k) {
    unsigned b = (k & 0x80000000u) ? (k ^ 0x80000000u) : ~k;
    return __uint_as_float(b);
}
#define ENC_NEG_INF 0x007FFFFFu   // enc_f(-inf)

__global__ void k_fill_u32(unsigned* p, unsigned v, int n) {
    int i = blockIdx.x * blockDim.x + threadIdx.x;
    if (i < n) p[i] = v;
}

// =================== MFMA B-fragment packing ===================
__global__ void k_packfrag_dual(const float* __restrict__ wl, const float* __restrict__ wr,
                                ushort* __restrict__ frag) {
    int idx = blockIdx.x * 256 + threadIdx.x;
    if (idx >= 4 * 8 * 64 * 8) return;
    int e = idx & 7;
    int lane = (idx >> 3) & 63;
    int ct = (idx >> 9) & 7;
    int ks = idx >> 12;
    int k = ks * 32 + (lane >> 4) * 8 + e;
    int n = ct * 16 + (lane & 15);
    float val = (n < 64) ? wl[k * 64 + n] : wr[k * 64 + (n - 64)];
    frag[idx] = f2bf(val);
}

__global__ void k_packfrag_gcn(const float* __restrict__ wm, ushort* __restrict__ frag) {
    int idx = blockIdx.x * 256 + threadIdx.x;
    if (idx >= 2 * 4 * 64 * 8) return;
    int e = idx & 7;
    int lane = (idx >> 3) & 63;
    int ct = (idx >> 9) & 3;
    int ks = idx >> 11;
    int k = ks * 32 + (lane >> 4) * 8 + e;
    int n = ct * 16 + (lane & 15);
    frag[idx] = f2bf(wm[k * 64 + n]);
}

// =================== CSR build (radix only: hist -> bchunkscan -> scatter -> sort) ===================
// pass 1: per-chunk histogram over 391 dst buckets
__global__ void k_hist(const int* __restrict__ ei, int* __restrict__ ghist) {
    __shared__ int lh[NBUCK];
    int c = blockIdx.x, t = threadIdx.x;
    for (int b = t; b < NBUCK; b += 256) lh[b] = 0;
    __syncthreads();
    int e0 = c * CH_E;
#pragma unroll
    for (int i = 0; i < CH_E / 256; i++) {
        int d = ei[NE + e0 + t + i * 256];
        atomicAdd(&lh[d >> 8], 1);
    }
    __syncthreads();
    for (int b = t; b < NBUCK; b += 256) ghist[c * NBUCK + b] = lh[b];
}

// pass 2 (1 block, 512 thr): bucket totals -> exclusive bucket bases -> chunk offsets
__global__ void k_bchunkscan(int* __restrict__ ghist, int* __restrict__ bbase,
                             int* __restrict__ rowptr) {
    __shared__ int sh[512];
    int b = threadIdx.x;
    int tot = 0;
    if (b < NBUCK)
        for (int c = 0; c < NCHUNK; c++) tot += ghist[c * NBUCK + b];
    sh[b] = tot;
    __syncthreads();
    for (int off = 1; off < 512; off <<= 1) {
        int v = (b >= off) ? sh[b - off] : 0;
        __syncthreads();
        sh[b] += v;
        __syncthreads();
    }
    int base = sh[b] - tot;   // exclusive prefix
    if (b <= NBUCK) bbase[b] = (b < NBUCK) ? base : NE;
    if (b == 0) rowptr[NN] = NE;
    int run = base;
    if (b < NBUCK)
        for (int c = 0; c < NCHUNK; c++) {
            int h = ghist[c * NBUCK + b];
            ghist[c * NBUCK + b] = run;
            run += h;
        }
}

// pass 3: scatter into bucket-major staged array (packed (dlow<<17)|src)
__global__ void k_scatter2(const int* __restrict__ ei, const int* __restrict__ ghist,
                           unsigned* __restrict__ staged) {
    __shared__ int lcur[NBUCK];
    int c = blockIdx.x, t = threadIdx.x;
    for (int b = t; b < NBUCK; b += 256) lcur[b] = ghist[c * NBUCK + b];
    __syncthreads();
    int e0 = c * CH_E;
#pragma unroll
    for (int i = 0; i < CH_E / 256; i++) {
        int e = e0 + t + i * 256;
        int s = ei[e];
        int d = ei[NE + e];
        int pos = atomicAdd(&lcur[d >> 8], 1);
        staged[pos] = (((unsigned)(d & 255)) << 17) | (unsigned)s;
    }
}

// pass 4: per-bucket LDS histogram + scan (writes rowptr) + counting sort -> csr_src
__global__ void k_bucket_sort(const unsigned* __restrict__ staged, const int* __restrict__ bbase,
                              int* __restrict__ rowptr, int* __restrict__ csr_src) {
    __shared__ unsigned ein[CAPB];
    __shared__ unsigned sout[CAPB];
    __shared__ int lhist[256];
    __shared__ int lps[256];
    int b = blockIdx.x, t = threadIdx.x;
    int n0 = b * 256;
    int g0 = bbase[b];
    int m = bbase[b + 1] - g0;
    lhist[t] = 0;
    __syncthreads();
    if (m <= CAPB) {
        for (int i = t; i < m; i += 256) {
            unsigned u = staged[g0 + i];
            ein[i] = u;
            atomicAdd(&lhist[u >> 17], 1);
        }
        __syncthreads();
        lps[t] = lhist[t];
        __syncthreads();
        for (int off = 1; off < 256; off <<= 1) {
            int v = (t >= off) ? lps[t - off] : 0;
            __syncthreads();
            lps[t] += v;
            __syncthreads();
        }
        int excl = lps[t] - lhist[t];
        if (n0 + t < NN) rowptr[n0 + t] = g0 + excl;
        __syncthreads();
        lhist[t] = excl;   // reuse as cursor
        __syncthreads();
        for (int i = t; i < m; i += 256) {
            unsigned u = ein[i];
            int pos = atomicAdd(&lhist[u >> 17], 1);
            sout[pos] = u & 0x1FFFFu;
        }
        __syncthreads();
        for (int i = t; i < m; i += 256) csr_src[g0 + i] = (int)sout[i];
    } else {
        // statistically unreachable fallback (bucket > CAPB)
        for (int i = t; i < m; i += 256) {
            unsigned u = staged[g0 + i];
            atomicAdd(&lhist[u >> 17], 1);
        }
        __syncthreads();
        lps[t] = lhist[t];
        __syncthreads();
        for (int off = 1; off < 256; off <<= 1) {
            int v = (t >= off) ? lps[t - off] : 0;
            __syncthreads();
            lps[t] += v;
            __syncthreads();
        }
        int excl = lps[t] - lhist[t];
        if (n0 + t < NN) rowptr[n0 + t] = g0 + excl;
        __syncthreads();
        lhist[t] = excl;
        __syncthreads();
        for (int i = t; i < m; i += 256) {
            unsigned u = staged[g0 + i];
            int pos = atomicAdd(&lhist[u >> 17], 1);
            csr_src[g0 + pos] = (int)(u & 0x1FFFFu);
        }
    }
}

// =================== GAT ===================
// xw (bf16 packed pairs) = x @ gat_w ; per-node attention logits.
// 64 nodes/block; weights staged once; wave per node, lane = feats (2l, 2l+1).
__global__ void k_xw(const float* __restrict__ x, const float* __restrict__ gw,
                     const float* __restrict__ aw_src, const float* __restrict__ aw_dst,
                     unsigned* __restrict__ xw32, float* __restrict__ a_src,
                     float* __restrict__ a_dst) {
    __shared__ float w[F_IN * F1];
    int t = threadIdx.x;
    for (int i = t; i < F_IN * F1; i += 256) w[i] = gw[i];
    int wv = t >> 6, lane = t & 63;
    int f0 = 2 * lane, f1 = 2 * lane + 1;
    float as0 = aw_src[f0], as1 = aw_src[f1];
    float ad0 = aw_dst[f0], ad1 = aw_dst[f1];
    __syncthreads();
    int nbase = blockIdx.x * 64;
    for (int it = 0; it < 16; it++) {
        int n = nbase + it * 4 + wv;
        if (n >= NN) break;                       // uniform per wave
        float xs[F_IN];
#pragma unroll
        for (int j = 0; j < F_IN; j++) xs[j] = x[n * F_IN + j];
        float acc0 = 0.f, acc1 = 0.f;
#pragma unroll
        for (int j = 0; j < F_IN; j++) {
            acc0 += xs[j] * w[j * F1 + f0];
            acc1 += xs[j] * w[j * F1 + f1];
        }
        xw32[(size_t)n * 64 + lane] = pack2bf(acc0, acc1);
        float p = acc0 * as0 + acc1 * as1;
        float q = acc0 * ad0 + acc1 * ad1;
#pragma unroll
        for (int off = 1; off < 32; off <<= 1) {  // half-wave reduce: heads stay separate
            p += __shfl_xor(p, off);
            q += __shfl_xor(q, off);
        }
        if (lane == 0)  { a_src[n * 2 + 0] = p; a_dst[n * 2 + 0] = q; }
        if (lane == 32) { a_src[n * 2 + 1] = p; a_dst[n * 2 + 1] = q; }
    }
}

// FUSED softmax + gather: one wave per dst node.
__global__ void k_gat_gather(const int* __restrict__ rowptr, const int* __restrict__ csr_src,
                             const float* __restrict__ a_src, const float* __restrict__ a_dst,
                             const unsigned* __restrict__ xw32, float* __restrict__ h1) {
    int n = blockIdx.x * 4 + (threadIdx.x >> 6);
    int lane = threadIdx.x & 63;
    if (n >= NN) return;
    int j0 = rowptr[n], j1 = rowptr[n + 1];
    int deg = j1 - j0;
    float ad0 = a_dst[n * 2 + 0], ad1 = a_dst[n * 2 + 1];
    float acc0 = 0.f, acc1 = 0.f;
    bool lo = (lane < 32);
    if (deg <= 64) {
        int sl = 0;
        float l0 = -INFINITY, l1 = -INFINITY;
        if (lane < deg) {
            sl = csr_src[j0 + lane];
            l0 = a_src[sl * 2 + 0] + ad0;
            l1 = a_src[sl * 2 + 1] + ad1;
            l0 = l0 > 0.f ? l0 : 0.2f * l0;
            l1 = l1 > 0.f ? l1 : 0.2f * l1;
        }
        float m0 = l0, m1 = l1;
#pragma unroll
        for (int off = 32; off > 0; off >>= 1) {
            m0 = fmaxf(m0, __shfl_xor(m0, off));
            m1 = fmaxf(m1, __shfl_xor(m1, off));
        }
        float e0 = 0.f, e1 = 0.f;
        if (lane < deg) { e0 = expf(l0 - m0); e1 = expf(l1 - m1); }
        float s0 = e0, s1 = e1;
#pragma unroll
        for (int off = 32; off > 0; off >>= 1) {
            s0 += __shfl_xor(s0, off);
            s1 += __shfl_xor(s1, off);
        }
        unsigned al = pack2bf(e0 / (s0 + 1e-16f), e1 / (s1 + 1e-16f));
        int e = 0;
        for (; e + 4 <= deg; e += 4) {
            int s0i = __shfl(sl, e + 0), s1i = __shfl(sl, e + 1),
                s2i = __shfl(sl, e + 2), s3i = __shfl(sl, e + 3);
            unsigned b0 = __shfl(al, e + 0), b1 = __shfl(al, e + 1),
                     b2 = __shfl(al, e + 2), b3 = __shfl(al, e + 3);
            unsigned p0 = xw32[(size_t)s0i * 64 + lane];
            unsigned p1 = xw32[(size_t)s1i * 64 + lane];
            unsigned p2 = xw32[(size_t)s2i * 64 + lane];
            unsigned p3 = xw32[(size_t)s3i * 64 + lane];
            float w0 = lo ? lo_bf(b0) : hi_bf(b0);
            float w1 = lo ? lo_bf(b1) : hi_bf(b1);
            float w2 = lo ? lo_bf(b2) : hi_bf(b2);
            float w3 = lo ? lo_bf(b3) : hi_bf(b3);
            acc0 = fmaf(lo_bf(p0), w0, acc0); acc1 = fmaf(hi_bf(p0), w0, acc1);
            acc0 = fmaf(lo_bf(p1), w1, acc0); acc1 = fmaf(hi_bf(p1), w1, acc1);
            acc0 = fmaf(lo_bf(p2), w2, acc0); acc1 = fmaf(hi_bf(p2), w2, acc1);
            acc0 = fmaf(lo_bf(p3), w3, acc0); acc1 = fmaf(hi_bf(p3), w3, acc1);
        }
        for (; e < deg; e++) {
            int s = __shfl(sl, e); unsigned b = __shfl(al, e);
            unsigned p = xw32[(size_t)s * 64 + lane];
            float w = lo ? lo_bf(b) : hi_bf(b);
            acc0 = fmaf(lo_bf(p), w, acc0);
            acc1 = fmaf(hi_bf(p), w, acc1);
        }
    } else {
        float m0 = -INFINITY, m1 = -INFINITY, s0 = 0.f, s1 = 0.f;
        for (int base = j0; base < j1; base += 64) {
            int myj = base + lane;
            float l0 = -INFINITY, l1 = -INFINITY;
            if (myj < j1) {
                int s = csr_src[myj];
                l0 = a_src[s * 2 + 0] + ad0;
                l1 = a_src[s * 2 + 1] + ad1;
                l0 = l0 > 0.f ? l0 : 0.2f * l0;
                l1 = l1 > 0.f ? l1 : 0.2f * l1;
            }
            float cm0 = l0, cm1 = l1;
#pragma unroll
            for (int off = 32; off > 0; off >>= 1) {
                cm0 = fmaxf(cm0, __shfl_xor(cm0, off));
                cm1 = fmaxf(cm1, __shfl_xor(cm1, off));
            }
            float nm0 = fmaxf(m0, cm0), nm1 = fmaxf(m1, cm1);
            float ce0 = (myj < j1) ? expf(l0 - nm0) : 0.f;
            float ce1 = (myj < j1) ? expf(l1 - nm1) : 0.f;
            float cs0 = ce0, cs1 = ce1;
#pragma unroll
            for (int off = 32; off > 0; off >>= 1) {
                cs0 += __shfl_xor(cs0, off);
                cs1 += __shfl_xor(cs1, off);
            }
            s0 = s0 * expf(m0 - nm0) + cs0;
            s1 = s1 * expf(m1 - nm1) + cs1;
            m0 = nm0; m1 = nm1;
        }
        float r0 = 1.0f / (s0 + 1e-16f), r1 = 1.0f / (s1 + 1e-16f);
        for (int base = j0; base < j1; base += 64) {
            int cnt = min(64, j1 - base);
            int myj = base + lane;
            int sl = 0; unsigned al = 0;
            if (myj < j1) {
                sl = csr_src[myj];
                float l0 = a_src[sl * 2 + 0] + ad0;
                float l1 = a_src[sl * 2 + 1] + ad1;
                l0 = l0 > 0.f ? l0 : 0.2f * l0;
                l1 = l1 > 0.f ? l1 : 0.2f * l1;
                al = pack2bf(expf(l0 - m0) * r0, expf(l1 - m1) * r1);
            }
            int e = 0;
            for (; e + 4 <= cnt; e += 4) {
                int s0i = __shfl(sl, e + 0), s1i = __shfl(sl, e + 1),
                    s2i = __shfl(sl, e + 2), s3i = __shfl(sl, e + 3);
                unsigned b0 = __shfl(al, e + 0), b1 = __shfl(al, e + 1),
                         b2 = __shfl(al, e + 2), b3 = __shfl(al, e + 3);
                unsigned p0 = xw32[(size_t)s0i * 64 + lane];
                unsigned p1 = xw32[(size_t)s1i * 64 + lane];
                unsigned p2 = xw32[(size_t)s2i * 64 + lane];
                unsigned p3 = xw32[(size_t)s3i * 64 + lane];
                float w0 = lo ? lo_bf(b0) : hi_bf(b0);
                float w1 = lo ? lo_bf(b1) : hi_bf(b1);
                float w2 = lo ? lo_bf(b2) : hi_bf(b2);
                float w3 = lo ? lo_bf(b3) : hi_bf(b3);
                acc0 = fmaf(lo_bf(p0), w0, acc0); acc1 = fmaf(hi_bf(p0), w0, acc1);
                acc0 = fmaf(lo_bf(p1), w1, acc0); acc1 = fmaf(hi_bf(p1), w1, acc1);
                acc0 = fmaf(lo_bf(p2), w2, acc0); acc1 = fmaf(hi_bf(p2), w2, acc1);
                acc0 = fmaf(lo_bf(p3), w3, acc0); acc1 = fmaf(hi_bf(p3), w3, acc1);
            }
            for (; e < cnt; e++) {
                int s = __shfl(sl, e); unsigned b = __shfl(al, e);
                unsigned p = xw32[(size_t)s * 64 + lane];
                float w = lo ? lo_bf(b) : hi_bf(b);
                acc0 = fmaf(lo_bf(p), w, acc0);
                acc1 = fmaf(hi_bf(p), w, acc1);
            }
        }
    }
    float2 o; o.x = acc0; o.y = acc1;
    *(float2*)&h1[(size_t)n * F1 + 2 * lane] = o;
}

// =================== BatchNorm ===================
// 256 threads: R=256/nfeat row-groups in flight; LDS-reduce, 1 atomic/feature/block
__global__ void k_bn_stats(const float* __restrict__ h, int nfeat, float* __restrict__ sums) {
    __shared__ float sh[512];
    int t = threadIdx.x;
    int f = t & (nfeat - 1);
    int rg = t / nfeat;
    int R = 256 / nfeat;
    int rows = (NN + gridDim.x - 1) / gridDim.x;
    int rbase = blockIdx.x * rows;
    int r1 = min(NN, rbase + rows);
    float s = 0.f, ss = 0.f;
    for (int r = rbase + rg; r < r1; r += R) {
        float v = h[(size_t)r * nfeat + f];
        s += v; ss += v * v;
    }
    sh[t] = s; sh[256 + t] = ss;
    __syncthreads();
    if (rg == 0) {
        for (int g = 1; g < R; g++) {
            s += sh[g * nfeat + f];
            ss += sh[256 + g * nfeat + f];
        }
        atomicAdd(&sums[f], s);
        atomicAdd(&sums[nfeat + f], ss);
    }
}

// BN apply + ELU, writing bf16 to a SEPARATE buffer (consumed by MFMA GEMMs)
__global__ void k_bn_apply_bf(const float* __restrict__ h, const float* __restrict__ sums,
                              const float* __restrict__ g, const float* __restrict__ b,
                              int nfeat, int total, ushort* __restrict__ hb) {
    int i = blockIdx.x * blockDim.x + threadIdx.x;
    if (i >= total) return;
    int f = i & (nfeat - 1);
    float m = sums[f] * (1.0f / NN);
    float var = sums[nfeat + f] * (1.0f / NN) - m * m;
    float v = (h[i] - m) * rsqrtf(var + 1e-5f) * g[f] + b[f];
    hb[i] = f2bf(v > 0.f ? v : expm1f(v));
}

// =================== SAGE dual GEMM via MFMA ===================
__global__ void k_sage_dualgemm(const ushort* __restrict__ h1b, const ushort* __restrict__ fragd,
                                ushort* __restrict__ u_bf, float* __restrict__ v) {
    __shared__ uint4 sfrag[2048];               // 32 KB
    int t = threadIdx.x;
    const uint4* f4 = (const uint4*)fragd;
    for (int i = t; i < 2048; i += 256) sfrag[i] = f4[i];
    __syncthreads();
    int w = t >> 6, lane = t & 63;
    int row0 = blockIdx.x * 64 + w * 16;
    int arow = row0 + (lane & 15);
    if (arow >= NN) arow = NN - 1;
    f32x4 acc[8];
#pragma unroll
    for (int c = 0; c < 8; c++) acc[c] = (f32x4){0.f, 0.f, 0.f, 0.f};
#pragma unroll
    for (int ks = 0; ks < 4; ks++) {
        union { uint4 u; bf16x8 f; } ua;
        ua.u = *(const uint4*)&h1b[(size_t)arow * F1 + ks * 32 + (lane >> 4) * 8];
#pragma unroll
        for (int ct = 0; ct < 8; ct++) {
            union { uint4 u; bf16x8 f; } ub;
            ub.u = sfrag[(ks * 8 + ct) * 64 + lane];
            acc[ct] = __builtin_amdgcn_mfma_f32_16x16x32_bf16(ua.f, ub.f, acc[ct], 0, 0, 0);
        }
    }
    int mrow0 = row0 + (lane >> 4) * 4;
    int n = lane & 15;
#pragma unroll
    for (int reg = 0; reg < 4; reg++) {
        int r = mrow0 + reg;
        if (r >= NN) continue;
#pragma unroll
        for (int ct = 0; ct < 4; ct++)
            u_bf[(size_t)r * F2 + ct * 16 + n] = f2bf(acc[ct][reg]);
#pragma unroll
        for (int ct = 4; ct < 8; ct++)
            v[(size_t)r * F2 + (ct - 4) * 16 + n] = acc[ct][reg];
    }
}

// h2raw[n] = mean-gather(u_bf16) + v[n] + bl
__global__ void k_sage_gather2(const int* __restrict__ rowptr, const int* __restrict__ csr_src,
                               const ushort* __restrict__ u_bf, const float* __restrict__ v,
                               const float* __restrict__ bl, float* __restrict__ h2) {
    int n = blockIdx.x * 4 + (threadIdx.x >> 6);
    int lane = threadIdx.x & 63;
    if (n >= NN) return;
    int j0 = rowptr[n], j1 = rowptr[n + 1];
    float a = 0.f;
    for (int base = j0; base < j1; base += 64) {
        int cnt = min(64, j1 - base);
        int myj = base + lane;
        int sl = (myj < j1) ? csr_src[myj] : 0;
        int e = 0;
        for (; e + 4 <= cnt; e += 4) {
            int s0 = __shfl(sl, e + 0), s1 = __shfl(sl, e + 1),
                s2 = __shfl(sl, e + 2), s3 = __shfl(sl, e + 3);
            float t0 = bf2f(u_bf[(size_t)s0 * F2 + lane]);
            float t1 = bf2f(u_bf[(size_t)s1 * F2 + lane]);
            float t2 = bf2f(u_bf[(size_t)s2 * F2 + lane]);
            float t3 = bf2f(u_bf[(size_t)s3 * F2 + lane]);
            a += (t0 + t1) + (t2 + t3);
        }
        for (; e < cnt; e++) {
            int s = __shfl(sl, e);
            a += bf2f(u_bf[(size_t)s * F2 + lane]);
        }
    }
    float inv = 1.0f / fmaxf((float)(j1 - j0), 1.0f);
    h2[(size_t)n * F2 + lane] = a * inv + v[(size_t)n * F2 + lane] + bl[lane];
}

__global__ void k_dinv(const int* __restrict__ rowptr, float* __restrict__ dinv) {
    int i = blockIdx.x * blockDim.x + threadIdx.x;
    if (i < NN) dinv[i] = rsqrtf((float)(rowptr[i + 1] - rowptr[i]) + 1.0f);
}

// =================== GCN GEMM via MFMA ===================
__global__ void k_gcn_gemm(const ushort* __restrict__ h2b, const ushort* __restrict__ fragg,
                           const float* __restrict__ dinv, ushort* __restrict__ hwd_bf) {
    __shared__ uint4 sfrag[512];                // 8 KB
    int t = threadIdx.x;
    const uint4* f4 = (const uint4*)fragg;
    for (int i = t; i < 512; i += 256) sfrag[i] = f4[i];
    __syncthreads();
    int w = t >> 6, lane = t & 63;
    int row0 = blockIdx.x * 64 + w * 16;
    int arow = row0 + (lane & 15);
    if (arow >= NN) arow = NN - 1;
    f32x4 acc[4];
#pragma unroll
    for (int c = 0; c < 4; c++) acc[c] = (f32x4){0.f, 0.f, 0.f, 0.f};
#pragma unroll
    for (int ks = 0; ks < 2; ks++) {
        union { uint4 u; bf16x8 f; } ua;
        ua.u = *(const uint4*)&h2b[(size_t)arow * F2 + ks * 32 + (lane >> 4) * 8];
#pragma unroll
        for (int ct = 0; ct < 4; ct++) {
            union { uint4 u; bf16x8 f; } ub;
            ub.u = sfrag[(ks * 4 + ct) * 64 + lane];
            acc[ct] = __builtin_amdgcn_mfma_f32_16x16x32_bf16(ua.f, ub.f, acc[ct], 0, 0, 0);
        }
    }
    int mrow0 = row0 + (lane >> 4) * 4;
    int n = lane & 15;
#pragma unroll
    for (int reg = 0; reg < 4; reg++) {
        int r = mrow0 + reg;
        if (r >= NN) continue;
        float d = dinv[r];
#pragma unroll
        for (int ct = 0; ct < 4; ct++)
            hwd_bf[(size_t)r * F2 + ct * 16 + n] = f2bf(acc[ct][reg] * d);
    }
}

// h3 = dinv[n]*(sum_src hwd[s] + hwd[n]) + gb
__global__ void k_gcn_gather(const int* __restrict__ rowptr, const int* __restrict__ csr_src,
                             const ushort* __restrict__ hwd_bf, const float* __restrict__ dinv,
                             const float* __restrict__ gb, float* __restrict__ h3) {
    int n = blockIdx.x * 4 + (threadIdx.x >> 6);
    int lane = threadIdx.x & 63;
    if (n >= NN) return;
    int j0 = rowptr[n], j1 = rowptr[n + 1];
    float acc = 0.f;
    for (int base = j0; base < j1; base += 64) {
        int cnt = min(64, j1 - base);
        int myj = base + lane;
        int sl = (myj < j1) ? csr_src[myj] : 0;
        int e = 0;
        for (; e + 4 <= cnt; e += 4) {
            int s0 = __shfl(sl, e + 0), s1 = __shfl(sl, e + 1),
                s2 = __shfl(sl, e + 2), s3 = __shfl(sl, e + 3);
            float t0 = bf2f(hwd_bf[(size_t)s0 * F2 + lane]);
            float t1 = bf2f(hwd_bf[(size_t)s1 * F2 + lane]);
            float t2 = bf2f(hwd_bf[(size_t)s2 * F2 + lane]);
            float t3 = bf2f(hwd_bf[(size_t)s3 * F2 + lane]);
            acc += (t0 + t1) + (t2 + t3);
        }
        for (; e < cnt; e++) {
            int s = __shfl(sl, e);
            acc += bf2f(hwd_bf[(size_t)s * F2 + lane]);
        }
    }
    float di = dinv[n];
    acc += bf2f(hwd_bf[(size_t)n * F2 + lane]);
    h3[(size_t)n * F2 + lane] = acc * di + gb[lane];
}

// =================== fused BN3-apply + ELU + segmented pool ===================
// 256 threads = 4 waves; each wave owns one contiguous row chunk.
__global__ void k_bn3_pool(const float* __restrict__ h3raw, const float* __restrict__ sums,
                           const float* __restrict__ g3, const float* __restrict__ b3,
                           const int* __restrict__ batch, float* __restrict__ psum,
                           unsigned* __restrict__ pmax, float* __restrict__ cnt) {
    int w = threadIdx.x >> 6;
    int lane = threadIdx.x & 63;   // lane = feature
    int chunk = blockIdx.x * 4 + w;
    int nchunks = gridDim.x * 4;
    int rows = (NN + nchunks - 1) / nchunks;
    int r0 = chunk * rows;
    int r1 = min(NN, r0 + rows);
    if (r0 >= r1) return;
    float m = sums[lane] * (1.0f / NN);
    float var = sums[F2 + lane] * (1.0f / NN) - m * m;
    float sc = rsqrtf(var + 1e-5f) * g3[lane];
    float bb = b3[lane];
    int curg = batch[r0];
    float ls = 0.f, lm = -INFINITY;
    int run = 0;
    for (int r = r0; r < r1; r++) {
        int gg = batch[r];
        if (gg != curg) {
            atomicAdd(&psum[curg * F2 + lane], ls);
            atomicMax(&pmax[curg * F2 + lane], enc_f(lm));
            if (lane == 0) atomicAdd(&cnt[curg], (float)run);
            curg = gg; ls = 0.f; lm = -INFINITY; run = 0;
        }
        float v = (h3raw[(size_t)r * F2 + lane] - m) * sc + bb;
        v = v > 0.f ? v : expm1f(v);
        ls += v; lm = fmaxf(lm, v); run++;
    }
    atomicAdd(&psum[curg * F2 + lane], ls);
    atomicMax(&pmax[curg * F2 + lane], enc_f(lm));
    if (lane == 0) atomicAdd(&cnt[curg], (float)run);
}

// =================== classifier ===================
__global__ void k_cls(const float* __restrict__ psum, const unsigned* __restrict__ pmax,
                      const float* __restrict__ cnt, const float* __restrict__ w1,
                      const float* __restrict__ b1, const float* __restrict__ w2,
                      const float* __restrict__ b2, float* __restrict__ out) {
    int g = blockIdx.x;
    int j = threadIdx.x;  // 64 threads
    __shared__ float z[2 * F2];
    __shared__ float hid[F2];
    float c = fmaxf(cnt[g], 1.0f);
    z[j] = psum[g * F2 + j] / c;
    float mv = dec_f(pmax[g * F2 + j]);
    z[F2 + j] = isfinite(mv) ? mv : 0.f;
    __syncthreads();
    float acc = b1[j];
#pragma unroll 8
    for (int k = 0; k < 2 * F2; k++) acc += z[k] * w1[k * F2 + j];
    hid[j] = fmaxf(acc, 0.f);
    __syncthreads();
    if (j < NCLS) {
        float o = b2[j];
#pragma unroll 8
        for (int k = 0; k < F2; k++) o += hid[k] * w2[k * NCLS + j];
        out[g * NCLS + j] = o;
    }
}

extern "C" void kernel_launch(void* const* d_in, const int* in_sizes, int n_in,
                              void* d_out, int out_size, void* d_ws, size_t ws_size,
                              hipStream_t stream) {
    const float* x       = (const float*)d_in[0];
    const int*   ei      = (const int*)d_in[1];
    const int*   batch   = (const int*)d_in[2];
    const float* gat_w   = (const float*)d_in[3];
    const float* att_src = (const float*)d_in[4];
    const float* att_dst = (const float*)d_in[5];
    // d_in[6] gat_b: cancels inside BN1
    const float* bn1_g   = (const float*)d_in[7];
    const float* bn1_b   = (const float*)d_in[8];
    const float* sage_wl = (const float*)d_in[9];
    const float* sage_bl = (const float*)d_in[10];
    const float* sage_wr = (const float*)d_in[11];
    const float* bn2_g   = (const float*)d_in[12];
    const float* bn2_b   = (const float*)d_in[13];
    const float* gcn_w   = (const float*)d_in[14];
    const float* gcn_b   = (const float*)d_in[15];
    const float* bn3_g   = (const float*)d_in[16];
    const float* bn3_b   = (const float*)d_in[17];
    const float* w1      = (const float*)d_in[18];
    const float* b1      = (const float*)d_in[19];
    const float* w2      = (const float*)d_in[20];
    const float* b2      = (const float*)d_in[21];
    float* out = (float*)d_out;

    float* ws = (float*)d_ws;
    // workspace layout (4-byte units; 16B alignment maintained)
    size_t o_A    = 0;                        // NN*F1 floats region, aliased (see below)
    size_t o_h1   = o_A   + (size_t)NN * F1;  // NN*F1 f32: GAT raw out; later h2b (bf16)
    size_t o_h2   = o_h1  + (size_t)NN * F1;  // NN*F2 f32: h1b (bf16) first, then h2 raw
    size_t o_csr  = o_h2  + (size_t)NN * F2;  // E ints (csr_src)
    size_t o_rp   = o_csr + (size_t)NE;       // N+4 ints (rowptr)
    size_t o_bb   = o_rp  + (size_t)(NN + 4); // NBUCK+1 ints (bucket bases), padded
    size_t o_asrc = o_bb  + 400;              // N*2
    size_t o_adst = o_asrc + (size_t)NN * 2;  // N*2
    size_t o_dinv = o_adst + (size_t)NN * 2;  // N
    size_t o_sums = o_dinv + (size_t)NN;      // 256
    size_t o_frd  = o_sums + 256;             // 8192 floats = 32KB dual B-frags
    size_t o_frg  = o_frd  + 8192;            // 2048 floats = 8KB gcn B-frags
    size_t o_psum = o_frg  + 2048;            // G*F2
    size_t o_pmax = o_psum + (size_t)NG * F2; // G*F2
    size_t o_cnt  = o_pmax + (size_t)NG * F2; // G

    float* A    = ws + o_A;
    float* h1   = ws + o_h1;
    float* h2   = ws + o_h2;
    int* csr_src = (int*)(ws + o_csr);
    int* rowptr  = (int*)(ws + o_rp);
    int* bbase   = (int*)(ws + o_bb);
    float* asr  = ws + o_asrc;
    float* ads  = ws + o_adst;
    float* dinv = ws + o_dinv;
    float* sums = ws + o_sums;
    ushort* fragd = (ushort*)(ws + o_frd);
    ushort* fragg = (ushort*)(ws + o_frg);
    float* psum = ws + o_psum;
    unsigned* pmax = (unsigned*)(ws + o_pmax);
    float* cnt  = ws + o_cnt;

    // region aliases (lifetimes disjoint):
    unsigned* staged = (unsigned*)A;                    // CSR build: NE entries (6.4 MB)
    int*    ghist  = (int*)(A + 2 * 1024 * 1024);       // CSR build: NCHUNK*NBUCK ints
    unsigned* xw32 = (unsigned*)A;                      // GAT: NN*64 packed bf16 pairs
    ushort* u_bf   = (ushort*)A;                        // SAGE: NN*F2 bf16 (xw dead)
    float*  vmat   = A + (size_t)NN * F2 / 2;           // SAGE: NN*F2 f32
    ushort* hwd_bf = (ushort*)A;                        // GCN: NN*F2 bf16 (u dead)
    float*  h3     = A + (size_t)NN * F2 / 2;           // GCN out: NN*F2 f32 (v dead)
    ushort* h1b    = (ushort*)h2;                       // post-BN1 bf16 (= h2 region)
    ushort* h2b    = (ushort*)h1;                       // post-BN2 bf16 (h1 dead after dualgemm)

    // ---- CSR build: chunk-major radix (hist -> bchunkscan -> scatter -> sort) ----
    k_hist<<<NCHUNK, 256, 0, stream>>>(ei, ghist);
    k_bchunkscan<<<1, 512, 0, stream>>>(ghist, bbase, rowptr);
    k_scatter2<<<NCHUNK, 256, 0, stream>>>(ei, ghist, staged);
    k_bucket_sort<<<NBUCK, 256, 0, stream>>>(staged, bbase, rowptr, csr_src);

    // ---- GAT (softmax fused into gather) ----
    k_xw<<<(NN + 63) / 64, 256, 0, stream>>>(x, gat_w, att_src, att_dst, xw32, asr, ads);
    k_gat_gather<<<(NN + 3) / 4, 256, 0, stream>>>(rowptr, csr_src, asr, ads, xw32, h1);
    hipMemsetAsync(sums, 0, sizeof(float) * 256, stream);
    k_bn_stats<<<1024, 256, 0, stream>>>(h1, F1, sums);
    k_bn_apply_bf<<<(NN * F1 + 255) / 256, 256, 0, stream>>>(h1, sums, bn1_g, bn1_b,
                                                             F1, NN * F1, h1b);

    // ---- SAGE: MFMA dual-GEMM then bf16 mean-gather ----
    k_packfrag_dual<<<(16384 + 255) / 256, 256, 0, stream>>>(sage_wl, sage_wr, fragd);
    k_sage_dualgemm<<<(NN + 63) / 64, 256, 0, stream>>>(h1b, fragd, u_bf, vmat);
    k_sage_gather2<<<(NN + 3) / 4, 256, 0, stream>>>(rowptr, csr_src, u_bf, vmat, sage_bl, h2);
    hipMemsetAsync(sums, 0, sizeof(float) * 256, stream);
    k_bn_stats<<<1024, 256, 0, stream>>>(h2, F2, sums);
    k_bn_apply_bf<<<(NN * F2 + 255) / 256, 256, 0, stream>>>(h2, sums, bn2_g, bn2_b,
                                                             F2, NN * F2, h2b);

    // ---- GCN: MFMA GEMM (dinv folded) then gather ----
    k_dinv<<<(NN + 255) / 256, 256, 0, stream>>>(rowptr, dinv);
    k_packfrag_gcn<<<(4096 + 255) / 256, 256, 0, stream>>>(gcn_w, fragg);
    k_gcn_gemm<<<(NN + 63) / 64, 256, 0, stream>>>(h2b, fragg, dinv, hwd_bf);
    k_gcn_gather<<<(NN + 3) / 4, 256, 0, stream>>>(rowptr, csr_src, hwd_bf, dinv, gcn_b, h3);
    hipMemsetAsync(sums, 0, sizeof(float) * 256, stream);
    k_bn_stats<<<1024, 256, 0, stream>>>(h3, F2, sums);

    // ---- fused BN3 + ELU + pooling, then classifier ----
    hipMemsetAsync(psum, 0, sizeof(float) * NG * F2, stream);
    hipMemsetAsync(cnt, 0, sizeof(float) * NG, stream);
    k_fill_u32<<<(NG * F2 + 255) / 256, 256, 0, stream>>>(pmax, ENC_NEG_INF, NG * F2);
    k_bn3_pool<<<1024, 256, 0, stream>>>(h3, sums, bn3_g, bn3_b, batch, psum, pmax, cnt);
    k_cls<<<NG, F2, 0, stream>>>(psum, pmax, cnt, w1, b1, w2, b2, out);
}

// Round 18
// 474.902 us; speedup vs baseline: 2.8617x; 1.0405x over previous
//
#include <hip/hip_runtime.h>
#include <hip/hip_bf16.h>
#include <math.h>

#define NN 100000      // nodes
#define NE 1600000     // edges
#define NG 64          // graphs
#define F_IN 5
#define F1 128         // H*HID
#define F2 64          // HID
#define NCLS 4
#define NCHUNK 250                   // edge chunks (250 * 6400 = NE)
#define CH_E 6400                    // edges per chunk
#define NBUCK ((NN + 255) / 256)     // 391 dst buckets of 256 nodes
#define CAPB 6144                    // bucket capacity in LDS sort

typedef unsigned short ushort;
typedef __bf16 bf16x8 __attribute__((ext_vector_type(8)));
typedef float f32x4 __attribute__((ext_vector_type(4)));

// ---------- bf16 helpers (round-to-nearest-even pack) ----------
__device__ __forceinline__ ushort f2bf(float f) {
    unsigned u = __float_as_uint(f);
    u = (u + 0x7fffu + ((u >> 16) & 1u)) >> 16;
    return (ushort)u;
}
__device__ __forceinline__ float bf2f(ushort h) {
    return __uint_as_float(((unsigned)h) << 16);
}
__device__ __forceinline__ unsigned pack2bf(float a, float b) {
    return (unsigned)f2bf(a) | ((unsigned)f2bf(b) << 16);
}
__device__ __forceinline__ float lo_bf(unsigned p) { return __uint_as_float(p << 16); }
__device__ __forceinline__ float hi_bf(unsigned p) { return __uint_as_float(p & 0xffff0000u); }

// ---------- order-preserving float<->uint encoding for atomicMax ----------
__device__ __forceinline__ unsigned enc_f(float f) {
    unsigned b = __float_as_uint(f);
    return (b & 0x80000000u) ? ~b : (b | 0x80000000u);
}
__device__ __forceinline__ float dec_f(unsigned k) {
    unsigned b = (k & 0x80000000u) ? (k ^ 0x80000000u) : ~k;
    return __uint_as_float(b);
}
#define ENC_NEG_INF 0x007FFFFFu   // enc_f(-inf)

__global__ void k_fill_u32(unsigned* p, unsigned v, int n) {
    int i = blockIdx.x * blockDim.x + threadIdx.x;
    if (i < n) p[i] = v;
}

// =================== MFMA B-fragment packing ===================
__global__ void k_packfrag_dual(const float* __restrict__ wl, const float* __restrict__ wr,
                                ushort* __restrict__ frag) {
    int idx = blockIdx.x * 256 + threadIdx.x;
    if (idx >= 4 * 8 * 64 * 8) return;
    int e = idx & 7;
    int lane = (idx >> 3) & 63;
    int ct = (idx >> 9) & 7;
    int ks = idx >> 12;
    int k = ks * 32 + (lane >> 4) * 8 + e;
    int n = ct * 16 + (lane & 15);
    float val = (n < 64) ? wl[k * 64 + n] : wr[k * 64 + (n - 64)];
    frag[idx] = f2bf(val);
}

__global__ void k_packfrag_gcn(const float* __restrict__ wm, ushort* __restrict__ frag) {
    int idx = blockIdx.x * 256 + threadIdx.x;
    if (idx >= 2 * 4 * 64 * 8) return;
    int e = idx & 7;
    int lane = (idx >> 3) & 63;
    int ct = (idx >> 9) & 3;
    int ks = idx >> 11;
    int k = ks * 32 + (lane >> 4) * 8 + e;
    int n = ct * 16 + (lane & 15);
    frag[idx] = f2bf(wm[k * 64 + n]);
}

// =================== CSR build (radix: hist -> bscan -> bprefix -> scatter -> sort) ===========
// pass 1: per-chunk histogram over 391 dst buckets
__global__ void k_hist(const int* __restrict__ ei, int* __restrict__ ghist) {
    __shared__ int lh[NBUCK];
    int c = blockIdx.x, t = threadIdx.x;
    for (int b = t; b < NBUCK; b += 256) lh[b] = 0;
    __syncthreads();
    int e0 = c * CH_E;
#pragma unroll
    for (int i = 0; i < CH_E / 256; i++) {
        int d = ei[NE + e0 + t + i * 256];
        atomicAdd(&lh[d >> 8], 1);
    }
    __syncthreads();
    for (int b = t; b < NBUCK; b += 256) ghist[c * NBUCK + b] = lh[b];
}

// pass 2a: per-bucket exclusive scan over chunks (grid = NBUCK blocks); totals out
__global__ void k_bscan(int* __restrict__ ghist, int* __restrict__ btot) {
    __shared__ int sh[256];
    int b = blockIdx.x, t = threadIdx.x;
    int v = (t < NCHUNK) ? ghist[t * NBUCK + b] : 0;
    sh[t] = v;
    __syncthreads();
    for (int off = 1; off < 256; off <<= 1) {
        int u = (t >= off) ? sh[t - off] : 0;
        __syncthreads();
        sh[t] += u;
        __syncthreads();
    }
    if (t < NCHUNK) ghist[t * NBUCK + b] = sh[t] - v;   // exclusive, bucket-local
    if (t == 255) btot[b] = sh[255];
}

// pass 2b (1 small block): exclusive prefix of bucket totals -> bbase
__global__ void k_bprefix(const int* __restrict__ btot, int* __restrict__ bbase,
                          int* __restrict__ rowptr) {
    __shared__ int sh[512];
    int t = threadIdx.x;
    int v = (t < NBUCK) ? btot[t] : 0;
    sh[t] = v;
    __syncthreads();
    for (int off = 1; off < 512; off <<= 1) {
        int u = (t >= off) ? sh[t - off] : 0;
        __syncthreads();
        sh[t] += u;
        __syncthreads();
    }
    if (t < NBUCK) bbase[t] = sh[t] - v;
    if (t == 0) { bbase[NBUCK] = NE; rowptr[NN] = NE; }
}

// pass 3: scatter into bucket-major staged array (packed (dlow<<17)|src)
__global__ void k_scatter2(const int* __restrict__ ei, const int* __restrict__ ghist,
                           const int* __restrict__ bbase, unsigned* __restrict__ staged) {
    __shared__ int lcur[NBUCK];
    int c = blockIdx.x, t = threadIdx.x;
    for (int b = t; b < NBUCK; b += 256) lcur[b] = ghist[c * NBUCK + b] + bbase[b];
    __syncthreads();
    int e0 = c * CH_E;
#pragma unroll
    for (int i = 0; i < CH_E / 256; i++) {
        int e = e0 + t + i * 256;
        int s = ei[e];
        int d = ei[NE + e];
        int pos = atomicAdd(&lcur[d >> 8], 1);
        staged[pos] = (((unsigned)(d & 255)) << 17) | (unsigned)s;
    }
}

// pass 4: per-bucket LDS histogram + scan (writes rowptr, dinv) + counting sort -> csr_src
__global__ void k_bucket_sort(const unsigned* __restrict__ staged, const int* __restrict__ bbase,
                              int* __restrict__ rowptr, int* __restrict__ csr_src,
                              float* __restrict__ dinv) {
    __shared__ unsigned ein[CAPB];
    __shared__ unsigned sout[CAPB];
    __shared__ int lhist[256];
    __shared__ int lps[256];
    int b = blockIdx.x, t = threadIdx.x;
    int n0 = b * 256;
    int g0 = bbase[b];
    int m = bbase[b + 1] - g0;
    lhist[t] = 0;
    __syncthreads();
    if (m <= CAPB) {
        for (int i = t; i < m; i += 256) {
            unsigned u = staged[g0 + i];
            ein[i] = u;
            atomicAdd(&lhist[u >> 17], 1);
        }
        __syncthreads();
        if (n0 + t < NN) dinv[n0 + t] = rsqrtf((float)lhist[t] + 1.0f);
        lps[t] = lhist[t];
        __syncthreads();
        for (int off = 1; off < 256; off <<= 1) {
            int v = (t >= off) ? lps[t - off] : 0;
            __syncthreads();
            lps[t] += v;
            __syncthreads();
        }
        int excl = lps[t] - lhist[t];
        if (n0 + t < NN) rowptr[n0 + t] = g0 + excl;
        __syncthreads();
        lhist[t] = excl;   // reuse as cursor
        __syncthreads();
        for (int i = t; i < m; i += 256) {
            unsigned u = ein[i];
            int pos = atomicAdd(&lhist[u >> 17], 1);
            sout[pos] = u & 0x1FFFFu;
        }
        __syncthreads();
        for (int i = t; i < m; i += 256) csr_src[g0 + i] = (int)sout[i];
    } else {
        // statistically unreachable fallback (bucket > CAPB)
        for (int i = t; i < m; i += 256) {
            unsigned u = staged[g0 + i];
            atomicAdd(&lhist[u >> 17], 1);
        }
        __syncthreads();
        if (n0 + t < NN) dinv[n0 + t] = rsqrtf((float)lhist[t] + 1.0f);
        lps[t] = lhist[t];
        __syncthreads();
        for (int off = 1; off < 256; off <<= 1) {
            int v = (t >= off) ? lps[t - off] : 0;
            __syncthreads();
            lps[t] += v;
            __syncthreads();
        }
        int excl = lps[t] - lhist[t];
        if (n0 + t < NN) rowptr[n0 + t] = g0 + excl;
        __syncthreads();
        lhist[t] = excl;
        __syncthreads();
        for (int i = t; i < m; i += 256) {
            unsigned u = staged[g0 + i];
            int pos = atomicAdd(&lhist[u >> 17], 1);
            csr_src[g0 + pos] = (int)(u & 0x1FFFFu);
        }
    }
}

// =================== GAT ===================
// xw (bf16 packed pairs) = x @ gat_w ; per-node attention logits.
__global__ void k_xw(const float* __restrict__ x, const float* __restrict__ gw,
                     const float* __restrict__ aw_src, const float* __restrict__ aw_dst,
                     unsigned* __restrict__ xw32, float* __restrict__ a_src,
                     float* __restrict__ a_dst) {
    __shared__ float w[F_IN * F1];
    int t = threadIdx.x;
    for (int i = t; i < F_IN * F1; i += 256) w[i] = gw[i];
    int wv = t >> 6, lane = t & 63;
    int f0 = 2 * lane, f1 = 2 * lane + 1;
    float as0 = aw_src[f0], as1 = aw_src[f1];
    float ad0 = aw_dst[f0], ad1 = aw_dst[f1];
    __syncthreads();
    int nbase = blockIdx.x * 64;
    for (int it = 0; it < 16; it++) {
        int n = nbase + it * 4 + wv;
        if (n >= NN) break;
        float xs[F_IN];
#pragma unroll
        for (int j = 0; j < F_IN; j++) xs[j] = x[n * F_IN + j];
        float acc0 = 0.f, acc1 = 0.f;
#pragma unroll
        for (int j = 0; j < F_IN; j++) {
            acc0 += xs[j] * w[j * F1 + f0];
            acc1 += xs[j] * w[j * F1 + f1];
        }
        xw32[(size_t)n * 64 + lane] = pack2bf(acc0, acc1);
        float p = acc0 * as0 + acc1 * as1;
        float q = acc0 * ad0 + acc1 * ad1;
#pragma unroll
        for (int off = 1; off < 32; off <<= 1) {
            p += __shfl_xor(p, off);
            q += __shfl_xor(q, off);
        }
        if (lane == 0)  { a_src[n * 2 + 0] = p; a_dst[n * 2 + 0] = q; }
        if (lane == 32) { a_src[n * 2 + 1] = p; a_dst[n * 2 + 1] = q; }
    }
}

// FUSED softmax + gather: one wave per dst node; h1 written as packed bf16 pairs.
__global__ void k_gat_gather(const int* __restrict__ rowptr, const int* __restrict__ csr_src,
                             const float* __restrict__ a_src, const float* __restrict__ a_dst,
                             const unsigned* __restrict__ xw32, unsigned* __restrict__ h1p) {
    int n = blockIdx.x * 4 + (threadIdx.x >> 6);
    int lane = threadIdx.x & 63;
    if (n >= NN) return;
    int j0 = rowptr[n], j1 = rowptr[n + 1];
    int deg = j1 - j0;
    float ad0 = a_dst[n * 2 + 0], ad1 = a_dst[n * 2 + 1];
    float acc0 = 0.f, acc1 = 0.f;
    bool lo = (lane < 32);
    if (deg <= 64) {
        int sl = 0;
        float l0 = -INFINITY, l1 = -INFINITY;
        if (lane < deg) {
            sl = csr_src[j0 + lane];
            l0 = a_src[sl * 2 + 0] + ad0;
            l1 = a_src[sl * 2 + 1] + ad1;
            l0 = l0 > 0.f ? l0 : 0.2f * l0;
            l1 = l1 > 0.f ? l1 : 0.2f * l1;
        }
        float m0 = l0, m1 = l1;
#pragma unroll
        for (int off = 32; off > 0; off >>= 1) {
            m0 = fmaxf(m0, __shfl_xor(m0, off));
            m1 = fmaxf(m1, __shfl_xor(m1, off));
        }
        float e0 = 0.f, e1 = 0.f;
        if (lane < deg) { e0 = expf(l0 - m0); e1 = expf(l1 - m1); }
        float s0 = e0, s1 = e1;
#pragma unroll
        for (int off = 32; off > 0; off >>= 1) {
            s0 += __shfl_xor(s0, off);
            s1 += __shfl_xor(s1, off);
        }
        unsigned al = pack2bf(e0 / (s0 + 1e-16f), e1 / (s1 + 1e-16f));
        int e = 0;
        for (; e + 4 <= deg; e += 4) {
            int s0i = __shfl(sl, e + 0), s1i = __shfl(sl, e + 1),
                s2i = __shfl(sl, e + 2), s3i = __shfl(sl, e + 3);
            unsigned b0 = __shfl(al, e + 0), b1 = __shfl(al, e + 1),
                     b2 = __shfl(al, e + 2), b3 = __shfl(al, e + 3);
            unsigned p0 = xw32[(size_t)s0i * 64 + lane];
            unsigned p1 = xw32[(size_t)s1i * 64 + lane];
            unsigned p2 = xw32[(size_t)s2i * 64 + lane];
            unsigned p3 = xw32[(size_t)s3i * 64 + lane];
            float w0 = lo ? lo_bf(b0) : hi_bf(b0);
            float w1 = lo ? lo_bf(b1) : hi_bf(b1);
            float w2 = lo ? lo_bf(b2) : hi_bf(b2);
            float w3 = lo ? lo_bf(b3) : hi_bf(b3);
            acc0 = fmaf(lo_bf(p0), w0, acc0); acc1 = fmaf(hi_bf(p0), w0, acc1);
            acc0 = fmaf(lo_bf(p1), w1, acc0); acc1 = fmaf(hi_bf(p1), w1, acc1);
            acc0 = fmaf(lo_bf(p2), w2, acc0); acc1 = fmaf(hi_bf(p2), w2, acc1);
            acc0 = fmaf(lo_bf(p3), w3, acc0); acc1 = fmaf(hi_bf(p3), w3, acc1);
        }
        for (; e < deg; e++) {
            int s = __shfl(sl, e); unsigned b = __shfl(al, e);
            unsigned p = xw32[(size_t)s * 64 + lane];
            float w = lo ? lo_bf(b) : hi_bf(b);
            acc0 = fmaf(lo_bf(p), w, acc0);
            acc1 = fmaf(hi_bf(p), w, acc1);
        }
    } else {
        float m0 = -INFINITY, m1 = -INFINITY, s0 = 0.f, s1 = 0.f;
        for (int base = j0; base < j1; base += 64) {
            int myj = base + lane;
            float l0 = -INFINITY, l1 = -INFINITY;
            if (myj < j1) {
                int s = csr_src[myj];
                l0 = a_src[s * 2 + 0] + ad0;
                l1 = a_src[s * 2 + 1] + ad1;
                l0 = l0 > 0.f ? l0 : 0.2f * l0;
                l1 = l1 > 0.f ? l1 : 0.2f * l1;
            }
            float cm0 = l0, cm1 = l1;
#pragma unroll
            for (int off = 32; off > 0; off >>= 1) {
                cm0 = fmaxf(cm0, __shfl_xor(cm0, off));
                cm1 = fmaxf(cm1, __shfl_xor(cm1, off));
            }
            float nm0 = fmaxf(m0, cm0), nm1 = fmaxf(m1, cm1);
            float ce0 = (myj < j1) ? expf(l0 - nm0) : 0.f;
            float ce1 = (myj < j1) ? expf(l1 - nm1) : 0.f;
            float cs0 = ce0, cs1 = ce1;
#pragma unroll
            for (int off = 32; off > 0; off >>= 1) {
                cs0 += __shfl_xor(cs0, off);
                cs1 += __shfl_xor(cs1, off);
            }
            s0 = s0 * expf(m0 - nm0) + cs0;
            s1 = s1 * expf(m1 - nm1) + cs1;
            m0 = nm0; m1 = nm1;
        }
        float r0 = 1.0f / (s0 + 1e-16f), r1 = 1.0f / (s1 + 1e-16f);
        for (int base = j0; base < j1; base += 64) {
            int cnt = min(64, j1 - base);
            int myj = base + lane;
            int sl = 0; unsigned al = 0;
            if (myj < j1) {
                sl = csr_src[myj];
                float l0 = a_src[sl * 2 + 0] + ad0;
                float l1 = a_src[sl * 2 + 1] + ad1;
                l0 = l0 > 0.f ? l0 : 0.2f * l0;
                l1 = l1 > 0.f ? l1 : 0.2f * l1;
                al = pack2bf(expf(l0 - m0) * r0, expf(l1 - m1) * r1);
            }
            int e = 0;
            for (; e + 4 <= cnt; e += 4) {
                int s0i = __shfl(sl, e + 0), s1i = __shfl(sl, e + 1),
                    s2i = __shfl(sl, e + 2), s3i = __shfl(sl, e + 3);
                unsigned b0 = __shfl(al, e + 0), b1 = __shfl(al, e + 1),
                         b2 = __shfl(al, e + 2), b3 = __shfl(al, e + 3);
                unsigned p0 = xw32[(size_t)s0i * 64 + lane];
                unsigned p1 = xw32[(size_t)s1i * 64 + lane];
                unsigned p2 = xw32[(size_t)s2i * 64 + lane];
                unsigned p3 = xw32[(size_t)s3i * 64 + lane];
                float w0 = lo ? lo_bf(b0) : hi_bf(b0);
                float w1 = lo ? lo_bf(b1) : hi_bf(b1);
                float w2 = lo ? lo_bf(b2) : hi_bf(b2);
                float w3 = lo ? lo_bf(b3) : hi_bf(b3);
                acc0 = fmaf(lo_bf(p0), w0, acc0); acc1 = fmaf(hi_bf(p0), w0, acc1);
                acc0 = fmaf(lo_bf(p1), w1, acc0); acc1 = fmaf(hi_bf(p1), w1, acc1);
                acc0 = fmaf(lo_bf(p2), w2, acc0); acc1 = fmaf(hi_bf(p2), w2, acc1);
                acc0 = fmaf(lo_bf(p3), w3, acc0); acc1 = fmaf(hi_bf(p3), w3, acc1);
            }
            for (; e < cnt; e++) {
                int s = __shfl(sl, e); unsigned b = __shfl(al, e);
                unsigned p = xw32[(size_t)s * 64 + lane];
                float w = lo ? lo_bf(b) : hi_bf(b);
                acc0 = fmaf(lo_bf(p), w, acc0);
                acc1 = fmaf(hi_bf(p), w, acc1);
            }
        }
    }
    h1p[(size_t)n * 64 + lane] = pack2bf(acc0, acc1);
}

// =================== BatchNorm (bf16 inputs) ===================
__global__ void k_bn_stats_bf(const ushort* __restrict__ h, int nfeat, float* __restrict__ sums) {
    __shared__ float sh[512];
    int t = threadIdx.x;
    int f = t & (nfeat - 1);
    int rg = t / nfeat;
    int R = 256 / nfeat;
    int rows = (NN + gridDim.x - 1) / gridDim.x;
    int rbase = blockIdx.x * rows;
    int r1 = min(NN, rbase + rows);
    float s = 0.f, ss = 0.f;
    for (int r = rbase + rg; r < r1; r += R) {
        float v = bf2f(h[(size_t)r * nfeat + f]);
        s += v; ss += v * v;
    }
    sh[t] = s; sh[256 + t] = ss;
    __syncthreads();
    if (rg == 0) {
        for (int g = 1; g < R; g++) {
            s += sh[g * nfeat + f];
            ss += sh[256 + g * nfeat + f];
        }
        atomicAdd(&sums[f], s);
        atomicAdd(&sums[nfeat + f], ss);
    }
}

// BN apply + ELU from bf16 input, writing bf16 output (consumed by MFMA GEMMs)
__global__ void k_bn_apply_bf(const ushort* __restrict__ h, const float* __restrict__ sums,
                              const float* __restrict__ g, const float* __restrict__ b,
                              int nfeat, int total, ushort* __restrict__ hb) {
    int i = blockIdx.x * blockDim.x + threadIdx.x;
    if (i >= total) return;
    int f = i & (nfeat - 1);
    float m = sums[f] * (1.0f / NN);
    float var = sums[nfeat + f] * (1.0f / NN) - m * m;
    float v = (bf2f(h[i]) - m) * rsqrtf(var + 1e-5f) * g[f] + b[f];
    hb[i] = f2bf(v > 0.f ? v : expm1f(v));
}

// =================== SAGE dual GEMM via MFMA ===================
__global__ void k_sage_dualgemm(const ushort* __restrict__ h1b, const ushort* __restrict__ fragd,
                                ushort* __restrict__ u_bf, float* __restrict__ v) {
    __shared__ uint4 sfrag[2048];               // 32 KB
    int t = threadIdx.x;
    const uint4* f4 = (const uint4*)fragd;
    for (int i = t; i < 2048; i += 256) sfrag[i] = f4[i];
    __syncthreads();
    int w = t >> 6, lane = t & 63;
    int row0 = blockIdx.x * 64 + w * 16;
    int arow = row0 + (lane & 15);
    if (arow >= NN) arow = NN - 1;
    f32x4 acc[8];
#pragma unroll
    for (int c = 0; c < 8; c++) acc[c] = (f32x4){0.f, 0.f, 0.f, 0.f};
#pragma unroll
    for (int ks = 0; ks < 4; ks++) {
        union { uint4 u; bf16x8 f; } ua;
        ua.u = *(const uint4*)&h1b[(size_t)arow * F1 + ks * 32 + (lane >> 4) * 8];
#pragma unroll
        for (int ct = 0; ct < 8; ct++) {
            union { uint4 u; bf16x8 f; } ub;
            ub.u = sfrag[(ks * 8 + ct) * 64 + lane];
            acc[ct] = __builtin_amdgcn_mfma_f32_16x16x32_bf16(ua.f, ub.f, acc[ct], 0, 0, 0);
        }
    }
    int mrow0 = row0 + (lane >> 4) * 4;
    int n = lane & 15;
#pragma unroll
    for (int reg = 0; reg < 4; reg++) {
        int r = mrow0 + reg;
        if (r >= NN) continue;
#pragma unroll
        for (int ct = 0; ct < 4; ct++)
            u_bf[(size_t)r * F2 + ct * 16 + n] = f2bf(acc[ct][reg]);
#pragma unroll
        for (int ct = 4; ct < 8; ct++)
            v[(size_t)r * F2 + (ct - 4) * 16 + n] = acc[ct][reg];
    }
}

// h2 (bf16) = mean-gather(u_bf16) + v[n] + bl
__global__ void k_sage_gather2(const int* __restrict__ rowptr, const int* __restrict__ csr_src,
                               const ushort* __restrict__ u_bf, const float* __restrict__ v,
                               const float* __restrict__ bl, ushort* __restrict__ h2bf) {
    int n = blockIdx.x * 4 + (threadIdx.x >> 6);
    int lane = threadIdx.x & 63;
    if (n >= NN) return;
    int j0 = rowptr[n], j1 = rowptr[n + 1];
    float a = 0.f;
    for (int base = j0; base < j1; base += 64) {
        int cnt = min(64, j1 - base);
        int myj = base + lane;
        int sl = (myj < j1) ? csr_src[myj] : 0;
        int e = 0;
        for (; e + 4 <= cnt; e += 4) {
            int s0 = __shfl(sl, e + 0), s1 = __shfl(sl, e + 1),
                s2 = __shfl(sl, e + 2), s3 = __shfl(sl, e + 3);
            float t0 = bf2f(u_bf[(size_t)s0 * F2 + lane]);
            float t1 = bf2f(u_bf[(size_t)s1 * F2 + lane]);
            float t2 = bf2f(u_bf[(size_t)s2 * F2 + lane]);
            float t3 = bf2f(u_bf[(size_t)s3 * F2 + lane]);
            a += (t0 + t1) + (t2 + t3);
        }
        for (; e < cnt; e++) {
            int s = __shfl(sl, e);
            a += bf2f(u_bf[(size_t)s * F2 + lane]);
        }
    }
    float inv = 1.0f / fmaxf((float)(j1 - j0), 1.0f);
    h2bf[(size_t)n * F2 + lane] = f2bf(a * inv + v[(size_t)n * F2 + lane] + bl[lane]);
}

// =================== GCN GEMM via MFMA ===================
__global__ void k_gcn_gemm(const ushort* __restrict__ h2b, const ushort* __restrict__ fragg,
                           const float* __restrict__ dinv, ushort* __restrict__ hwd_bf) {
    __shared__ uint4 sfrag[512];                // 8 KB
    int t = threadIdx.x;
    const uint4* f4 = (const uint4*)fragg;
    for (int i = t; i < 512; i += 256) sfrag[i] = f4[i];
    __syncthreads();
    int w = t >> 6, lane = t & 63;
    int row0 = blockIdx.x * 64 + w * 16;
    int arow = row0 + (lane & 15);
    if (arow >= NN) arow = NN - 1;
    f32x4 acc[4];
#pragma unroll
    for (int c = 0; c < 4; c++) acc[c] = (f32x4){0.f, 0.f, 0.f, 0.f};
#pragma unroll
    for (int ks = 0; ks < 2; ks++) {
        union { uint4 u; bf16x8 f; } ua;
        ua.u = *(const uint4*)&h2b[(size_t)arow * F2 + ks * 32 + (lane >> 4) * 8];
#pragma unroll
        for (int ct = 0; ct < 4; ct++) {
            union { uint4 u; bf16x8 f; } ub;
            ub.u = sfrag[(ks * 4 + ct) * 64 + lane];
            acc[ct] = __builtin_amdgcn_mfma_f32_16x16x32_bf16(ua.f, ub.f, acc[ct], 0, 0, 0);
        }
    }
    int mrow0 = row0 + (lane >> 4) * 4;
    int n = lane & 15;
#pragma unroll
    for (int reg = 0; reg < 4; reg++) {
        int r = mrow0 + reg;
        if (r >= NN) continue;
        float d = dinv[r];
#pragma unroll
        for (int ct = 0; ct < 4; ct++)
            hwd_bf[(size_t)r * F2 + ct * 16 + n] = f2bf(acc[ct][reg] * d);
    }
}

// h3 (bf16) = dinv[n]*(sum_src hwd[s] + hwd[n]) + gb
__global__ void k_gcn_gather(const int* __restrict__ rowptr, const int* __restrict__ csr_src,
                             const ushort* __restrict__ hwd_bf, const float* __restrict__ dinv,
                             const float* __restrict__ gb, ushort* __restrict__ h3bf) {
    int n = blockIdx.x * 4 + (threadIdx.x >> 6);
    int lane = threadIdx.x & 63;
    if (n >= NN) return;
    int j0 = rowptr[n], j1 = rowptr[n + 1];
    float acc = 0.f;
    for (int base = j0; base < j1; base += 64) {
        int cnt = min(64, j1 - base);
        int myj = base + lane;
        int sl = (myj < j1) ? csr_src[myj] : 0;
        int e = 0;
        for (; e + 4 <= cnt; e += 4) {
            int s0 = __shfl(sl, e + 0), s1 = __shfl(sl, e + 1),
                s2 = __shfl(sl, e + 2), s3 = __shfl(sl, e + 3);
            float t0 = bf2f(hwd_bf[(size_t)s0 * F2 + lane]);
            float t1 = bf2f(hwd_bf[(size_t)s1 * F2 + lane]);
            float t2 = bf2f(hwd_bf[(size_t)s2 * F2 + lane]);
            float t3 = bf2f(hwd_bf[(size_t)s3 * F2 + lane]);
            acc += (t0 + t1) + (t2 + t3);
        }
        for (; e < cnt; e++) {
            int s = __shfl(sl, e);
            acc += bf2f(hwd_bf[(size_t)s * F2 + lane]);
        }
    }
    float di = dinv[n];
    acc += bf2f(hwd_bf[(size_t)n * F2 + lane]);
    h3bf[(size_t)n * F2 + lane] = f2bf(acc * di + gb[lane]);
}

// =================== fused BN3-apply + ELU + segmented pool (bf16 input) ===================
__global__ void k_bn3_pool(const ushort* __restrict__ h3bf, const float* __restrict__ sums,
                           const float* __restrict__ g3, const float* __restrict__ b3,
                           const int* __restrict__ batch, float* __restrict__ psum,
                           unsigned* __restrict__ pmax, float* __restrict__ cnt) {
    int w = threadIdx.x >> 6;
    int lane = threadIdx.x & 63;   // lane = feature
    int chunk = blockIdx.x * 4 + w;
    int nchunks = gridDim.x * 4;
    int rows = (NN + nchunks - 1) / nchunks;
    int r0 = chunk * rows;
    int r1 = min(NN, r0 + rows);
    if (r0 >= r1) return;
    float m = sums[lane] * (1.0f / NN);
    float var = sums[F2 + lane] * (1.0f / NN) - m * m;
    float sc = rsqrtf(var + 1e-5f) * g3[lane];
    float bb = b3[lane];
    int curg = batch[r0];
    float ls = 0.f, lm = -INFINITY;
    int run = 0;
    for (int r = r0; r < r1; r++) {
        int gg = batch[r];
        if (gg != curg) {
            atomicAdd(&psum[curg * F2 + lane], ls);
            atomicMax(&pmax[curg * F2 + lane], enc_f(lm));
            if (lane == 0) atomicAdd(&cnt[curg], (float)run);
            curg = gg; ls = 0.f; lm = -INFINITY; run = 0;
        }
        float v = (bf2f(h3bf[(size_t)r * F2 + lane]) - m) * sc + bb;
        v = v > 0.f ? v : expm1f(v);
        ls += v; lm = fmaxf(lm, v); run++;
    }
    atomicAdd(&psum[curg * F2 + lane], ls);
    atomicMax(&pmax[curg * F2 + lane], enc_f(lm));
    if (lane == 0) atomicAdd(&cnt[curg], (float)run);
}

// =================== classifier ===================
__global__ void k_cls(const float* __restrict__ psum, const unsigned* __restrict__ pmax,
                      const float* __restrict__ cnt, const float* __restrict__ w1,
                      const float* __restrict__ b1, const float* __restrict__ w2,
                      const float* __restrict__ b2, float* __restrict__ out) {
    int g = blockIdx.x;
    int j = threadIdx.x;  // 64 threads
    __shared__ float z[2 * F2];
    __shared__ float hid[F2];
    float c = fmaxf(cnt[g], 1.0f);
    z[j] = psum[g * F2 + j] / c;
    float mv = dec_f(pmax[g * F2 + j]);
    z[F2 + j] = isfinite(mv) ? mv : 0.f;
    __syncthreads();
    float acc = b1[j];
#pragma unroll 8
    for (int k = 0; k < 2 * F2; k++) acc += z[k] * w1[k * F2 + j];
    hid[j] = fmaxf(acc, 0.f);
    __syncthreads();
    if (j < NCLS) {
        float o = b2[j];
#pragma unroll 8
        for (int k = 0; k < F2; k++) o += hid[k] * w2[k * NCLS + j];
        out[g * NCLS + j] = o;
    }
}

extern "C" void kernel_launch(void* const* d_in, const int* in_sizes, int n_in,
                              void* d_out, int out_size, void* d_ws, size_t ws_size,
                              hipStream_t stream) {
    const float* x       = (const float*)d_in[0];
    const int*   ei      = (const int*)d_in[1];
    const int*   batch   = (const int*)d_in[2];
    const float* gat_w   = (const float*)d_in[3];
    const float* att_src = (const float*)d_in[4];
    const float* att_dst = (const float*)d_in[5];
    // d_in[6] gat_b: cancels inside BN1
    const float* bn1_g   = (const float*)d_in[7];
    const float* bn1_b   = (const float*)d_in[8];
    const float* sage_wl = (const float*)d_in[9];
    const float* sage_bl = (const float*)d_in[10];
    const float* sage_wr = (const float*)d_in[11];
    const float* bn2_g   = (const float*)d_in[12];
    const float* bn2_b   = (const float*)d_in[13];
    const float* gcn_w   = (const float*)d_in[14];
    const float* gcn_b   = (const float*)d_in[15];
    const float* bn3_g   = (const float*)d_in[16];
    const float* bn3_b   = (const float*)d_in[17];
    const float* w1      = (const float*)d_in[18];
    const float* b1      = (const float*)d_in[19];
    const float* w2      = (const float*)d_in[20];
    const float* b2      = (const float*)d_in[21];
    float* out = (float*)d_out;

    float* ws = (float*)d_ws;
    // workspace layout (4-byte units; 16B alignment maintained)
    size_t o_A    = 0;                        // NN*F1 floats region, aliased (see below)
    size_t o_h1   = o_A   + (size_t)NN * F1;  // h1 bf16 (pre-BN1); later h2b (post-BN2 bf16)
    size_t o_h2   = o_h1  + (size_t)NN * F1;  // h1b (post-BN1 bf16); later h2 bf16 (pre-BN2)
    size_t o_csr  = o_h2  + (size_t)NN * F2;  // E ints (csr_src)
    size_t o_rp   = o_csr + (size_t)NE;       // N+4 ints (rowptr)
    size_t o_bb   = o_rp  + (size_t)(NN + 4); // NBUCK+1 ints (bucket bases), padded
    size_t o_bt   = o_bb  + 400;              // NBUCK ints (bucket totals), padded
    size_t o_asrc = o_bt  + 400;              // N*2
    size_t o_adst = o_asrc + (size_t)NN * 2;  // N*2
    size_t o_dinv = o_adst + (size_t)NN * 2;  // N
    size_t o_sums = o_dinv + (size_t)NN;      // 768 (3 x 256: bn1, bn2, bn3)
    size_t o_frd  = o_sums + 768;             // 8192 floats = 32KB dual B-frags
    size_t o_frg  = o_frd  + 8192;            // 2048 floats = 8KB gcn B-frags
    size_t o_psum = o_frg  + 2048;            // G*F2
    size_t o_cnt  = o_psum + (size_t)NG * F2; // G (adjacent to psum: one memset)
    size_t o_pmax = o_cnt  + (size_t)NG;      // G*F2

    float* A    = ws + o_A;
    float* h1r  = ws + o_h1;
    float* h2r  = ws + o_h2;
    int* csr_src = (int*)(ws + o_csr);
    int* rowptr  = (int*)(ws + o_rp);
    int* bbase   = (int*)(ws + o_bb);
    int* btot    = (int*)(ws + o_bt);
    float* asr  = ws + o_asrc;
    float* ads  = ws + o_adst;
    float* dinv = ws + o_dinv;
    float* sums1 = ws + o_sums;
    float* sums2 = sums1 + 256;
    float* sums3 = sums2 + 256;
    ushort* fragd = (ushort*)(ws + o_frd);
    ushort* fragg = (ushort*)(ws + o_frg);
    float* psum = ws + o_psum;
    float* cnt  = ws + o_cnt;
    unsigned* pmax = (unsigned*)(ws + o_pmax);

    // region aliases (lifetimes disjoint):
    unsigned* staged = (unsigned*)A;                    // CSR build: NE entries (6.4 MB)
    int*    ghist  = (int*)(A + 2 * 1024 * 1024);       // CSR build: NCHUNK*NBUCK ints
    unsigned* xw32 = (unsigned*)A;                      // GAT: NN*64 packed bf16 pairs
    ushort* u_bf   = (ushort*)A;                        // SAGE: NN*F2 bf16 (xw dead)
    float*  vmat   = A + (size_t)NN * F2 / 2;           // SAGE: NN*F2 f32
    ushort* hwd_bf = (ushort*)A;                        // GCN: NN*F2 bf16 (u dead)
    ushort* h3bf   = (ushort*)(A + (size_t)NN * F2 / 2);// GCN out: NN*F2 bf16 (v dead)
    unsigned* h1p  = (unsigned*)h1r;                    // pre-BN1 bf16 pairs (NN*64 u32)
    ushort* h1bf   = (ushort*)h1r;                      // same bytes viewed as bf16[NN][128]
    ushort* h1b    = (ushort*)h2r;                      // post-BN1 bf16 (NN*F1)
    ushort* h2bf   = (ushort*)h2r;                      // pre-BN2 bf16 (overwrites h1b after dead)
    ushort* h2b    = (ushort*)h1r;                      // post-BN2 bf16 (h1 region dead)

    // ---- upfront init (independent of everything) ----
    hipMemsetAsync(sums1, 0, sizeof(float) * 768, stream);
    hipMemsetAsync(psum, 0, sizeof(float) * (NG * F2 + NG), stream);   // psum + cnt
    k_fill_u32<<<(NG * F2 + 255) / 256, 256, 0, stream>>>(pmax, ENC_NEG_INF, NG * F2);

    // ---- CSR build: chunk-major radix ----
    k_hist<<<NCHUNK, 256, 0, stream>>>(ei, ghist);
    k_bscan<<<NBUCK, 256, 0, stream>>>(ghist, btot);
    k_bprefix<<<1, 512, 0, stream>>>(btot, bbase, rowptr);
    k_scatter2<<<NCHUNK, 256, 0, stream>>>(ei, ghist, bbase, staged);
    k_bucket_sort<<<NBUCK, 256, 0, stream>>>(staged, bbase, rowptr, csr_src, dinv);

    // ---- GAT (softmax fused into gather) ----
    k_xw<<<(NN + 63) / 64, 256, 0, stream>>>(x, gat_w, att_src, att_dst, xw32, asr, ads);
    k_gat_gather<<<(NN + 3) / 4, 256, 0, stream>>>(rowptr, csr_src, asr, ads, xw32, h1p);
    k_bn_stats_bf<<<1024, 256, 0, stream>>>(h1bf, F1, sums1);
    k_bn_apply_bf<<<(NN * F1 + 255) / 256, 256, 0, stream>>>(h1bf, sums1, bn1_g, bn1_b,
                                                             F1, NN * F1, h1b);

    // ---- SAGE: MFMA dual-GEMM then bf16 mean-gather ----
    k_packfrag_dual<<<(16384 + 255) / 256, 256, 0, stream>>>(sage_wl, sage_wr, fragd);
    k_sage_dualgemm<<<(NN + 63) / 64, 256, 0, stream>>>(h1b, fragd, u_bf, vmat);
    k_sage_gather2<<<(NN + 3) / 4, 256, 0, stream>>>(rowptr, csr_src, u_bf, vmat, sage_bl, h2bf);
    k_bn_stats_bf<<<1024, 256, 0, stream>>>(h2bf, F2, sums2);
    k_bn_apply_bf<<<(NN * F2 + 255) / 256, 256, 0, stream>>>(h2bf, sums2, bn2_g, bn2_b,
                                                             F2, NN * F2, h2b);

    // ---- GCN: MFMA GEMM (dinv folded) then gather ----
    k_packfrag_gcn<<<(4096 + 255) / 256, 256, 0, stream>>>(gcn_w, fragg);
    k_gcn_gemm<<<(NN + 63) / 64, 256, 0, stream>>>(h2b, fragg, dinv, hwd_bf);
    k_gcn_gather<<<(NN + 3) / 4, 256, 0, stream>>>(rowptr, csr_src, hwd_bf, dinv, gcn_b, h3bf);
    k_bn_stats_bf<<<1024, 256, 0, stream>>>(h3bf, F2, sums3);

    // ---- fused BN3 + ELU + pooling, then classifier ----
    k_bn3_pool<<<1024, 256, 0, stream>>>(h3bf, sums3, bn3_g, bn3_b, batch, psum, pmax, cnt);
    k_cls<<<NG, F2, 0, stream>>>(psum, pmax, cnt, w1, b1, w2, b2, out);
}

// Round 19
// 445.193 us; speedup vs baseline: 3.0527x; 1.0667x over previous
//
#include <hip/hip_runtime.h>
#include <hip/hip_bf16.h>
#include <math.h>

#define NN 100000      // nodes
#define NE 1600000     // edges
#define NG 64          // graphs
#define F_IN 5
#define F1 128         // H*HID
#define F2 64          // HID
#define NCLS 4
#define NCHUNK 250                   // edge chunks (250 * 6400 = NE)
#define CH_E 6400                    // edges per chunk
#define NBUCK ((NN + 255) / 256)     // 391 dst buckets of 256 nodes
#define CAPB 6144                    // bucket capacity in LDS sort

typedef unsigned short ushort;
typedef __bf16 bf16x8 __attribute__((ext_vector_type(8)));
typedef float f32x4 __attribute__((ext_vector_type(4)));

// ---------- bf16 helpers (round-to-nearest-even pack) ----------
__device__ __forceinline__ ushort f2bf(float f) {
    unsigned u = __float_as_uint(f);
    u = (u + 0x7fffu + ((u >> 16) & 1u)) >> 16;
    return (ushort)u;
}
__device__ __forceinline__ float bf2f(ushort h) {
    return __uint_as_float(((unsigned)h) << 16);
}
__device__ __forceinline__ unsigned pack2bf(float a, float b) {
    return (unsigned)f2bf(a) | ((unsigned)f2bf(b) << 16);
}
__device__ __forceinline__ float lo_bf(unsigned p) { return __uint_as_float(p << 16); }
__device__ __forceinline__ float hi_bf(unsigned p) { return __uint_as_float(p & 0xffff0000u); }
__device__ __forceinline__ float eluf(float z) { return z > 0.f ? z : expm1f(z); }

// ---------- order-preserving float<->uint encoding for atomicMax ----------
__device__ __forceinline__ unsigned enc_f(float f) {
    unsigned b = __float_as_uint(f);
    return (b & 0x80000000u) ? ~b : (b | 0x80000000u);
}
__device__ __forceinline__ float dec_f(unsigned k) {
    unsigned b = (k & 0x80000000u) ? (k ^ 0x80000000u) : ~k;
    return __uint_as_float(b);
}
#define ENC_NEG_INF 0x007FFFFFu   // enc_f(-inf)

// one-shot init: sums (768), psum+cnt (NG*F2+NG), pmax (NG*F2)
__global__ void k_init(float* __restrict__ sums, float* __restrict__ psum_cnt,
                       unsigned* __restrict__ pmax) {
    int i = blockIdx.x * 256 + threadIdx.x;
    if (i < 768) sums[i] = 0.f;
    if (i < NG * F2 + NG) psum_cnt[i] = 0.f;
    if (i < NG * F2) pmax[i] = ENC_NEG_INF;
}

// =================== MFMA B-fragment packing (dual + gcn merged) ===================
__global__ void k_packfrag(const float* __restrict__ wl, const float* __restrict__ wr,
                           const float* __restrict__ wg,
                           ushort* __restrict__ fragd, ushort* __restrict__ fragg) {
    int idx = blockIdx.x * 256 + threadIdx.x;
    if (idx < 16384) {                       // dual: [ks(4)][ct(8)][lane(64)][e(8)]
        int e = idx & 7;
        int lane = (idx >> 3) & 63;
        int ct = (idx >> 9) & 7;
        int ks = idx >> 12;
        int k = ks * 32 + (lane >> 4) * 8 + e;
        int n = ct * 16 + (lane & 15);
        float val = (n < 64) ? wl[k * 64 + n] : wr[k * 64 + (n - 64)];
        fragd[idx] = f2bf(val);
    } else if (idx < 16384 + 4096) {         // gcn: [ks(2)][ct(4)][lane(64)][e(8)]
        int j = idx - 16384;
        int e = j & 7;
        int lane = (j >> 3) & 63;
        int ct = (j >> 9) & 3;
        int ks = j >> 11;
        int k = ks * 32 + (lane >> 4) * 8 + e;
        int n = ct * 16 + (lane & 15);
        fragg[j] = f2bf(wg[k * 64 + n]);
    }
}

// =================== CSR build (radix: hist -> bscan -> bprefix -> scatter -> sort) ===========
__global__ void k_hist(const int* __restrict__ ei, int* __restrict__ ghist) {
    __shared__ int lh[NBUCK];
    int c = blockIdx.x, t = threadIdx.x;
    for (int b = t; b < NBUCK; b += 256) lh[b] = 0;
    __syncthreads();
    int e0 = c * CH_E;
#pragma unroll
    for (int i = 0; i < CH_E / 256; i++) {
        int d = ei[NE + e0 + t + i * 256];
        atomicAdd(&lh[d >> 8], 1);
    }
    __syncthreads();
    for (int b = t; b < NBUCK; b += 256) ghist[c * NBUCK + b] = lh[b];
}

__global__ void k_bscan(int* __restrict__ ghist, int* __restrict__ btot) {
    __shared__ int sh[256];
    int b = blockIdx.x, t = threadIdx.x;
    int v = (t < NCHUNK) ? ghist[t * NBUCK + b] : 0;
    sh[t] = v;
    __syncthreads();
    for (int off = 1; off < 256; off <<= 1) {
        int u = (t >= off) ? sh[t - off] : 0;
        __syncthreads();
        sh[t] += u;
        __syncthreads();
    }
    if (t < NCHUNK) ghist[t * NBUCK + b] = sh[t] - v;   // exclusive, bucket-local
    if (t == 255) btot[b] = sh[255];
}

__global__ void k_bprefix(const int* __restrict__ btot, int* __restrict__ bbase,
                          int* __restrict__ rowptr) {
    __shared__ int sh[512];
    int t = threadIdx.x;
    int v = (t < NBUCK) ? btot[t] : 0;
    sh[t] = v;
    __syncthreads();
    for (int off = 1; off < 512; off <<= 1) {
        int u = (t >= off) ? sh[t - off] : 0;
        __syncthreads();
        sh[t] += u;
        __syncthreads();
    }
    if (t < NBUCK) bbase[t] = sh[t] - v;
    if (t == 0) { bbase[NBUCK] = NE; rowptr[NN] = NE; }
}

__global__ void k_scatter2(const int* __restrict__ ei, const int* __restrict__ ghist,
                           const int* __restrict__ bbase, unsigned* __restrict__ staged) {
    __shared__ int lcur[NBUCK];
    int c = blockIdx.x, t = threadIdx.x;
    for (int b = t; b < NBUCK; b += 256) lcur[b] = ghist[c * NBUCK + b] + bbase[b];
    __syncthreads();
    int e0 = c * CH_E;
#pragma unroll
    for (int i = 0; i < CH_E / 256; i++) {
        int e = e0 + t + i * 256;
        int s = ei[e];
        int d = ei[NE + e];
        int pos = atomicAdd(&lcur[d >> 8], 1);
        staged[pos] = (((unsigned)(d & 255)) << 17) | (unsigned)s;
    }
}

__global__ void k_bucket_sort(const unsigned* __restrict__ staged, const int* __restrict__ bbase,
                              int* __restrict__ rowptr, int* __restrict__ csr_src,
                              float* __restrict__ dinv) {
    __shared__ unsigned ein[CAPB];
    __shared__ unsigned sout[CAPB];
    __shared__ int lhist[256];
    __shared__ int lps[256];
    int b = blockIdx.x, t = threadIdx.x;
    int n0 = b * 256;
    int g0 = bbase[b];
    int m = bbase[b + 1] - g0;
    lhist[t] = 0;
    __syncthreads();
    if (m <= CAPB) {
        for (int i = t; i < m; i += 256) {
            unsigned u = staged[g0 + i];
            ein[i] = u;
            atomicAdd(&lhist[u >> 17], 1);
        }
        __syncthreads();
        if (n0 + t < NN) dinv[n0 + t] = rsqrtf((float)lhist[t] + 1.0f);
        lps[t] = lhist[t];
        __syncthreads();
        for (int off = 1; off < 256; off <<= 1) {
            int v = (t >= off) ? lps[t - off] : 0;
            __syncthreads();
            lps[t] += v;
            __syncthreads();
        }
        int excl = lps[t] - lhist[t];
        if (n0 + t < NN) rowptr[n0 + t] = g0 + excl;
        __syncthreads();
        lhist[t] = excl;   // reuse as cursor
        __syncthreads();
        for (int i = t; i < m; i += 256) {
            unsigned u = ein[i];
            int pos = atomicAdd(&lhist[u >> 17], 1);
            sout[pos] = u & 0x1FFFFu;
        }
        __syncthreads();
        for (int i = t; i < m; i += 256) csr_src[g0 + i] = (int)sout[i];
    } else {
        for (int i = t; i < m; i += 256) {
            unsigned u = staged[g0 + i];
            atomicAdd(&lhist[u >> 17], 1);
        }
        __syncthreads();
        if (n0 + t < NN) dinv[n0 + t] = rsqrtf((float)lhist[t] + 1.0f);
        lps[t] = lhist[t];
        __syncthreads();
        for (int off = 1; off < 256; off <<= 1) {
            int v = (t >= off) ? lps[t - off] : 0;
            __syncthreads();
            lps[t] += v;
            __syncthreads();
        }
        int excl = lps[t] - lhist[t];
        if (n0 + t < NN) rowptr[n0 + t] = g0 + excl;
        __syncthreads();
        lhist[t] = excl;
        __syncthreads();
        for (int i = t; i < m; i += 256) {
            unsigned u = staged[g0 + i];
            int pos = atomicAdd(&lhist[u >> 17], 1);
            csr_src[g0 + pos] = (int)(u & 0x1FFFFu);
        }
    }
}

// =================== GAT ===================
__global__ void k_xw(const float* __restrict__ x, const float* __restrict__ gw,
                     const float* __restrict__ aw_src, const float* __restrict__ aw_dst,
                     unsigned* __restrict__ xw32, float* __restrict__ a_src,
                     float* __restrict__ a_dst) {
    __shared__ float w[F_IN * F1];
    int t = threadIdx.x;
    for (int i = t; i < F_IN * F1; i += 256) w[i] = gw[i];
    int wv = t >> 6, lane = t & 63;
    int f0 = 2 * lane, f1 = 2 * lane + 1;
    float as0 = aw_src[f0], as1 = aw_src[f1];
    float ad0 = aw_dst[f0], ad1 = aw_dst[f1];
    __syncthreads();
    int nbase = blockIdx.x * 64;
    for (int it = 0; it < 16; it++) {
        int n = nbase + it * 4 + wv;
        if (n >= NN) break;
        float xs[F_IN];
#pragma unroll
        for (int j = 0; j < F_IN; j++) xs[j] = x[n * F_IN + j];
        float acc0 = 0.f, acc1 = 0.f;
#pragma unroll
        for (int j = 0; j < F_IN; j++) {
            acc0 += xs[j] * w[j * F1 + f0];
            acc1 += xs[j] * w[j * F1 + f1];
        }
        xw32[(size_t)n * 64 + lane] = pack2bf(acc0, acc1);
        float p = acc0 * as0 + acc1 * as1;
        float q = acc0 * ad0 + acc1 * ad1;
#pragma unroll
        for (int off = 1; off < 32; off <<= 1) {
            p += __shfl_xor(p, off);
            q += __shfl_xor(q, off);
        }
        if (lane == 0)  { a_src[n * 2 + 0] = p; a_dst[n * 2 + 0] = q; }
        if (lane == 32) { a_src[n * 2 + 1] = p; a_dst[n * 2 + 1] = q; }
    }
}

// FUSED softmax + gather: one wave per dst node; h1 written as packed bf16 pairs.
__global__ void k_gat_gather(const int* __restrict__ rowptr, const int* __restrict__ csr_src,
                             const float* __restrict__ a_src, const float* __restrict__ a_dst,
                             const unsigned* __restrict__ xw32, unsigned* __restrict__ h1p) {
    int n = blockIdx.x * 4 + (threadIdx.x >> 6);
    int lane = threadIdx.x & 63;
    if (n >= NN) return;
    int j0 = rowptr[n], j1 = rowptr[n + 1];
    int deg = j1 - j0;
    float ad0 = a_dst[n * 2 + 0], ad1 = a_dst[n * 2 + 1];
    float acc0 = 0.f, acc1 = 0.f;
    bool lo = (lane < 32);
    if (deg <= 64) {
        int sl = 0;
        float l0 = -INFINITY, l1 = -INFINITY;
        if (lane < deg) {
            sl = csr_src[j0 + lane];
            l0 = a_src[sl * 2 + 0] + ad0;
            l1 = a_src[sl * 2 + 1] + ad1;
            l0 = l0 > 0.f ? l0 : 0.2f * l0;
            l1 = l1 > 0.f ? l1 : 0.2f * l1;
        }
        float m0 = l0, m1 = l1;
#pragma unroll
        for (int off = 32; off > 0; off >>= 1) {
            m0 = fmaxf(m0, __shfl_xor(m0, off));
            m1 = fmaxf(m1, __shfl_xor(m1, off));
        }
        float e0 = 0.f, e1 = 0.f;
        if (lane < deg) { e0 = expf(l0 - m0); e1 = expf(l1 - m1); }
        float s0 = e0, s1 = e1;
#pragma unroll
        for (int off = 32; off > 0; off >>= 1) {
            s0 += __shfl_xor(s0, off);
            s1 += __shfl_xor(s1, off);
        }
        unsigned al = pack2bf(e0 / (s0 + 1e-16f), e1 / (s1 + 1e-16f));
        int e = 0;
        for (; e + 4 <= deg; e += 4) {
            int s0i = __shfl(sl, e + 0), s1i = __shfl(sl, e + 1),
                s2i = __shfl(sl, e + 2), s3i = __shfl(sl, e + 3);
            unsigned b0 = __shfl(al, e + 0), b1 = __shfl(al, e + 1),
                     b2 = __shfl(al, e + 2), b3 = __shfl(al, e + 3);
            unsigned p0 = xw32[(size_t)s0i * 64 + lane];
            unsigned p1 = xw32[(size_t)s1i * 64 + lane];
            unsigned p2 = xw32[(size_t)s2i * 64 + lane];
            unsigned p3 = xw32[(size_t)s3i * 64 + lane];
            float w0 = lo ? lo_bf(b0) : hi_bf(b0);
            float w1 = lo ? lo_bf(b1) : hi_bf(b1);
            float w2 = lo ? lo_bf(b2) : hi_bf(b2);
            float w3 = lo ? lo_bf(b3) : hi_bf(b3);
            acc0 = fmaf(lo_bf(p0), w0, acc0); acc1 = fmaf(hi_bf(p0), w0, acc1);
            acc0 = fmaf(lo_bf(p1), w1, acc0); acc1 = fmaf(hi_bf(p1), w1, acc1);
            acc0 = fmaf(lo_bf(p2), w2, acc0); acc1 = fmaf(hi_bf(p2), w2, acc1);
            acc0 = fmaf(lo_bf(p3), w3, acc0); acc1 = fmaf(hi_bf(p3), w3, acc1);
        }
        for (; e < deg; e++) {
            int s = __shfl(sl, e); unsigned b = __shfl(al, e);
            unsigned p = xw32[(size_t)s * 64 + lane];
            float w = lo ? lo_bf(b) : hi_bf(b);
            acc0 = fmaf(lo_bf(p), w, acc0);
            acc1 = fmaf(hi_bf(p), w, acc1);
        }
    } else {
        float m0 = -INFINITY, m1 = -INFINITY, s0 = 0.f, s1 = 0.f;
        for (int base = j0; base < j1; base += 64) {
            int myj = base + lane;
            float l0 = -INFINITY, l1 = -INFINITY;
            if (myj < j1) {
                int s = csr_src[myj];
                l0 = a_src[s * 2 + 0] + ad0;
                l1 = a_src[s * 2 + 1] + ad1;
                l0 = l0 > 0.f ? l0 : 0.2f * l0;
                l1 = l1 > 0.f ? l1 : 0.2f * l1;
            }
            float cm0 = l0, cm1 = l1;
#pragma unroll
            for (int off = 32; off > 0; off >>= 1) {
                cm0 = fmaxf(cm0, __shfl_xor(cm0, off));
                cm1 = fmaxf(cm1, __shfl_xor(cm1, off));
            }
            float nm0 = fmaxf(m0, cm0), nm1 = fmaxf(m1, cm1);
            float ce0 = (myj < j1) ? expf(l0 - nm0) : 0.f;
            float ce1 = (myj < j1) ? expf(l1 - nm1) : 0.f;
            float cs0 = ce0, cs1 = ce1;
#pragma unroll
            for (int off = 32; off > 0; off >>= 1) {
                cs0 += __shfl_xor(cs0, off);
                cs1 += __shfl_xor(cs1, off);
            }
            s0 = s0 * expf(m0 - nm0) + cs0;
            s1 = s1 * expf(m1 - nm1) + cs1;
            m0 = nm0; m1 = nm1;
        }
        float r0 = 1.0f / (s0 + 1e-16f), r1 = 1.0f / (s1 + 1e-16f);
        for (int base = j0; base < j1; base += 64) {
            int cnt = min(64, j1 - base);
            int myj = base + lane;
            int sl = 0; unsigned al = 0;
            if (myj < j1) {
                sl = csr_src[myj];
                float l0 = a_src[sl * 2 + 0] + ad0;
                float l1 = a_src[sl * 2 + 1] + ad1;
                l0 = l0 > 0.f ? l0 : 0.2f * l0;
                l1 = l1 > 0.f ? l1 : 0.2f * l1;
                al = pack2bf(expf(l0 - m0) * r0, expf(l1 - m1) * r1);
            }
            int e = 0;
            for (; e + 4 <= cnt; e += 4) {
                int s0i = __shfl(sl, e + 0), s1i = __shfl(sl, e + 1),
                    s2i = __shfl(sl, e + 2), s3i = __shfl(sl, e + 3);
                unsigned b0 = __shfl(al, e + 0), b1 = __shfl(al, e + 1),
                         b2 = __shfl(al, e + 2), b3 = __shfl(al, e + 3);
                unsigned p0 = xw32[(size_t)s0i * 64 + lane];
                unsigned p1 = xw32[(size_t)s1i * 64 + lane];
                unsigned p2 = xw32[(size_t)s2i * 64 + lane];
                unsigned p3 = xw32[(size_t)s3i * 64 + lane];
                float w0 = lo ? lo_bf(b0) : hi_bf(b0);
                float w1 = lo ? lo_bf(b1) : hi_bf(b1);
                float w2 = lo ? lo_bf(b2) : hi_bf(b2);
                float w3 = lo ? lo_bf(b3) : hi_bf(b3);
                acc0 = fmaf(lo_bf(p0), w0, acc0); acc1 = fmaf(hi_bf(p0), w0, acc1);
                acc0 = fmaf(lo_bf(p1), w1, acc0); acc1 = fmaf(hi_bf(p1), w1, acc1);
                acc0 = fmaf(lo_bf(p2), w2, acc0); acc1 = fmaf(hi_bf(p2), w2, acc1);
                acc0 = fmaf(lo_bf(p3), w3, acc0); acc1 = fmaf(hi_bf(p3), w3, acc1);
            }
            for (; e < cnt; e++) {
                int s = __shfl(sl, e); unsigned b = __shfl(al, e);
                unsigned p = xw32[(size_t)s * 64 + lane];
                float w = lo ? lo_bf(b) : hi_bf(b);
                acc0 = fmaf(lo_bf(p), w, acc0);
                acc1 = fmaf(hi_bf(p), w, acc1);
            }
        }
    }
    h1p[(size_t)n * 64 + lane] = pack2bf(acc0, acc1);
}

// =================== BatchNorm stats (bf16 inputs) ===================
__global__ void k_bn_stats_bf(const ushort* __restrict__ h, int nfeat, float* __restrict__ sums) {
    __shared__ float sh[512];
    int t = threadIdx.x;
    int f = t & (nfeat - 1);
    int rg = t / nfeat;
    int R = 256 / nfeat;
    int rows = (NN + gridDim.x - 1) / gridDim.x;
    int rbase = blockIdx.x * rows;
    int r1 = min(NN, rbase + rows);
    float s = 0.f, ss = 0.f;
    for (int r = rbase + rg; r < r1; r += R) {
        float v = bf2f(h[(size_t)r * nfeat + f]);
        s += v; ss += v * v;
    }
    sh[t] = s; sh[256 + t] = ss;
    __syncthreads();
    if (rg == 0) {
        for (int g = 1; g < R; g++) {
            s += sh[g * nfeat + f];
            ss += sh[256 + g * nfeat + f];
        }
        atomicAdd(&sums[f], s);
        atomicAdd(&sums[nfeat + f], ss);
    }
}

// =================== SAGE dual GEMM via MFMA, BN1+ELU fused on A-load ===================
// Each h1 element is loaded exactly ONCE per wave (lane-distinct rows) -> no redundant ELU.
__global__ void k_sage_dualgemm(const ushort* __restrict__ h1bf, const float* __restrict__ sums,
                                const float* __restrict__ g, const float* __restrict__ b,
                                const ushort* __restrict__ fragd,
                                ushort* __restrict__ u_bf, ushort* __restrict__ v_bf) {
    __shared__ uint4 sfrag[2048];               // 32 KB
    __shared__ float sco[F1], ssh[F1];
    int t = threadIdx.x;
    const uint4* f4 = (const uint4*)fragd;
    for (int i = t; i < 2048; i += 256) sfrag[i] = f4[i];
    if (t < F1) {
        float m = sums[t] * (1.0f / NN);
        float var = sums[F1 + t] * (1.0f / NN) - m * m;
        float sc = rsqrtf(var + 1e-5f) * g[t];
        sco[t] = sc;
        ssh[t] = b[t] - m * sc;
    }
    __syncthreads();
    int w = t >> 6, lane = t & 63;
    int row0 = blockIdx.x * 64 + w * 16;
    int arow = row0 + (lane & 15);
    if (arow >= NN) arow = NN - 1;
    f32x4 acc[8];
#pragma unroll
    for (int c = 0; c < 8; c++) acc[c] = (f32x4){0.f, 0.f, 0.f, 0.f};
#pragma unroll
    for (int ks = 0; ks < 4; ks++) {
        int kb = ks * 32 + (lane >> 4) * 8;
        uint4 raw = *(const uint4*)&h1bf[(size_t)arow * F1 + kb];
        union { uint4 u; bf16x8 f; } ua;
        {
            float e0 = eluf(fmaf(lo_bf(raw.x), sco[kb + 0], ssh[kb + 0]));
            float e1 = eluf(fmaf(hi_bf(raw.x), sco[kb + 1], ssh[kb + 1]));
            float e2 = eluf(fmaf(lo_bf(raw.y), sco[kb + 2], ssh[kb + 2]));
            float e3 = eluf(fmaf(hi_bf(raw.y), sco[kb + 3], ssh[kb + 3]));
            float e4 = eluf(fmaf(lo_bf(raw.z), sco[kb + 4], ssh[kb + 4]));
            float e5 = eluf(fmaf(hi_bf(raw.z), sco[kb + 5], ssh[kb + 5]));
            float e6 = eluf(fmaf(lo_bf(raw.w), sco[kb + 6], ssh[kb + 6]));
            float e7 = eluf(fmaf(hi_bf(raw.w), sco[kb + 7], ssh[kb + 7]));
            ua.u.x = pack2bf(e0, e1); ua.u.y = pack2bf(e2, e3);
            ua.u.z = pack2bf(e4, e5); ua.u.w = pack2bf(e6, e7);
        }
#pragma unroll
        for (int ct = 0; ct < 8; ct++) {
            union { uint4 u; bf16x8 f; } ub;
            ub.u = sfrag[(ks * 8 + ct) * 64 + lane];
            acc[ct] = __builtin_amdgcn_mfma_f32_16x16x32_bf16(ua.f, ub.f, acc[ct], 0, 0, 0);
        }
    }
    int mrow0 = row0 + (lane >> 4) * 4;
    int n = lane & 15;
#pragma unroll
    for (int reg = 0; reg < 4; reg++) {
        int r = mrow0 + reg;
        if (r >= NN) continue;
#pragma unroll
        for (int ct = 0; ct < 4; ct++)
            u_bf[(size_t)r * F2 + ct * 16 + n] = f2bf(acc[ct][reg]);
#pragma unroll
        for (int ct = 4; ct < 8; ct++)
            v_bf[(size_t)r * F2 + (ct - 4) * 16 + n] = f2bf(acc[ct][reg]);
    }
}

// h2 (bf16) = mean-gather(u_bf16) + v_bf16[n] + bl
__global__ void k_sage_gather2(const int* __restrict__ rowptr, const int* __restrict__ csr_src,
                               const ushort* __restrict__ u_bf, const ushort* __restrict__ v_bf,
                               const float* __restrict__ bl, ushort* __restrict__ h2bf) {
    int n = blockIdx.x * 4 + (threadIdx.x >> 6);
    int lane = threadIdx.x & 63;
    if (n >= NN) return;
    int j0 = rowptr[n], j1 = rowptr[n + 1];
    float a = 0.f;
    for (int base = j0; base < j1; base += 64) {
        int cnt = min(64, j1 - base);
        int myj = base + lane;
        int sl = (myj < j1) ? csr_src[myj] : 0;
        int e = 0;
        for (; e + 4 <= cnt; e += 4) {
            int s0 = __shfl(sl, e + 0), s1 = __shfl(sl, e + 1),
                s2 = __shfl(sl, e + 2), s3 = __shfl(sl, e + 3);
            float t0 = bf2f(u_bf[(size_t)s0 * F2 + lane]);
            float t1 = bf2f(u_bf[(size_t)s1 * F2 + lane]);
            float t2 = bf2f(u_bf[(size_t)s2 * F2 + lane]);
            float t3 = bf2f(u_bf[(size_t)s3 * F2 + lane]);
            a += (t0 + t1) + (t2 + t3);
        }
        for (; e < cnt; e++) {
            int s = __shfl(sl, e);
            a += bf2f(u_bf[(size_t)s * F2 + lane]);
        }
    }
    float inv = 1.0f / fmaxf((float)(j1 - j0), 1.0f);
    h2bf[(size_t)n * F2 + lane] = f2bf(a * inv + bf2f(v_bf[(size_t)n * F2 + lane]) + bl[lane]);
}

// =================== GCN GEMM via MFMA, BN2+ELU fused on A-load ===================
__global__ void k_gcn_gemm(const ushort* __restrict__ h2bf, const float* __restrict__ sums,
                           const float* __restrict__ g, const float* __restrict__ b,
                           const ushort* __restrict__ fragg,
                           const float* __restrict__ dinv, ushort* __restrict__ hwd_bf) {
    __shared__ uint4 sfrag[512];                // 8 KB
    __shared__ float sco[F2], ssh[F2];
    int t = threadIdx.x;
    const uint4* f4 = (const uint4*)fragg;
    for (int i = t; i < 512; i += 256) sfrag[i] = f4[i];
    if (t < F2) {
        float m = sums[t] * (1.0f / NN);
        float var = sums[F2 + t] * (1.0f / NN) - m * m;
        float sc = rsqrtf(var + 1e-5f) * g[t];
        sco[t] = sc;
        ssh[t] = b[t] - m * sc;
    }
    __syncthreads();
    int w = t >> 6, lane = t & 63;
    int row0 = blockIdx.x * 64 + w * 16;
    int arow = row0 + (lane & 15);
    if (arow >= NN) arow = NN - 1;
    f32x4 acc[4];
#pragma unroll
    for (int c = 0; c < 4; c++) acc[c] = (f32x4){0.f, 0.f, 0.f, 0.f};
#pragma unroll
    for (int ks = 0; ks < 2; ks++) {
        int kb = ks * 32 + (lane >> 4) * 8;
        uint4 raw = *(const uint4*)&h2bf[(size_t)arow * F2 + kb];
        union { uint4 u; bf16x8 f; } ua;
        {
            float e0 = eluf(fmaf(lo_bf(raw.x), sco[kb + 0], ssh[kb + 0]));
            float e1 = eluf(fmaf(hi_bf(raw.x), sco[kb + 1], ssh[kb + 1]));
            float e2 = eluf(fmaf(lo_bf(raw.y), sco[kb + 2], ssh[kb + 2]));
            float e3 = eluf(fmaf(hi_bf(raw.y), sco[kb + 3], ssh[kb + 3]));
            float e4 = eluf(fmaf(lo_bf(raw.z), sco[kb + 4], ssh[kb + 4]));
            float e5 = eluf(fmaf(hi_bf(raw.z), sco[kb + 5], ssh[kb + 5]));
            float e6 = eluf(fmaf(lo_bf(raw.w), sco[kb + 6], ssh[kb + 6]));
            float e7 = eluf(fmaf(hi_bf(raw.w), sco[kb + 7], ssh[kb + 7]));
            ua.u.x = pack2bf(e0, e1); ua.u.y = pack2bf(e2, e3);
            ua.u.z = pack2bf(e4, e5); ua.u.w = pack2bf(e6, e7);
        }
#pragma unroll
        for (int ct = 0; ct < 4; ct++) {
            union { uint4 u; bf16x8 f; } ub;
            ub.u = sfrag[(ks * 4 + ct) * 64 + lane];
            acc[ct] = __builtin_amdgcn_mfma_f32_16x16x32_bf16(ua.f, ub.f, acc[ct], 0, 0, 0);
        }
    }
    int mrow0 = row0 + (lane >> 4) * 4;
    int n = lane & 15;
#pragma unroll
    for (int reg = 0; reg < 4; reg++) {
        int r = mrow0 + reg;
        if (r >= NN) continue;
        float d = dinv[r];
#pragma unroll
        for (int ct = 0; ct < 4; ct++)
            hwd_bf[(size_t)r * F2 + ct * 16 + n] = f2bf(acc[ct][reg] * d);
    }
}

// h3 (bf16) = dinv[n]*(sum_src hwd[s] + hwd[n]) + gb
__global__ void k_gcn_gather(const int* __restrict__ rowptr, const int* __restrict__ csr_src,
                             const ushort* __restrict__ hwd_bf, const float* __restrict__ dinv,
                             const float* __restrict__ gb, ushort* __restrict__ h3bf) {
    int n = blockIdx.x * 4 + (threadIdx.x >> 6);
    int lane = threadIdx.x & 63;
    if (n >= NN) return;
    int j0 = rowptr[n], j1 = rowptr[n + 1];
    float acc = 0.f;
    for (int base = j0; base < j1; base += 64) {
        int cnt = min(64, j1 - base);
        int myj = base + lane;
        int sl = (myj < j1) ? csr_src[myj] : 0;
        int e = 0;
        for (; e + 4 <= cnt; e += 4) {
            int s0 = __shfl(sl, e + 0), s1 = __shfl(sl, e + 1),
                s2 = __shfl(sl, e + 2), s3 = __shfl(sl, e + 3);
            float t0 = bf2f(hwd_bf[(size_t)s0 * F2 + lane]);
            float t1 = bf2f(hwd_bf[(size_t)s1 * F2 + lane]);
            float t2 = bf2f(hwd_bf[(size_t)s2 * F2 + lane]);
            float t3 = bf2f(hwd_bf[(size_t)s3 * F2 + lane]);
            acc += (t0 + t1) + (t2 + t3);
        }
        for (; e < cnt; e++) {
            int s = __shfl(sl, e);
            acc += bf2f(hwd_bf[(size_t)s * F2 + lane]);
        }
    }
    float di = dinv[n];
    acc += bf2f(hwd_bf[(size_t)n * F2 + lane]);
    h3bf[(size_t)n * F2 + lane] = f2bf(acc * di + gb[lane]);
}

// =================== fused BN3-apply + ELU + segmented pool (bf16 input) ===================
__global__ void k_bn3_pool(const ushort* __restrict__ h3bf, const float* __restrict__ sums,
                           const float* __restrict__ g3, const float* __restrict__ b3,
                           const int* __restrict__ batch, float* __restrict__ psum,
                           unsigned* __restrict__ pmax, float* __restrict__ cnt) {
    int w = threadIdx.x >> 6;
    int lane = threadIdx.x & 63;   // lane = feature
    int chunk = blockIdx.x * 4 + w;
    int nchunks = gridDim.x * 4;
    int rows = (NN + nchunks - 1) / nchunks;
    int r0 = chunk * rows;
    int r1 = min(NN, r0 + rows);
    if (r0 >= r1) return;
    float m = sums[lane] * (1.0f / NN);
    float var = sums[F2 + lane] * (1.0f / NN) - m * m;
    float sc = rsqrtf(var + 1e-5f) * g3[lane];
    float bb = b3[lane];
    int curg = batch[r0];
    float ls = 0.f, lm = -INFINITY;
    int run = 0;
    for (int r = r0; r < r1; r++) {
        int gg = batch[r];
        if (gg != curg) {
            atomicAdd(&psum[curg * F2 + lane], ls);
            atomicMax(&pmax[curg * F2 + lane], enc_f(lm));
            if (lane == 0) atomicAdd(&cnt[curg], (float)run);
            curg = gg; ls = 0.f; lm = -INFINITY; run = 0;
        }
        float v = (bf2f(h3bf[(size_t)r * F2 + lane]) - m) * sc + bb;
        v = v > 0.f ? v : expm1f(v);
        ls += v; lm = fmaxf(lm, v); run++;
    }
    atomicAdd(&psum[curg * F2 + lane], ls);
    atomicMax(&pmax[curg * F2 + lane], enc_f(lm));
    if (lane == 0) atomicAdd(&cnt[curg], (float)run);
}

// =================== classifier ===================
__global__ void k_cls(const float* __restrict__ psum, const unsigned* __restrict__ pmax,
                      const float* __restrict__ cnt, const float* __restrict__ w1,
                      const float* __restrict__ b1, const float* __restrict__ w2,
                      const float* __restrict__ b2, float* __restrict__ out) {
    int g = blockIdx.x;
    int j = threadIdx.x;  // 64 threads
    __shared__ float z[2 * F2];
    __shared__ float hid[F2];
    float c = fmaxf(cnt[g], 1.0f);
    z[j] = psum[g * F2 + j] / c;
    float mv = dec_f(pmax[g * F2 + j]);
    z[F2 + j] = isfinite(mv) ? mv : 0.f;
    __syncthreads();
    float acc = b1[j];
#pragma unroll 8
    for (int k = 0; k < 2 * F2; k++) acc += z[k] * w1[k * F2 + j];
    hid[j] = fmaxf(acc, 0.f);
    __syncthreads();
    if (j < NCLS) {
        float o = b2[j];
#pragma unroll 8
        for (int k = 0; k < F2; k++) o += hid[k] * w2[k * NCLS + j];
        out[g * NCLS + j] = o;
    }
}

extern "C" void kernel_launch(void* const* d_in, const int* in_sizes, int n_in,
                              void* d_out, int out_size, void* d_ws, size_t ws_size,
                              hipStream_t stream) {
    const float* x       = (const float*)d_in[0];
    const int*   ei      = (const int*)d_in[1];
    const int*   batch   = (const int*)d_in[2];
    const float* gat_w   = (const float*)d_in[3];
    const float* att_src = (const float*)d_in[4];
    const float* att_dst = (const float*)d_in[5];
    // d_in[6] gat_b: cancels inside BN1
    const float* bn1_g   = (const float*)d_in[7];
    const float* bn1_b   = (const float*)d_in[8];
    const float* sage_wl = (const float*)d_in[9];
    const float* sage_bl = (const float*)d_in[10];
    const float* sage_wr = (const float*)d_in[11];
    const float* bn2_g   = (const float*)d_in[12];
    const float* bn2_b   = (const float*)d_in[13];
    const float* gcn_w   = (const float*)d_in[14];
    const float* gcn_b   = (const float*)d_in[15];
    const float* bn3_g   = (const float*)d_in[16];
    const float* bn3_b   = (const float*)d_in[17];
    const float* w1      = (const float*)d_in[18];
    const float* b1      = (const float*)d_in[19];
    const float* w2      = (const float*)d_in[20];
    const float* b2      = (const float*)d_in[21];
    float* out = (float*)d_out;

    float* ws = (float*)d_ws;
    // workspace layout (4-byte units; 16B alignment maintained)
    size_t o_A    = 0;                        // NN*F1 floats region, aliased (see below)
    size_t o_h1   = o_A   + (size_t)NN * F1;  // h1 bf16 (pre-BN1)
    size_t o_h2   = o_h1  + (size_t)NN * F1;  // h2 bf16 (pre-BN2)
    size_t o_csr  = o_h2  + (size_t)NN * F2;  // E ints (csr_src)
    size_t o_rp   = o_csr + (size_t)NE;       // N+4 ints (rowptr)
    size_t o_bb   = o_rp  + (size_t)(NN + 4); // NBUCK+1 ints (bucket bases), padded
    size_t o_bt   = o_bb  + 400;              // NBUCK ints (bucket totals), padded
    size_t o_asrc = o_bt  + 400;              // N*2
    size_t o_adst = o_asrc + (size_t)NN * 2;  // N*2
    size_t o_dinv = o_adst + (size_t)NN * 2;  // N
    size_t o_sums = o_dinv + (size_t)NN;      // 768 (3 x 256: bn1, bn2, bn3)
    size_t o_frd  = o_sums + 768;             // 8192 floats = 32KB dual B-frags
    size_t o_frg  = o_frd  + 8192;            // 2048 floats = 8KB gcn B-frags
    size_t o_psum = o_frg  + 2048;            // G*F2
    size_t o_cnt  = o_psum + (size_t)NG * F2; // G (adjacent to psum: one init)
    size_t o_pmax = o_cnt  + (size_t)NG;      // G*F2

    float* A    = ws + o_A;
    float* h1r  = ws + o_h1;
    float* h2r  = ws + o_h2;
    int* csr_src = (int*)(ws + o_csr);
    int* rowptr  = (int*)(ws + o_rp);
    int* bbase   = (int*)(ws + o_bb);
    int* btot    = (int*)(ws + o_bt);
    float* asr  = ws + o_asrc;
    float* ads  = ws + o_adst;
    float* dinv = ws + o_dinv;
    float* sums1 = ws + o_sums;
    float* sums2 = sums1 + 256;
    float* sums3 = sums2 + 256;
    ushort* fragd = (ushort*)(ws + o_frd);
    ushort* fragg = (ushort*)(ws + o_frg);
    float* psum = ws + o_psum;
    float* cnt  = ws + o_cnt;
    unsigned* pmax = (unsigned*)(ws + o_pmax);

    // region aliases (lifetimes disjoint):
    unsigned* staged = (unsigned*)A;                    // CSR build: NE entries (6.4 MB)
    int*    ghist  = (int*)(A + 2 * 1024 * 1024);       // CSR build: NCHUNK*NBUCK ints
    unsigned* xw32 = (unsigned*)A;                      // GAT: NN*64 packed bf16 pairs
    ushort* u_bf   = (ushort*)A;                        // SAGE: NN*F2 bf16 (xw dead)
    ushort* v_bf   = (ushort*)(A + (size_t)NN * F2 / 2);// SAGE: NN*F2 bf16
    ushort* hwd_bf = (ushort*)A;                        // GCN: NN*F2 bf16 (u dead)
    ushort* h3bf   = (ushort*)(A + (size_t)NN * F2 / 2);// GCN out: NN*F2 bf16 (v dead)
    unsigned* h1p  = (unsigned*)h1r;                    // pre-BN1 bf16 pairs (NN*64 u32)
    ushort* h1bf   = (ushort*)h1r;                      // same bytes as bf16[NN][128]
    ushort* h2bf   = (ushort*)h2r;                      // pre-BN2 bf16 (NN*F2)

    // ---- upfront init (one kernel) ----
    k_init<<<(NG * F2 + NG + 255) / 256 + 1, 256, 0, stream>>>(sums1, psum, pmax);

    // ---- CSR build: chunk-major radix ----
    k_hist<<<NCHUNK, 256, 0, stream>>>(ei, ghist);
    k_bscan<<<NBUCK, 256, 0, stream>>>(ghist, btot);
    k_bprefix<<<1, 512, 0, stream>>>(btot, bbase, rowptr);
    k_scatter2<<<NCHUNK, 256, 0, stream>>>(ei, ghist, bbase, staged);
    k_bucket_sort<<<NBUCK, 256, 0, stream>>>(staged, bbase, rowptr, csr_src, dinv);

    // ---- GAT (softmax fused into gather) ----
    k_xw<<<(NN + 63) / 64, 256, 0, stream>>>(x, gat_w, att_src, att_dst, xw32, asr, ads);
    k_gat_gather<<<(NN + 3) / 4, 256, 0, stream>>>(rowptr, csr_src, asr, ads, xw32, h1p);
    k_bn_stats_bf<<<1024, 256, 0, stream>>>(h1bf, F1, sums1);

    // ---- SAGE: MFMA dual-GEMM (BN1+ELU fused) then bf16 mean-gather ----
    k_packfrag<<<(16384 + 4096 + 255) / 256, 256, 0, stream>>>(sage_wl, sage_wr, gcn_w,
                                                               fragd, fragg);
    k_sage_dualgemm<<<(NN + 63) / 64, 256, 0, stream>>>(h1bf, sums1, bn1_g, bn1_b,
                                                        fragd, u_bf, v_bf);
    k_sage_gather2<<<(NN + 3) / 4, 256, 0, stream>>>(rowptr, csr_src, u_bf, v_bf,
                                                     sage_bl, h2bf);
    k_bn_stats_bf<<<1024, 256, 0, stream>>>(h2bf, F2, sums2);

    // ---- GCN: MFMA GEMM (BN2+ELU fused, dinv folded) then gather ----
    k_gcn_gemm<<<(NN + 63) / 64, 256, 0, stream>>>(h2bf, sums2, bn2_g, bn2_b,
                                                   fragg, dinv, hwd_bf);
    k_gcn_gather<<<(NN + 3) / 4, 256, 0, stream>>>(rowptr, csr_src, hwd_bf, dinv, gcn_b, h3bf);
    k_bn_stats_bf<<<1024, 256, 0, stream>>>(h3bf, F2, sums3);

    // ---- fused BN3 + ELU + pooling, then classifier ----
    k_bn3_pool<<<1024, 256, 0, stream>>>(h3bf, sums3, bn3_g, bn3_b, batch, psum, pmax, cnt);
    k_cls<<<NG, F2, 0, stream>>>(psum, pmax, cnt, w1, b1, w2, b2, out);
}

// Round 20
// 444.802 us; speedup vs baseline: 3.0553x; 1.0009x over previous
//
#include <hip/hip_runtime.h>
#include <hip/hip_bf16.h>
#include <math.h>

#define NN 100000      // nodes
#define NE 1600000     // edges
#define NG 64          // graphs
#define F_IN 5
#define F1 128         // H*HID
#define F2 64          // HID
#define NCLS 4
#define NCHUNK 250                   // edge chunks (250 * 6400 = NE)
#define CH_E 6400                    // edges per chunk
#define NBUCK ((NN + 255) / 256)     // 391 dst buckets of 256 nodes
#define CAPB 6144                    // bucket capacity in LDS sort

typedef unsigned short ushort;
typedef __bf16 bf16x8 __attribute__((ext_vector_type(8)));
typedef float f32x4 __attribute__((ext_vector_type(4)));

// ---------- bf16 helpers (round-to-nearest-even pack) ----------
__device__ __forceinline__ ushort f2bf(float f) {
    unsigned u = __float_as_uint(f);
    u = (u + 0x7fffu + ((u >> 16) & 1u)) >> 16;
    return (ushort)u;
}
__device__ __forceinline__ float bf2f(ushort h) {
    return __uint_as_float(((unsigned)h) << 16);
}
__device__ __forceinline__ unsigned pack2bf(float a, float b) {
    return (unsigned)f2bf(a) | ((unsigned)f2bf(b) << 16);
}
__device__ __forceinline__ float lo_bf(unsigned p) { return __uint_as_float(p << 16); }
__device__ __forceinline__ float hi_bf(unsigned p) { return __uint_as_float(p & 0xffff0000u); }
__device__ __forceinline__ float eluf(float z) { return z > 0.f ? z : expm1f(z); }

// ---------- order-preserving float<->uint encoding for atomicMax ----------
__device__ __forceinline__ unsigned enc_f(float f) {
    unsigned b = __float_as_uint(f);
    return (b & 0x80000000u) ? ~b : (b | 0x80000000u);
}
__device__ __forceinline__ float dec_f(unsigned k) {
    unsigned b = (k & 0x80000000u) ? (k ^ 0x80000000u) : ~k;
    return __uint_as_float(b);
}
#define ENC_NEG_INF 0x007FFFFFu   // enc_f(-inf)

// one-shot init: sums (768), psum+cnt (NG*F2+NG), pmax (NG*F2)
__global__ void k_init(float* __restrict__ sums, float* __restrict__ psum_cnt,
                       unsigned* __restrict__ pmax) {
    int i = blockIdx.x * 256 + threadIdx.x;
    if (i < 768) sums[i] = 0.f;
    if (i < NG * F2 + NG) psum_cnt[i] = 0.f;
    if (i < NG * F2) pmax[i] = ENC_NEG_INF;
}

// =================== CSR build (radix: hist -> bscan -> bprefix -> scatter -> sort) ===========
__global__ void k_hist(const int* __restrict__ ei, int* __restrict__ ghist) {
    __shared__ int lh[NBUCK];
    int c = blockIdx.x, t = threadIdx.x;
    for (int b = t; b < NBUCK; b += 256) lh[b] = 0;
    __syncthreads();
    int e0 = c * CH_E;
#pragma unroll
    for (int i = 0; i < CH_E / 256; i++) {
        int d = ei[NE + e0 + t + i * 256];
        atomicAdd(&lh[d >> 8], 1);
    }
    __syncthreads();
    for (int b = t; b < NBUCK; b += 256) ghist[c * NBUCK + b] = lh[b];
}

__global__ void k_bscan(int* __restrict__ ghist, int* __restrict__ btot) {
    __shared__ int sh[256];
    int b = blockIdx.x, t = threadIdx.x;
    int v = (t < NCHUNK) ? ghist[t * NBUCK + b] : 0;
    sh[t] = v;
    __syncthreads();
    for (int off = 1; off < 256; off <<= 1) {
        int u = (t >= off) ? sh[t - off] : 0;
        __syncthreads();
        sh[t] += u;
        __syncthreads();
    }
    if (t < NCHUNK) ghist[t * NBUCK + b] = sh[t] - v;   // exclusive, bucket-local
    if (t == 255) btot[b] = sh[255];
}

__global__ void k_bprefix(const int* __restrict__ btot, int* __restrict__ bbase,
                          int* __restrict__ rowptr) {
    __shared__ int sh[512];
    int t = threadIdx.x;
    int v = (t < NBUCK) ? btot[t] : 0;
    sh[t] = v;
    __syncthreads();
    for (int off = 1; off < 512; off <<= 1) {
        int u = (t >= off) ? sh[t - off] : 0;
        __syncthreads();
        sh[t] += u;
        __syncthreads();
    }
    if (t < NBUCK) bbase[t] = sh[t] - v;
    if (t == 0) { bbase[NBUCK] = NE; rowptr[NN] = NE; }
}

__global__ void k_scatter2(const int* __restrict__ ei, const int* __restrict__ ghist,
                           const int* __restrict__ bbase, unsigned* __restrict__ staged) {
    __shared__ int lcur[NBUCK];
    int c = blockIdx.x, t = threadIdx.x;
    for (int b = t; b < NBUCK; b += 256) lcur[b] = ghist[c * NBUCK + b] + bbase[b];
    __syncthreads();
    int e0 = c * CH_E;
#pragma unroll
    for (int i = 0; i < CH_E / 256; i++) {
        int e = e0 + t + i * 256;
        int s = ei[e];
        int d = ei[NE + e];
        int pos = atomicAdd(&lcur[d >> 8], 1);
        staged[pos] = (((unsigned)(d & 255)) << 17) | (unsigned)s;
    }
}

__global__ void k_bucket_sort(const unsigned* __restrict__ staged, const int* __restrict__ bbase,
                              int* __restrict__ rowptr, int* __restrict__ csr_src,
                              float* __restrict__ dinv) {
    __shared__ unsigned ein[CAPB];
    __shared__ unsigned sout[CAPB];
    __shared__ int lhist[256];
    __shared__ int lps[256];
    int b = blockIdx.x, t = threadIdx.x;
    int n0 = b * 256;
    int g0 = bbase[b];
    int m = bbase[b + 1] - g0;
    lhist[t] = 0;
    __syncthreads();
    if (m <= CAPB) {
        for (int i = t; i < m; i += 256) {
            unsigned u = staged[g0 + i];
            ein[i] = u;
            atomicAdd(&lhist[u >> 17], 1);
        }
        __syncthreads();
        if (n0 + t < NN) dinv[n0 + t] = rsqrtf((float)lhist[t] + 1.0f);
        lps[t] = lhist[t];
        __syncthreads();
        for (int off = 1; off < 256; off <<= 1) {
            int v = (t >= off) ? lps[t - off] : 0;
            __syncthreads();
            lps[t] += v;
            __syncthreads();
        }
        int excl = lps[t] - lhist[t];
        if (n0 + t < NN) rowptr[n0 + t] = g0 + excl;
        __syncthreads();
        lhist[t] = excl;   // reuse as cursor
        __syncthreads();
        for (int i = t; i < m; i += 256) {
            unsigned u = ein[i];
            int pos = atomicAdd(&lhist[u >> 17], 1);
            sout[pos] = u & 0x1FFFFu;
        }
        __syncthreads();
        for (int i = t; i < m; i += 256) csr_src[g0 + i] = (int)sout[i];
    } else {
        for (int i = t; i < m; i += 256) {
            unsigned u = staged[g0 + i];
            atomicAdd(&lhist[u >> 17], 1);
        }
        __syncthreads();
        if (n0 + t < NN) dinv[n0 + t] = rsqrtf((float)lhist[t] + 1.0f);
        lps[t] = lhist[t];
        __syncthreads();
        for (int off = 1; off < 256; off <<= 1) {
            int v = (t >= off) ? lps[t - off] : 0;
            __syncthreads();
            lps[t] += v;
            __syncthreads();
        }
        int excl = lps[t] - lhist[t];
        if (n0 + t < NN) rowptr[n0 + t] = g0 + excl;
        __syncthreads();
        lhist[t] = excl;
        __syncthreads();
        for (int i = t; i < m; i += 256) {
            unsigned u = staged[g0 + i];
            int pos = atomicAdd(&lhist[u >> 17], 1);
            csr_src[g0 + pos] = (int)(u & 0x1FFFFu);
        }
    }
}

// =================== GAT (xw + fused weight-fragment packing) ===================
__global__ void k_xw(const float* __restrict__ x, const float* __restrict__ gw,
                     const float* __restrict__ aw_src, const float* __restrict__ aw_dst,
                     const float* __restrict__ wl, const float* __restrict__ wr,
                     const float* __restrict__ wg,
                     ushort* __restrict__ fragd, ushort* __restrict__ fragg,
                     unsigned* __restrict__ xw32, float* __restrict__ a_src,
                     float* __restrict__ a_dst) {
    // fused MFMA B-fragment packing (first 80 blocks' indices)
    int gid = blockIdx.x * 256 + threadIdx.x;
    if (gid < 16384) {                       // dual: [ks(4)][ct(8)][lane(64)][e(8)]
        int e = gid & 7;
        int ln = (gid >> 3) & 63;
        int ct = (gid >> 9) & 7;
        int ks = gid >> 12;
        int k = ks * 32 + (ln >> 4) * 8 + e;
        int n = ct * 16 + (ln & 15);
        float val = (n < 64) ? wl[k * 64 + n] : wr[k * 64 + (n - 64)];
        fragd[gid] = f2bf(val);
    } else if (gid < 16384 + 4096) {         // gcn: [ks(2)][ct(4)][lane(64)][e(8)]
        int j = gid - 16384;
        int e = j & 7;
        int ln = (j >> 3) & 63;
        int ct = (j >> 9) & 3;
        int ks = j >> 11;
        int k = ks * 32 + (ln >> 4) * 8 + e;
        int n = ct * 16 + (ln & 15);
        fragg[j] = f2bf(wg[k * 64 + n]);
    }
    __shared__ float w[F_IN * F1];
    int t = threadIdx.x;
    for (int i = t; i < F_IN * F1; i += 256) w[i] = gw[i];
    int wv = t >> 6, lane = t & 63;
    int f0 = 2 * lane, f1 = 2 * lane + 1;
    float as0 = aw_src[f0], as1 = aw_src[f1];
    float ad0 = aw_dst[f0], ad1 = aw_dst[f1];
    __syncthreads();
    int nbase = blockIdx.x * 64;
    for (int it = 0; it < 16; it++) {
        int n = nbase + it * 4 + wv;
        if (n >= NN) break;
        float xs[F_IN];
#pragma unroll
        for (int j = 0; j < F_IN; j++) xs[j] = x[n * F_IN + j];
        float acc0 = 0.f, acc1 = 0.f;
#pragma unroll
        for (int j = 0; j < F_IN; j++) {
            acc0 += xs[j] * w[j * F1 + f0];
            acc1 += xs[j] * w[j * F1 + f1];
        }
        xw32[(size_t)n * 64 + lane] = pack2bf(acc0, acc1);
        float p = acc0 * as0 + acc1 * as1;
        float q = acc0 * ad0 + acc1 * ad1;
#pragma unroll
        for (int off = 1; off < 32; off <<= 1) {
            p += __shfl_xor(p, off);
            q += __shfl_xor(q, off);
        }
        if (lane == 0)  { a_src[n * 2 + 0] = p; a_dst[n * 2 + 0] = q; }
        if (lane == 32) { a_src[n * 2 + 1] = p; a_dst[n * 2 + 1] = q; }
    }
}

// FUSED softmax + gather: one wave per dst node; h1 written as packed bf16 pairs.
// Head-select via hoisted per-lane shift: w = uint_as_float((alpha << sh) & hi-mask).
__global__ void k_gat_gather(const int* __restrict__ rowptr, const int* __restrict__ csr_src,
                             const float* __restrict__ a_src, const float* __restrict__ a_dst,
                             const unsigned* __restrict__ xw32, unsigned* __restrict__ h1p) {
    int n = blockIdx.x * 4 + (threadIdx.x >> 6);
    int lane = threadIdx.x & 63;
    if (n >= NN) return;
    int j0 = rowptr[n], j1 = rowptr[n + 1];
    int deg = j1 - j0;
    float ad0 = a_dst[n * 2 + 0], ad1 = a_dst[n * 2 + 1];
    float acc0 = 0.f, acc1 = 0.f;
    unsigned sh = (lane < 32) ? 16u : 0u;
    if (deg <= 64) {
        int sl = 0;
        float l0 = -INFINITY, l1 = -INFINITY;
        if (lane < deg) {
            sl = csr_src[j0 + lane];
            l0 = a_src[sl * 2 + 0] + ad0;
            l1 = a_src[sl * 2 + 1] + ad1;
            l0 = l0 > 0.f ? l0 : 0.2f * l0;
            l1 = l1 > 0.f ? l1 : 0.2f * l1;
        }
        float m0 = l0, m1 = l1;
#pragma unroll
        for (int off = 32; off > 0; off >>= 1) {
            m0 = fmaxf(m0, __shfl_xor(m0, off));
            m1 = fmaxf(m1, __shfl_xor(m1, off));
        }
        float e0 = 0.f, e1 = 0.f;
        if (lane < deg) { e0 = expf(l0 - m0); e1 = expf(l1 - m1); }
        float s0 = e0, s1 = e1;
#pragma unroll
        for (int off = 32; off > 0; off >>= 1) {
            s0 += __shfl_xor(s0, off);
            s1 += __shfl_xor(s1, off);
        }
        unsigned al = pack2bf(e0 / (s0 + 1e-16f), e1 / (s1 + 1e-16f));
        int e = 0;
        for (; e + 4 <= deg; e += 4) {
            int s0i = __shfl(sl, e + 0), s1i = __shfl(sl, e + 1),
                s2i = __shfl(sl, e + 2), s3i = __shfl(sl, e + 3);
            unsigned b0 = __shfl(al, e + 0), b1 = __shfl(al, e + 1),
                     b2 = __shfl(al, e + 2), b3 = __shfl(al, e + 3);
            unsigned p0 = xw32[(size_t)s0i * 64 + lane];
            unsigned p1 = xw32[(size_t)s1i * 64 + lane];
            unsigned p2 = xw32[(size_t)s2i * 64 + lane];
            unsigned p3 = xw32[(size_t)s3i * 64 + lane];
            float w0 = __uint_as_float((b0 << sh) & 0xffff0000u);
            float w1 = __uint_as_float((b1 << sh) & 0xffff0000u);
            float w2 = __uint_as_float((b2 << sh) & 0xffff0000u);
            float w3 = __uint_as_float((b3 << sh) & 0xffff0000u);
            acc0 = fmaf(lo_bf(p0), w0, acc0); acc1 = fmaf(hi_bf(p0), w0, acc1);
            acc0 = fmaf(lo_bf(p1), w1, acc0); acc1 = fmaf(hi_bf(p1), w1, acc1);
            acc0 = fmaf(lo_bf(p2), w2, acc0); acc1 = fmaf(hi_bf(p2), w2, acc1);
            acc0 = fmaf(lo_bf(p3), w3, acc0); acc1 = fmaf(hi_bf(p3), w3, acc1);
        }
        for (; e < deg; e++) {
            int s = __shfl(sl, e); unsigned b = __shfl(al, e);
            unsigned p = xw32[(size_t)s * 64 + lane];
            float w = __uint_as_float((b << sh) & 0xffff0000u);
            acc0 = fmaf(lo_bf(p), w, acc0);
            acc1 = fmaf(hi_bf(p), w, acc1);
        }
    } else {
        float m0 = -INFINITY, m1 = -INFINITY, s0 = 0.f, s1 = 0.f;
        for (int base = j0; base < j1; base += 64) {
            int myj = base + lane;
            float l0 = -INFINITY, l1 = -INFINITY;
            if (myj < j1) {
                int s = csr_src[myj];
                l0 = a_src[s * 2 + 0] + ad0;
                l1 = a_src[s * 2 + 1] + ad1;
                l0 = l0 > 0.f ? l0 : 0.2f * l0;
                l1 = l1 > 0.f ? l1 : 0.2f * l1;
            }
            float cm0 = l0, cm1 = l1;
#pragma unroll
            for (int off = 32; off > 0; off >>= 1) {
                cm0 = fmaxf(cm0, __shfl_xor(cm0, off));
                cm1 = fmaxf(cm1, __shfl_xor(cm1, off));
            }
            float nm0 = fmaxf(m0, cm0), nm1 = fmaxf(m1, cm1);
            float ce0 = (myj < j1) ? expf(l0 - nm0) : 0.f;
            float ce1 = (myj < j1) ? expf(l1 - nm1) : 0.f;
            float cs0 = ce0, cs1 = ce1;
#pragma unroll
            for (int off = 32; off > 0; off >>= 1) {
                cs0 += __shfl_xor(cs0, off);
                cs1 += __shfl_xor(cs1, off);
            }
            s0 = s0 * expf(m0 - nm0) + cs0;
            s1 = s1 * expf(m1 - nm1) + cs1;
            m0 = nm0; m1 = nm1;
        }
        float r0 = 1.0f / (s0 + 1e-16f), r1 = 1.0f / (s1 + 1e-16f);
        for (int base = j0; base < j1; base += 64) {
            int cnt = min(64, j1 - base);
            int myj = base + lane;
            int sl = 0; unsigned al = 0;
            if (myj < j1) {
                sl = csr_src[myj];
                float l0 = a_src[sl * 2 + 0] + ad0;
                float l1 = a_src[sl * 2 + 1] + ad1;
                l0 = l0 > 0.f ? l0 : 0.2f * l0;
                l1 = l1 > 0.f ? l1 : 0.2f * l1;
                al = pack2bf(expf(l0 - m0) * r0, expf(l1 - m1) * r1);
            }
            int e = 0;
            for (; e + 4 <= cnt; e += 4) {
                int s0i = __shfl(sl, e + 0), s1i = __shfl(sl, e + 1),
                    s2i = __shfl(sl, e + 2), s3i = __shfl(sl, e + 3);
                unsigned b0 = __shfl(al, e + 0), b1 = __shfl(al, e + 1),
                         b2 = __shfl(al, e + 2), b3 = __shfl(al, e + 3);
                unsigned p0 = xw32[(size_t)s0i * 64 + lane];
                unsigned p1 = xw32[(size_t)s1i * 64 + lane];
                unsigned p2 = xw32[(size_t)s2i * 64 + lane];
                unsigned p3 = xw32[(size_t)s3i * 64 + lane];
                float w0 = __uint_as_float((b0 << sh) & 0xffff0000u);
                float w1 = __uint_as_float((b1 << sh) & 0xffff0000u);
                float w2 = __uint_as_float((b2 << sh) & 0xffff0000u);
                float w3 = __uint_as_float((b3 << sh) & 0xffff0000u);
                acc0 = fmaf(lo_bf(p0), w0, acc0); acc1 = fmaf(hi_bf(p0), w0, acc1);
                acc0 = fmaf(lo_bf(p1), w1, acc0); acc1 = fmaf(hi_bf(p1), w1, acc1);
                acc0 = fmaf(lo_bf(p2), w2, acc0); acc1 = fmaf(hi_bf(p2), w2, acc1);
                acc0 = fmaf(lo_bf(p3), w3, acc0); acc1 = fmaf(hi_bf(p3), w3, acc1);
            }
            for (; e < cnt; e++) {
                int s = __shfl(sl, e); unsigned b = __shfl(al, e);
                unsigned p = xw32[(size_t)s * 64 + lane];
                float w = __uint_as_float((b << sh) & 0xffff0000u);
                acc0 = fmaf(lo_bf(p), w, acc0);
                acc1 = fmaf(hi_bf(p), w, acc1);
            }
        }
    }
    h1p[(size_t)n * 64 + lane] = pack2bf(acc0, acc1);
}

// =================== BatchNorm stats (bf16 inputs) ===================
__global__ void k_bn_stats_bf(const ushort* __restrict__ h, int nfeat, float* __restrict__ sums) {
    __shared__ float sh[512];
    int t = threadIdx.x;
    int f = t & (nfeat - 1);
    int rg = t / nfeat;
    int R = 256 / nfeat;
    int rows = (NN + gridDim.x - 1) / gridDim.x;
    int rbase = blockIdx.x * rows;
    int r1 = min(NN, rbase + rows);
    float s = 0.f, ss = 0.f;
    for (int r = rbase + rg; r < r1; r += R) {
        float v = bf2f(h[(size_t)r * nfeat + f]);
        s += v; ss += v * v;
    }
    sh[t] = s; sh[256 + t] = ss;
    __syncthreads();
    if (rg == 0) {
        for (int g = 1; g < R; g++) {
            s += sh[g * nfeat + f];
            ss += sh[256 + g * nfeat + f];
        }
        atomicAdd(&sums[f], s);
        atomicAdd(&sums[nfeat + f], ss);
    }
}

// =================== SAGE dual GEMM via MFMA, BN1+ELU fused on A-load ===================
__global__ void k_sage_dualgemm(const ushort* __restrict__ h1bf, const float* __restrict__ sums,
                                const float* __restrict__ g, const float* __restrict__ b,
                                const ushort* __restrict__ fragd,
                                ushort* __restrict__ u_bf, ushort* __restrict__ v_bf) {
    __shared__ uint4 sfrag[2048];               // 32 KB
    __shared__ float sco[F1], ssh[F1];
    int t = threadIdx.x;
    const uint4* f4 = (const uint4*)fragd;
    for (int i = t; i < 2048; i += 256) sfrag[i] = f4[i];
    if (t < F1) {
        float m = sums[t] * (1.0f / NN);
        float var = sums[F1 + t] * (1.0f / NN) - m * m;
        float sc = rsqrtf(var + 1e-5f) * g[t];
        sco[t] = sc;
        ssh[t] = b[t] - m * sc;
    }
    __syncthreads();
    int w = t >> 6, lane = t & 63;
    int row0 = blockIdx.x * 64 + w * 16;
    int arow = row0 + (lane & 15);
    if (arow >= NN) arow = NN - 1;
    f32x4 acc[8];
#pragma unroll
    for (int c = 0; c < 8; c++) acc[c] = (f32x4){0.f, 0.f, 0.f, 0.f};
#pragma unroll
    for (int ks = 0; ks < 4; ks++) {
        int kb = ks * 32 + (lane >> 4) * 8;
        uint4 raw = *(const uint4*)&h1bf[(size_t)arow * F1 + kb];
        union { uint4 u; bf16x8 f; } ua;
        {
            float e0 = eluf(fmaf(lo_bf(raw.x), sco[kb + 0], ssh[kb + 0]));
            float e1 = eluf(fmaf(hi_bf(raw.x), sco[kb + 1], ssh[kb + 1]));
            float e2 = eluf(fmaf(lo_bf(raw.y), sco[kb + 2], ssh[kb + 2]));
            float e3 = eluf(fmaf(hi_bf(raw.y), sco[kb + 3], ssh[kb + 3]));
            float e4 = eluf(fmaf(lo_bf(raw.z), sco[kb + 4], ssh[kb + 4]));
            float e5 = eluf(fmaf(hi_bf(raw.z), sco[kb + 5], ssh[kb + 5]));
            float e6 = eluf(fmaf(lo_bf(raw.w), sco[kb + 6], ssh[kb + 6]));
            float e7 = eluf(fmaf(hi_bf(raw.w), sco[kb + 7], ssh[kb + 7]));
            ua.u.x = pack2bf(e0, e1); ua.u.y = pack2bf(e2, e3);
            ua.u.z = pack2bf(e4, e5); ua.u.w = pack2bf(e6, e7);
        }
#pragma unroll
        for (int ct = 0; ct < 8; ct++) {
            union { uint4 u; bf16x8 f; } ub;
            ub.u = sfrag[(ks * 8 + ct) * 64 + lane];
            acc[ct] = __builtin_amdgcn_mfma_f32_16x16x32_bf16(ua.f, ub.f, acc[ct], 0, 0, 0);
        }
    }
    int mrow0 = row0 + (lane >> 4) * 4;
    int n = lane & 15;
#pragma unroll
    for (int reg = 0; reg < 4; reg++) {
        int r = mrow0 + reg;
        if (r >= NN) continue;
#pragma unroll
        for (int ct = 0; ct < 4; ct++)
            u_bf[(size_t)r * F2 + ct * 16 + n] = f2bf(acc[ct][reg]);
#pragma unroll
        for (int ct = 4; ct < 8; ct++)
            v_bf[(size_t)r * F2 + (ct - 4) * 16 + n] = f2bf(acc[ct][reg]);
    }
}

// h2 (bf16) = mean-gather(u_bf16) + v_bf16[n] + bl   (8-deep load pipeline)
__global__ void k_sage_gather2(const int* __restrict__ rowptr, const int* __restrict__ csr_src,
                               const ushort* __restrict__ u_bf, const ushort* __restrict__ v_bf,
                               const float* __restrict__ bl, ushort* __restrict__ h2bf) {
    int n = blockIdx.x * 4 + (threadIdx.x >> 6);
    int lane = threadIdx.x & 63;
    if (n >= NN) return;
    int j0 = rowptr[n], j1 = rowptr[n + 1];
    float a = 0.f;
    for (int base = j0; base < j1; base += 64) {
        int cnt = min(64, j1 - base);
        int myj = base + lane;
        int sl = (myj < j1) ? csr_src[myj] : 0;
        int e = 0;
        for (; e + 8 <= cnt; e += 8) {
            int s0 = __shfl(sl, e + 0), s1 = __shfl(sl, e + 1),
                s2 = __shfl(sl, e + 2), s3 = __shfl(sl, e + 3),
                s4 = __shfl(sl, e + 4), s5 = __shfl(sl, e + 5),
                s6 = __shfl(sl, e + 6), s7 = __shfl(sl, e + 7);
            float t0 = bf2f(u_bf[(size_t)s0 * F2 + lane]);
            float t1 = bf2f(u_bf[(size_t)s1 * F2 + lane]);
            float t2 = bf2f(u_bf[(size_t)s2 * F2 + lane]);
            float t3 = bf2f(u_bf[(size_t)s3 * F2 + lane]);
            float t4 = bf2f(u_bf[(size_t)s4 * F2 + lane]);
            float t5 = bf2f(u_bf[(size_t)s5 * F2 + lane]);
            float t6 = bf2f(u_bf[(size_t)s6 * F2 + lane]);
            float t7 = bf2f(u_bf[(size_t)s7 * F2 + lane]);
            a += ((t0 + t1) + (t2 + t3)) + ((t4 + t5) + (t6 + t7));
        }
        for (; e < cnt; e++) {
            int s = __shfl(sl, e);
            a += bf2f(u_bf[(size_t)s * F2 + lane]);
        }
    }
    float inv = 1.0f / fmaxf((float)(j1 - j0), 1.0f);
    h2bf[(size_t)n * F2 + lane] = f2bf(a * inv + bf2f(v_bf[(size_t)n * F2 + lane]) + bl[lane]);
}

// =================== GCN GEMM via MFMA, BN2+ELU fused on A-load ===================
__global__ void k_gcn_gemm(const ushort* __restrict__ h2bf, const float* __restrict__ sums,
                           const float* __restrict__ g, const float* __restrict__ b,
                           const ushort* __restrict__ fragg,
                           const float* __restrict__ dinv, ushort* __restrict__ hwd_bf) {
    __shared__ uint4 sfrag[512];                // 8 KB
    __shared__ float sco[F2], ssh[F2];
    int t = threadIdx.x;
    const uint4* f4 = (const uint4*)fragg;
    for (int i = t; i < 512; i += 256) sfrag[i] = f4[i];
    if (t < F2) {
        float m = sums[t] * (1.0f / NN);
        float var = sums[F2 + t] * (1.0f / NN) - m * m;
        float sc = rsqrtf(var + 1e-5f) * g[t];
        sco[t] = sc;
        ssh[t] = b[t] - m * sc;
    }
    __syncthreads();
    int w = t >> 6, lane = t & 63;
    int row0 = blockIdx.x * 64 + w * 16;
    int arow = row0 + (lane & 15);
    if (arow >= NN) arow = NN - 1;
    f32x4 acc[4];
#pragma unroll
    for (int c = 0; c < 4; c++) acc[c] = (f32x4){0.f, 0.f, 0.f, 0.f};
#pragma unroll
    for (int ks = 0; ks < 2; ks++) {
        int kb = ks * 32 + (lane >> 4) * 8;
        uint4 raw = *(const uint4*)&h2bf[(size_t)arow * F2 + kb];
        union { uint4 u; bf16x8 f; } ua;
        {
            float e0 = eluf(fmaf(lo_bf(raw.x), sco[kb + 0], ssh[kb + 0]));
            float e1 = eluf(fmaf(hi_bf(raw.x), sco[kb + 1], ssh[kb + 1]));
            float e2 = eluf(fmaf(lo_bf(raw.y), sco[kb + 2], ssh[kb + 2]));
            float e3 = eluf(fmaf(hi_bf(raw.y), sco[kb + 3], ssh[kb + 3]));
            float e4 = eluf(fmaf(lo_bf(raw.z), sco[kb + 4], ssh[kb + 4]));
            float e5 = eluf(fmaf(hi_bf(raw.z), sco[kb + 5], ssh[kb + 5]));
            float e6 = eluf(fmaf(lo_bf(raw.w), sco[kb + 6], ssh[kb + 6]));
            float e7 = eluf(fmaf(hi_bf(raw.w), sco[kb + 7], ssh[kb + 7]));
            ua.u.x = pack2bf(e0, e1); ua.u.y = pack2bf(e2, e3);
            ua.u.z = pack2bf(e4, e5); ua.u.w = pack2bf(e6, e7);
        }
#pragma unroll
        for (int ct = 0; ct < 4; ct++) {
            union { uint4 u; bf16x8 f; } ub;
            ub.u = sfrag[(ks * 4 + ct) * 64 + lane];
            acc[ct] = __builtin_amdgcn_mfma_f32_16x16x32_bf16(ua.f, ub.f, acc[ct], 0, 0, 0);
        }
    }
    int mrow0 = row0 + (lane >> 4) * 4;
    int n = lane & 15;
#pragma unroll
    for (int reg = 0; reg < 4; reg++) {
        int r = mrow0 + reg;
        if (r >= NN) continue;
        float d = dinv[r];
#pragma unroll
        for (int ct = 0; ct < 4; ct++)
            hwd_bf[(size_t)r * F2 + ct * 16 + n] = f2bf(acc[ct][reg] * d);
    }
}

// h3 (bf16) = dinv[n]*(sum_src hwd[s] + hwd[n]) + gb   (8-deep load pipeline)
__global__ void k_gcn_gather(const int* __restrict__ rowptr, const int* __restrict__ csr_src,
                             const ushort* __restrict__ hwd_bf, const float* __restrict__ dinv,
                             const float* __restrict__ gb, ushort* __restrict__ h3bf) {
    int n = blockIdx.x * 4 + (threadIdx.x >> 6);
    int lane = threadIdx.x & 63;
    if (n >= NN) return;
    int j0 = rowptr[n], j1 = rowptr[n + 1];
    float acc = 0.f;
    for (int base = j0; base < j1; base += 64) {
        int cnt = min(64, j1 - base);
        int myj = base + lane;
        int sl = (myj < j1) ? csr_src[myj] : 0;
        int e = 0;
        for (; e + 8 <= cnt; e += 8) {
            int s0 = __shfl(sl, e + 0), s1 = __shfl(sl, e + 1),
                s2 = __shfl(sl, e + 2), s3 = __shfl(sl, e + 3),
                s4 = __shfl(sl, e + 4), s5 = __shfl(sl, e + 5),
                s6 = __shfl(sl, e + 6), s7 = __shfl(sl, e + 7);
            float t0 = bf2f(hwd_bf[(size_t)s0 * F2 + lane]);
            float t1 = bf2f(hwd_bf[(size_t)s1 * F2 + lane]);
            float t2 = bf2f(hwd_bf[(size_t)s2 * F2 + lane]);
            float t3 = bf2f(hwd_bf[(size_t)s3 * F2 + lane]);
            float t4 = bf2f(hwd_bf[(size_t)s4 * F2 + lane]);
            float t5 = bf2f(hwd_bf[(size_t)s5 * F2 + lane]);
            float t6 = bf2f(hwd_bf[(size_t)s6 * F2 + lane]);
            float t7 = bf2f(hwd_bf[(size_t)s7 * F2 + lane]);
            acc += ((t0 + t1) + (t2 + t3)) + ((t4 + t5) + (t6 + t7));
        }
        for (; e < cnt; e++) {
            int s = __shfl(sl, e);
            acc += bf2f(hwd_bf[(size_t)s * F2 + lane]);
        }
    }
    float di = dinv[n];
    acc += bf2f(hwd_bf[(size_t)n * F2 + lane]);
    h3bf[(size_t)n * F2 + lane] = f2bf(acc * di + gb[lane]);
}

// =================== fused BN3-apply + ELU + segmented pool (bf16 input) ===================
__global__ void k_bn3_pool(const ushort* __restrict__ h3bf, const float* __restrict__ sums,
                           const float* __restrict__ g3, const float* __restrict__ b3,
                           const int* __restrict__ batch, float* __restrict__ psum,
                           unsigned* __restrict__ pmax, float* __restrict__ cnt) {
    int w = threadIdx.x >> 6;
    int lane = threadIdx.x & 63;   // lane = feature
    int chunk = blockIdx.x * 4 + w;
    int nchunks = gridDim.x * 4;
    int rows = (NN + nchunks - 1) / nchunks;
    int r0 = chunk * rows;
    int r1 = min(NN, r0 + rows);
    if (r0 >= r1) return;
    float m = sums[lane] * (1.0f / NN);
    float var = sums[F2 + lane] * (1.0f / NN) - m * m;
    float sc = rsqrtf(var + 1e-5f) * g3[lane];
    float bb = b3[lane];
    int curg = batch[r0];
    float ls = 0.f, lm = -INFINITY;
    int run = 0;
    for (int r = r0; r < r1; r++) {
        int gg = batch[r];
        if (gg != curg) {
            atomicAdd(&psum[curg * F2 + lane], ls);
            atomicMax(&pmax[curg * F2 + lane], enc_f(lm));
            if (lane == 0) atomicAdd(&cnt[curg], (float)run);
            curg = gg; ls = 0.f; lm = -INFINITY; run = 0;
        }
        float v = (bf2f(h3bf[(size_t)r * F2 + lane]) - m) * sc + bb;
        v = v > 0.f ? v : expm1f(v);
        ls += v; lm = fmaxf(lm, v); run++;
    }
    atomicAdd(&psum[curg * F2 + lane], ls);
    atomicMax(&pmax[curg * F2 + lane], enc_f(lm));
    if (lane == 0) atomicAdd(&cnt[curg], (float)run);
}

// =================== classifier ===================
__global__ void k_cls(const float* __restrict__ psum, const unsigned* __restrict__ pmax,
                      const float* __restrict__ cnt, const float* __restrict__ w1,
                      const float* __restrict__ b1, const float* __restrict__ w2,
                      const float* __restrict__ b2, float* __restrict__ out) {
    int g = blockIdx.x;
    int j = threadIdx.x;  // 64 threads
    __shared__ float z[2 * F2];
    __shared__ float hid[F2];
    float c = fmaxf(cnt[g], 1.0f);
    z[j] = psum[g * F2 + j] / c;
    float mv = dec_f(pmax[g * F2 + j]);
    z[F2 + j] = isfinite(mv) ? mv : 0.f;
    __syncthreads();
    float acc = b1[j];
#pragma unroll 8
    for (int k = 0; k < 2 * F2; k++) acc += z[k] * w1[k * F2 + j];
    hid[j] = fmaxf(acc, 0.f);
    __syncthreads();
    if (j < NCLS) {
        float o = b2[j];
#pragma unroll 8
        for (int k = 0; k < F2; k++) o += hid[k] * w2[k * NCLS + j];
        out[g * NCLS + j] = o;
    }
}

extern "C" void kernel_launch(void* const* d_in, const int* in_sizes, int n_in,
                              void* d_out, int out_size, void* d_ws, size_t ws_size,
                              hipStream_t stream) {
    const float* x       = (const float*)d_in[0];
    const int*   ei      = (const int*)d_in[1];
    const int*   batch   = (const int*)d_in[2];
    const float* gat_w   = (const float*)d_in[3];
    const float* att_src = (const float*)d_in[4];
    const float* att_dst = (const float*)d_in[5];
    // d_in[6] gat_b: cancels inside BN1
    const float* bn1_g   = (const float*)d_in[7];
    const float* bn1_b   = (const float*)d_in[8];
    const float* sage_wl = (const float*)d_in[9];
    const float* sage_bl = (const float*)d_in[10];
    const float* sage_wr = (const float*)d_in[11];
    const float* bn2_g   = (const float*)d_in[12];
    const float* bn2_b   = (const float*)d_in[13];
    const float* gcn_w   = (const float*)d_in[14];
    const float* gcn_b   = (const float*)d_in[15];
    const float* bn3_g   = (const float*)d_in[16];
    const float* bn3_b   = (const float*)d_in[17];
    const float* w1      = (const float*)d_in[18];
    const float* b1      = (const float*)d_in[19];
    const float* w2      = (const float*)d_in[20];
    const float* b2      = (const float*)d_in[21];
    float* out = (float*)d_out;

    float* ws = (float*)d_ws;
    // workspace layout (4-byte units; 16B alignment maintained)
    size_t o_A    = 0;                        // NN*F1 floats region, aliased (see below)
    size_t o_h1   = o_A   + (size_t)NN * F1;  // h1 bf16 (pre-BN1)
    size_t o_h2   = o_h1  + (size_t)NN * F1;  // h2 bf16 (pre-BN2)
    size_t o_csr  = o_h2  + (size_t)NN * F2;  // E ints (csr_src)
    size_t o_rp   = o_csr + (size_t)NE;       // N+4 ints (rowptr)
    size_t o_bb   = o_rp  + (size_t)(NN + 4); // NBUCK+1 ints (bucket bases), padded
    size_t o_bt   = o_bb  + 400;              // NBUCK ints (bucket totals), padded
    size_t o_asrc = o_bt  + 400;              // N*2
    size_t o_adst = o_asrc + (size_t)NN * 2;  // N*2
    size_t o_dinv = o_adst + (size_t)NN * 2;  // N
    size_t o_sums = o_dinv + (size_t)NN;      // 768 (3 x 256: bn1, bn2, bn3)
    size_t o_frd  = o_sums + 768;             // 8192 floats = 32KB dual B-frags
    size_t o_frg  = o_frd  + 8192;            // 2048 floats = 8KB gcn B-frags
    size_t o_psum = o_frg  + 2048;            // G*F2
    size_t o_cnt  = o_psum + (size_t)NG * F2; // G (adjacent to psum: one init)
    size_t o_pmax = o_cnt  + (size_t)NG;      // G*F2

    float* A    = ws + o_A;
    float* h1r  = ws + o_h1;
    float* h2r  = ws + o_h2;
    int* csr_src = (int*)(ws + o_csr);
    int* rowptr  = (int*)(ws + o_rp);
    int* bbase   = (int*)(ws + o_bb);
    int* btot    = (int*)(ws + o_bt);
    float* asr  = ws + o_asrc;
    float* ads  = ws + o_adst;
    float* dinv = ws + o_dinv;
    float* sums1 = ws + o_sums;
    float* sums2 = sums1 + 256;
    float* sums3 = sums2 + 256;
    ushort* fragd = (ushort*)(ws + o_frd);
    ushort* fragg = (ushort*)(ws + o_frg);
    float* psum = ws + o_psum;
    float* cnt  = ws + o_cnt;
    unsigned* pmax = (unsigned*)(ws + o_pmax);

    // region aliases (lifetimes disjoint):
    unsigned* staged = (unsigned*)A;                    // CSR build: NE entries (6.4 MB)
    int*    ghist  = (int*)(A + 2 * 1024 * 1024);       // CSR build: NCHUNK*NBUCK ints
    unsigned* xw32 = (unsigned*)A;                      // GAT: NN*64 packed bf16 pairs
    ushort* u_bf   = (ushort*)A;                        // SAGE: NN*F2 bf16 (xw dead)
    ushort* v_bf   = (ushort*)(A + (size_t)NN * F2 / 2);// SAGE: NN*F2 bf16
    ushort* hwd_bf = (ushort*)A;                        // GCN: NN*F2 bf16 (u dead)
    ushort* h3bf   = (ushort*)(A + (size_t)NN * F2 / 2);// GCN out: NN*F2 bf16 (v dead)
    unsigned* h1p  = (unsigned*)h1r;                    // pre-BN1 bf16 pairs (NN*64 u32)
    ushort* h1bf   = (ushort*)h1r;                      // same bytes as bf16[NN][128]
    ushort* h2bf   = (ushort*)h2r;                      // pre-BN2 bf16 (NN*F2)

    // ---- upfront init (one kernel) ----
    k_init<<<(NG * F2 + NG + 255) / 256 + 1, 256, 0, stream>>>(sums1, psum, pmax);

    // ---- CSR build: chunk-major radix ----
    k_hist<<<NCHUNK, 256, 0, stream>>>(ei, ghist);
    k_bscan<<<NBUCK, 256, 0, stream>>>(ghist, btot);
    k_bprefix<<<1, 512, 0, stream>>>(btot, bbase, rowptr);
    k_scatter2<<<NCHUNK, 256, 0, stream>>>(ei, ghist, bbase, staged);
    k_bucket_sort<<<NBUCK, 256, 0, stream>>>(staged, bbase, rowptr, csr_src, dinv);

    // ---- GAT (xw + fragment packing fused; softmax fused into gather) ----
    k_xw<<<(NN + 63) / 64, 256, 0, stream>>>(x, gat_w, att_src, att_dst,
                                             sage_wl, sage_wr, gcn_w, fragd, fragg,
                                             xw32, asr, ads);
    k_gat_gather<<<(NN + 3) / 4, 256, 0, stream>>>(rowptr, csr_src, asr, ads, xw32, h1p);
    k_bn_stats_bf<<<1024, 256, 0, stream>>>(h1bf, F1, sums1);

    // ---- SAGE: MFMA dual-GEMM (BN1+ELU fused) then bf16 mean-gather ----
    k_sage_dualgemm<<<(NN + 63) / 64, 256, 0, stream>>>(h1bf, sums1, bn1_g, bn1_b,
                                                        fragd, u_bf, v_bf);
    k_sage_gather2<<<(NN + 3) / 4, 256, 0, stream>>>(rowptr, csr_src, u_bf, v_bf,
                                                     sage_bl, h2bf);
    k_bn_stats_bf<<<1024, 256, 0, stream>>>(h2bf, F2, sums2);

    // ---- GCN: MFMA GEMM (BN2+ELU fused, dinv folded) then gather ----
    k_gcn_gemm<<<(NN + 63) / 64, 256, 0, stream>>>(h2bf, sums2, bn2_g, bn2_b,
                                                   fragg, dinv, hwd_bf);
    k_gcn_gather<<<(NN + 3) / 4, 256, 0, stream>>>(rowptr, csr_src, hwd_bf, dinv, gcn_b, h3bf);
    k_bn_stats_bf<<<1024, 256, 0, stream>>>(h3bf, F2, sums3);

    // ---- fused BN3 + ELU + pooling, then classifier ----
    k_bn3_pool<<<1024, 256, 0, stream>>>(h3bf, sums3, bn3_g, bn3_b, batch, psum, pmax, cnt);
    k_cls<<<NG, F2, 0, stream>>>(psum, pmax, cnt, w1, b1, w2, b2, out);
}